// Round 3
// baseline (6396.389 us; speedup 1.0000x reference)
//
#include <hip/hip_runtime.h>
#include <hip/hip_bf16.h>

// ---------------------------------------------------------------------------
// SHINE forward, fp32 direct-conv. Workspace (218,841,088 B total):
//   concat : bf16 [2][576][256][256]  150,994,944 B   (9 slices of 64ch)
//   A, B   : f32  [2][64][256][256]   2 x 33,554,432 B  (ping-pong, reused at
//                                      all scales; residual adds are in-place)
//   w1t    : f32  [576][288]              663,552 B
//   w2t    : f32  [288][64]                73,728 B
// ---------------------------------------------------------------------------

#define HPX 65536   // 256*256
#define FCH 64

__device__ __forceinline__ float gelu_f(float x) {
  return 0.5f * x * (1.0f + erff(x * 0.70710678118654752440f));
}

// ---------------- conv0: base = concat(gelu(1x1(target)), gelu(3x3(feats)))
__global__ __launch_bounds__(256) void conv0_kernel(
    const float* __restrict__ img,   // [2][5][256][256]
    const float* __restrict__ w0a,   // [16][4][3][3]
    const float* __restrict__ w0b,   // [48]
    float* __restrict__ base)        // [2][64][256][256]
{
  long t = (long)blockIdx.x * 256 + threadIdx.x;   // over 2*64*65536
  int px = (int)(t & (HPX - 1));
  int c  = (int)((t >> 16) & 63);
  int n  = (int)(t >> 22);
  const float* im = img + (long)n * 5 * HPX;
  float r;
  if (c < 48) {
    r = w0b[c] * im[2 * HPX + px];
  } else {
    int co = c - 48;
    int y = px >> 8, x = px & 255;
    r = 0.0f;
    const int map4[4] = {0, 1, 3, 4};
    #pragma unroll
    for (int fi = 0; fi < 4; fi++) {
      const float* imc = im + (long)map4[fi] * HPX;
      #pragma unroll
      for (int ky = 0; ky < 3; ky++) {
        int yy = y + ky - 1;
        #pragma unroll
        for (int kx = 0; kx < 3; kx++) {
          int xx = x + kx - 1;
          bool ok = ((unsigned)yy < 256u) && ((unsigned)xx < 256u);
          float v = ok ? imc[yy * 256 + xx] : 0.0f;
          r = fmaf(w0a[((co * 4 + fi) * 3 + ky) * 3 + kx], v, r);
        }
      }
    }
  }
  base[t] = gelu_f(r);
}

// ---------------- generic 64->64 direct conv (+gelu, opt residual, opt bf16 out)
// NTAPS: 9 = full 3x3, 8 = donut. thread: 4 px x 8 oc; block: 4 waves = 32 oc.
// RESID: out may alias resid (each (o,p) is read-then-written by one thread).
template <int NTAPS, bool RESID, bool OBF16>
__global__ __launch_bounds__(256) void conv64_kernel(
    const float* __restrict__ in,     // [2][64][Hs][Ws]
    const float* __restrict__ wgt,    // [64][64][NTAPS]
    const float* __restrict__ resid,  // [2][64][Hs][Ws] or null
    void* __restrict__ outv,
    int Hs, int logW, int dil, long out_n_stride /*elements*/)
{
  const int Ws   = 1 << logW;
  const int npx  = Hs << logW;
  const int lane = threadIdx.x & 63;
  const int wave = threadIdx.x >> 6;
  const int obase = blockIdx.y * 32 + wave * 8;
  const int n = blockIdx.z;
  const float* inn = in + (long)n * FCH * npx;

  const int p0 = blockIdx.x * 256 + lane;

  int   poff[NTAPS][4];
  float pmsk[NTAPS][4];
  #pragma unroll
  for (int t = 0; t < NTAPS; t++) {
    const int kk = (NTAPS == 9) ? t : (t < 4 ? t : t + 1);
    const int dy = kk / 3 - 1, dx = kk % 3 - 1;
    const int dyd = dy * dil, dxd = dx * dil;
    #pragma unroll
    for (int k = 0; k < 4; k++) {
      int p = p0 + 64 * k;
      int y = p >> logW, x = p & (Ws - 1);
      int yy = y + dyd, xx = x + dxd;
      bool ok = ((unsigned)yy < (unsigned)Hs) && ((unsigned)xx < (unsigned)Ws);
      poff[t][k] = ok ? ((yy << logW) + xx) : 0;
      pmsk[t][k] = ok ? 1.0f : 0.0f;
    }
  }

  float acc[8][4];
  #pragma unroll
  for (int j = 0; j < 8; j++)
    #pragma unroll
    for (int k = 0; k < 4; k++) acc[j][k] = 0.0f;

  for (int ci = 0; ci < FCH; ci++) {
    const float* inc = inn + (long)ci * npx;
    const float* wc  = wgt + ((long)obase * FCH + ci) * NTAPS;
    #pragma unroll
    for (int t = 0; t < NTAPS; t++) {
      float w[8];
      #pragma unroll
      for (int j = 0; j < 8; j++) w[j] = wc[(long)j * FCH * NTAPS + t];
      float v[4];
      #pragma unroll
      for (int k = 0; k < 4; k++) v[k] = inc[poff[t][k]] * pmsk[t][k];
      #pragma unroll
      for (int j = 0; j < 8; j++)
        #pragma unroll
        for (int k = 0; k < 4; k++)
          acc[j][k] = fmaf(w[j], v[k], acc[j][k]);
    }
  }

  #pragma unroll
  for (int j = 0; j < 8; j++) {
    const int o = obase + j;
    #pragma unroll
    for (int k = 0; k < 4; k++) {
      const int p = p0 + 64 * k;
      float r = acc[j][k];
      if (RESID) r += resid[(long)n * FCH * npx + (long)o * npx + p];
      r = gelu_f(r);
      long oidx = (long)n * out_n_stride + (long)o * npx + p;
      if (OBF16) ((__hip_bfloat16*)outv)[oidx] = __float2bfloat16(r);
      else       ((float*)outv)[oidx] = r;
    }
  }
}

// ---------------- 2x2 average pool
__global__ __launch_bounds__(256) void avgpool_kernel(
    const float* __restrict__ in, float* __restrict__ out, int logWo)
{
  const int lognpo = 2 * logWo;
  long t = (long)blockIdx.x * 256 + threadIdx.x;   // over 2*64*npo
  int p  = (int)(t & ((1 << lognpo) - 1));
  long nc = t >> lognpo;
  int y = p >> logWo, x = p & ((1 << logWo) - 1);
  int Wi = 2 << logWo;
  const float* ic = in + nc * ((long)4 << lognpo);
  int b = (2 * y) * Wi + 2 * x;
  float s = ic[b] + ic[b + 1] + ic[b + Wi] + ic[b + Wi + 1];
  out[t] = 0.25f * s;
}

// ---------------- bilinear upsample (Hs->256, clamped == jax renorm) fused
// with 1x1 conv64 + gelu -> bf16 slice of concat. Hs==256 degenerates to
// identity sampling (wy=wx=0, all taps equal).
__global__ __launch_bounds__(256) void ups_kernel(
    const float* __restrict__ in,        // [2][64][Hs][Hs]
    const float* __restrict__ w,         // [64][64]
    __hip_bfloat16* __restrict__ slice,  // concat + sidx*64*HPX, n-stride 576*HPX
    int Hs)
{
  const int lane = threadIdx.x & 63;
  const int wave = threadIdx.x >> 6;
  const int obase = blockIdx.y * 32 + wave * 8;
  const int n = blockIdx.z;
  const int p0 = blockIdx.x * 256 + lane;
  const float* inn = in + (long)n * FCH * Hs * Hs;

  int o00[4], o01[4], o10[4], o11[4];
  float fwx[4], fwy[4];
  const float s = (float)Hs * (1.0f / 256.0f);
  #pragma unroll
  for (int k = 0; k < 4; k++) {
    int p = p0 + 64 * k;
    int Y = p >> 8, X = p & 255;
    float fy = ((float)Y + 0.5f) * s - 0.5f;
    float fx = ((float)X + 0.5f) * s - 0.5f;
    int y0 = (int)floorf(fy), x0 = (int)floorf(fx);
    fwy[k] = fy - (float)y0; fwx[k] = fx - (float)x0;
    int y0c = min(max(y0, 0), Hs - 1), y1c = min(max(y0 + 1, 0), Hs - 1);
    int x0c = min(max(x0, 0), Hs - 1), x1c = min(max(x0 + 1, 0), Hs - 1);
    o00[k] = y0c * Hs + x0c; o01[k] = y0c * Hs + x1c;
    o10[k] = y1c * Hs + x0c; o11[k] = y1c * Hs + x1c;
  }

  float acc[8][4];
  #pragma unroll
  for (int j = 0; j < 8; j++)
    #pragma unroll
    for (int k = 0; k < 4; k++) acc[j][k] = 0.0f;

  for (int ci = 0; ci < FCH; ci++) {
    const float* inc = inn + (long)ci * Hs * Hs;
    float v[4];
    #pragma unroll
    for (int k = 0; k < 4; k++) {
      float v00 = inc[o00[k]], v01 = inc[o01[k]];
      float v10 = inc[o10[k]], v11 = inc[o11[k]];
      float a = v00 + fwx[k] * (v01 - v00);
      float b = v10 + fwx[k] * (v11 - v10);
      v[k] = a + fwy[k] * (b - a);
    }
    float wv[8];
    #pragma unroll
    for (int j = 0; j < 8; j++) wv[j] = w[(obase + j) * FCH + ci];
    #pragma unroll
    for (int j = 0; j < 8; j++)
      #pragma unroll
      for (int k = 0; k < 4; k++)
        acc[j][k] = fmaf(wv[j], v[k], acc[j][k]);
  }

  #pragma unroll
  for (int j = 0; j < 8; j++)
    #pragma unroll
    for (int k = 0; k < 4; k++)
      slice[(long)n * 576 * HPX + (long)(obase + j) * HPX + p0 + 64 * k] =
          __float2bfloat16(gelu_f(acc[j][k]));
}

// ---------------- tiny transpose: w[R][C] -> wt[C][R]
__global__ __launch_bounds__(256) void transpose_w_kernel(
    const float* __restrict__ w, float* __restrict__ wt, int R, int C)
{
  int t = blockIdx.x * 256 + threadIdx.x;
  if (t < R * C) {
    int r = t / C, c = t % C;
    wt[c * R + r] = w[t];
  }
}

// ---------------- fused head: out = W3 @ gelu(W2 @ gelu(W1 @ concat))
// block = 256 thr, 64 px. phase1: wave w computes h[w*72 .. +72][64px] -> LDS.
// phase2: 4 lanes/px cover 64 mid-channels in chunks of 16, shuffle-reduce.
__global__ __launch_bounds__(256) void head_kernel(
    const __hip_bfloat16* __restrict__ v,  // [2][576][65536]
    const float* __restrict__ w1t,         // [576][288]
    const float* __restrict__ w2t,         // [288][64]
    const float* __restrict__ w3,          // [64]
    float* __restrict__ out)               // [2][65536]
{
  __shared__ float h[288][64];   // 73,728 B
  const int lane = threadIdx.x & 63;
  const int wave = threadIdx.x >> 6;
  const int n = blockIdx.y;
  const int pxb = blockIdx.x * 64;
  const __hip_bfloat16* vn = v + (long)n * 576 * HPX + pxb;

  { // phase 1
    const int ocb = wave * 72;
    float acc[72];
    #pragma unroll
    for (int j = 0; j < 72; j++) acc[j] = 0.0f;
    for (int ci = 0; ci < 576; ci++) {
      float x = __bfloat162float(vn[(long)ci * HPX + lane]);
      const float4* wr = (const float4*)(w1t + (long)ci * 288 + ocb);
      #pragma unroll
      for (int j4 = 0; j4 < 18; j4++) {
        float4 wv = wr[j4];
        acc[4 * j4 + 0] = fmaf(wv.x, x, acc[4 * j4 + 0]);
        acc[4 * j4 + 1] = fmaf(wv.y, x, acc[4 * j4 + 1]);
        acc[4 * j4 + 2] = fmaf(wv.z, x, acc[4 * j4 + 2]);
        acc[4 * j4 + 3] = fmaf(wv.w, x, acc[4 * j4 + 3]);
      }
    }
    #pragma unroll
    for (int j = 0; j < 72; j++) h[ocb + j][lane] = gelu_f(acc[j]);
  }
  __syncthreads();
  { // phase 2
    const int px = wave * 16 + (lane & 15);
    const int q  = lane >> 4;          // 0..3
    const int ob = q * 16;
    float acc2[16];
    #pragma unroll
    for (int j = 0; j < 16; j++) acc2[j] = 0.0f;
    for (int c = 0; c < 288; c++) {
      float hv = h[c][px];
      const float4* wr = (const float4*)(w2t + c * 64 + ob);
      #pragma unroll
      for (int j4 = 0; j4 < 4; j4++) {
        float4 wv = wr[j4];
        acc2[4 * j4 + 0] = fmaf(wv.x, hv, acc2[4 * j4 + 0]);
        acc2[4 * j4 + 1] = fmaf(wv.y, hv, acc2[4 * j4 + 1]);
        acc2[4 * j4 + 2] = fmaf(wv.z, hv, acc2[4 * j4 + 2]);
        acc2[4 * j4 + 3] = fmaf(wv.w, hv, acc2[4 * j4 + 3]);
      }
    }
    float r = 0.0f;
    #pragma unroll
    for (int j = 0; j < 16; j++) r = fmaf(w3[ob + j], gelu_f(acc2[j]), r);
    r += __shfl_xor(r, 16);
    r += __shfl_xor(r, 32);
    if (q == 0) out[(long)n * HPX + pxb + px] = r;
  }
}

// ---------------------------------------------------------------------------
// host-side helpers
// ---------------------------------------------------------------------------
static inline void conv9(const float* in, const float* w, float* out,
                         int Hs, int logW, hipStream_t s) {
  int npx = Hs << logW;
  conv64_kernel<9, false, false><<<dim3(npx / 256, 2, 2), 256, 0, s>>>(
      in, w, nullptr, out, Hs, logW, 1, (long)FCH * npx);
}
// second conv of a resblock, residual add; out aliases resid (in-place safe)
static inline void conv9r(const float* in, const float* w, float* resid_out,
                          int Hs, int logW, hipStream_t s) {
  int npx = Hs << logW;
  conv64_kernel<9, true, false><<<dim3(npx / 256, 2, 2), 256, 0, s>>>(
      in, w, resid_out, resid_out, Hs, logW, 1, (long)FCH * npx);
}
static inline void donut_f(const float* in, const float* w, float* out,
                           int Hs, int logW, int dil, hipStream_t s) {
  int npx = Hs << logW;
  conv64_kernel<8, false, false><<<dim3(npx / 256, 2, 2), 256, 0, s>>>(
      in, w, nullptr, out, Hs, logW, dil, (long)FCH * npx);
}
static inline void donut_b(const float* in, const float* w, __hip_bfloat16* slice,
                           int dil, hipStream_t s) {
  conv64_kernel<8, false, true><<<dim3(256, 2, 2), 256, 0, s>>>(
      in, w, nullptr, slice, 256, 8, dil, (long)576 * HPX);
}
static inline void ups(const float* in, const float* w, __hip_bfloat16* slice,
                       int Hs, hipStream_t s) {
  ups_kernel<<<dim3(256, 2, 2), 256, 0, s>>>(in, w, slice, Hs);
}
static inline void avgpool(const float* in, float* out, int logWo, hipStream_t s) {
  long total = (long)2 * FCH * (1L << (2 * logWo));
  avgpool_kernel<<<(int)(total / 256), 256, 0, s>>>(in, out, logWo);
}

extern "C" void kernel_launch(void* const* d_in, const int* in_sizes, int n_in,
                              void* d_out, int out_size, void* d_ws, size_t ws_size,
                              hipStream_t stream) {
  const float* img      = (const float*)d_in[0];
  const float* w0a      = (const float*)d_in[1];
  const float* w0b      = (const float*)d_in[2];
  const float* first_p  = (const float*)d_in[3];
  const float* cl10     = (const float*)d_in[4];   // [4][2][64*64*9]
  const float* cl2      = (const float*)d_in[5];
  const float* dil_p    = (const float*)d_in[6];   // [4][64*64*8]
  const float* dilres_p = (const float*)d_in[7];
  const float* ups_w    = (const float*)d_in[8];   // [4][64*64]
  const float* w1       = (const float*)d_in[9];   // [288][576]
  const float* w2       = (const float*)d_in[10];  // [64][288]
  const float* w3       = (const float*)d_in[11];  // [64]

  const size_t CONCAT_B = 150994944ul;             // 2*576*65536*2
  const size_t PBUF_B   = 33554432ul;              // 2*64*65536*4
  const size_t W1T_B    = 576ul * 288 * 4;
  const size_t W2T_B    = 288ul * 64 * 4;
  const size_t NEED = CONCAT_B + 2 * PBUF_B + W1T_B + W2T_B;  // 218,841,088

  if (ws_size < NEED) {
    // diagnostic fallback: clean absmax failure instead of a page fault
    hipMemsetAsync(d_out, 0, (size_t)out_size * 4, stream);
    return;
  }

  char* wsb = (char*)d_ws;
  __hip_bfloat16* concat = (__hip_bfloat16*)wsb;
  float* A   = (float*)(wsb + CONCAT_B);
  float* B   = (float*)(wsb + CONCAT_B + PBUF_B);
  float* w1t = (float*)(wsb + CONCAT_B + 2 * PBUF_B);
  float* w2t = (float*)(wsb + CONCAT_B + 2 * PBUF_B + W1T_B);

  auto SL = [&](int sidx) { return concat + (long)sidx * FCH * HPX; };
  const int C9 = 64 * 64 * 9, C8 = 64 * 64 * 8, C1 = 64 * 64;

  transpose_w_kernel<<<(288 * 576 + 255) / 256, 256, 0, stream>>>(w1, w1t, 288, 576);
  transpose_w_kernel<<<(64 * 288 + 255) / 256, 256, 0, stream>>>(w2, w2t, 64, 288);

  conv0_kernel<<<(2 * FCH * HPX) / 256, 256, 0, stream>>>(img, w0a, w0b, A);

  // outs[0]; base = resblock(base, cl10[0]); outs[1]; base = resblock(base, cl2[0])
  donut_b(A, first_p, SL(0), 1, stream);
  conv9(A, cl10 + 0 * C9, B, 256, 8, stream);
  conv9r(B, cl10 + 1 * C9, A, 256, 8, stream);               // base = A @256
  donut_b(A, dilres_p + 0 * C8, SL(1), 3, stream);
  conv9(A, cl2 + 0 * C9, B, 256, 8, stream);
  conv9r(B, cl2 + 1 * C9, A, 256, 8, stream);                // base = A @256

  // ---- i = 0 (dil 5 @256)
  donut_f(A, dil_p + 0 * C8, B, 256, 8, 5, stream);
  ups(B, ups_w + 0 * C1, SL(2), 256, stream);                // scale 1 (identity)
  avgpool(A, B, 7, stream);                                  // base = B @128
  conv9(B, cl10 + 2 * C9, A, 128, 7, stream);
  conv9r(A, cl10 + 3 * C9, B, 128, 7, stream);               // base = B @128
  donut_f(B, dilres_p + 1 * C8, A, 128, 7, 6, stream);
  ups(A, ups_w + 1 * C1, SL(3), 128, stream);
  conv9(B, cl2 + 2 * C9, A, 128, 7, stream);
  conv9r(A, cl2 + 3 * C9, B, 128, 7, stream);                // base = B @128

  // ---- i = 1 (dil 8 @128)
  donut_f(B, dil_p + 1 * C8, A, 128, 7, 8, stream);
  ups(A, ups_w + 1 * C1, SL(4), 128, stream);
  avgpool(B, A, 6, stream);                                  // base = A @64
  conv9(A, cl10 + 4 * C9, B, 64, 6, stream);
  conv9r(B, cl10 + 5 * C9, A, 64, 6, stream);                // base = A @64
  donut_f(A, dilres_p + 2 * C8, B, 64, 6, 8, stream);
  ups(B, ups_w + 2 * C1, SL(5), 64, stream);
  conv9(A, cl2 + 4 * C9, B, 64, 6, stream);
  conv9r(B, cl2 + 5 * C9, A, 64, 6, stream);                 // base = A @64

  // ---- i = 2 (dil 10 @64)
  donut_f(A, dil_p + 2 * C8, B, 64, 6, 10, stream);
  ups(B, ups_w + 2 * C1, SL(6), 64, stream);
  avgpool(A, B, 5, stream);                                  // base = B @32
  conv9(B, cl10 + 6 * C9, A, 32, 5, stream);
  conv9r(A, cl10 + 7 * C9, B, 32, 5, stream);                // base = B @32
  donut_f(B, dilres_p + 3 * C8, A, 32, 5, 9, stream);
  ups(A, ups_w + 3 * C1, SL(7), 32, stream);
  conv9(B, cl2 + 6 * C9, A, 32, 5, stream);
  conv9r(A, cl2 + 7 * C9, B, 32, 5, stream);                 // base = B @32

  // ---- i = 3 (dil 11 @32)
  donut_f(B, dil_p + 3 * C8, A, 32, 5, 11, stream);
  ups(A, ups_w + 3 * C1, SL(8), 32, stream);

  // ---- fused head
  head_kernel<<<dim3(1024, 2), 256, 0, stream>>>(concat, w1t, w2t, w3,
                                                 (float*)d_out);
}

// Round 4
// 6384.798 us; speedup vs baseline: 1.0018x; 1.0018x over previous
//
#include <hip/hip_runtime.h>
#include <hip/hip_bf16.h>

// ---------------------------------------------------------------------------
// SHINE forward, fp32 direct-conv. Workspace (218,841,088 B total):
//   concat : bf16 [2][576][256][256]  150,994,944 B   (9 slices of 64ch)
//   A, B   : f32  [2][64][256][256]   2 x 33,554,432 B  (ping-pong, reused at
//                                      all scales; residual adds are in-place)
//   w1t    : f32  [576][288]              663,552 B
//   w2t    : f32  [288][64]                73,728 B
// ---------------------------------------------------------------------------

#define HPX 65536   // 256*256
#define FCH 64

__device__ __forceinline__ float gelu_f(float x) {
  return 0.5f * x * (1.0f + erff(x * 0.70710678118654752440f));
}

// ---------------- conv0: base = concat(gelu(1x1(target)), gelu(3x3(feats)))
__global__ __launch_bounds__(256) void conv0_kernel(
    const float* __restrict__ img,   // [2][5][256][256]
    const float* __restrict__ w0a,   // [16][4][3][3]
    const float* __restrict__ w0b,   // [48]
    float* __restrict__ base)        // [2][64][256][256]
{
  long t = (long)blockIdx.x * 256 + threadIdx.x;   // over 2*64*65536
  int px = (int)(t & (HPX - 1));
  int c  = (int)((t >> 16) & 63);
  int n  = (int)(t >> 22);
  const float* im = img + (long)n * 5 * HPX;
  float r;
  if (c < 48) {
    r = w0b[c] * im[2 * HPX + px];
  } else {
    int co = c - 48;
    int y = px >> 8, x = px & 255;
    r = 0.0f;
    const int map4[4] = {0, 1, 3, 4};
    #pragma unroll
    for (int fi = 0; fi < 4; fi++) {
      const float* imc = im + (long)map4[fi] * HPX;
      #pragma unroll
      for (int ky = 0; ky < 3; ky++) {
        int yy = y + ky - 1;
        #pragma unroll
        for (int kx = 0; kx < 3; kx++) {
          int xx = x + kx - 1;
          bool ok = ((unsigned)yy < 256u) && ((unsigned)xx < 256u);
          float v = ok ? imc[yy * 256 + xx] : 0.0f;
          r = fmaf(w0a[((co * 4 + fi) * 3 + ky) * 3 + kx], v, r);
        }
      }
    }
  }
  base[t] = gelu_f(r);
}

// ---------------- generic 64->64 direct conv (+gelu, opt residual, opt bf16 out)
// NTAPS: 9 = full 3x3, 8 = donut. thread: 4 px x 8 oc; block: 4 waves = 32 oc.
// RESID: out may alias resid (each (o,p) is read-then-written by one thread).
template <int NTAPS, bool RESID, bool OBF16>
__global__ __launch_bounds__(256) void conv64_kernel(
    const float* __restrict__ in,     // [2][64][Hs][Ws]
    const float* __restrict__ wgt,    // [64][64][NTAPS]
    const float* __restrict__ resid,  // [2][64][Hs][Ws] or null
    void* __restrict__ outv,
    int Hs, int logW, int dil, long out_n_stride /*elements*/)
{
  const int Ws   = 1 << logW;
  const int npx  = Hs << logW;
  const int lane = threadIdx.x & 63;
  const int wave = threadIdx.x >> 6;
  const int obase = blockIdx.y * 32 + wave * 8;
  const int n = blockIdx.z;
  const float* inn = in + (long)n * FCH * npx;

  const int p0 = blockIdx.x * 256 + lane;

  int   poff[NTAPS][4];
  float pmsk[NTAPS][4];
  #pragma unroll
  for (int t = 0; t < NTAPS; t++) {
    const int kk = (NTAPS == 9) ? t : (t < 4 ? t : t + 1);
    const int dy = kk / 3 - 1, dx = kk % 3 - 1;
    const int dyd = dy * dil, dxd = dx * dil;
    #pragma unroll
    for (int k = 0; k < 4; k++) {
      int p = p0 + 64 * k;
      int y = p >> logW, x = p & (Ws - 1);
      int yy = y + dyd, xx = x + dxd;
      bool ok = ((unsigned)yy < (unsigned)Hs) && ((unsigned)xx < (unsigned)Ws);
      poff[t][k] = ok ? ((yy << logW) + xx) : 0;
      pmsk[t][k] = ok ? 1.0f : 0.0f;
    }
  }

  float acc[8][4];
  #pragma unroll
  for (int j = 0; j < 8; j++)
    #pragma unroll
    for (int k = 0; k < 4; k++) acc[j][k] = 0.0f;

  for (int ci = 0; ci < FCH; ci++) {
    const float* inc = inn + (long)ci * npx;
    const float* wc  = wgt + ((long)obase * FCH + ci) * NTAPS;
    #pragma unroll
    for (int t = 0; t < NTAPS; t++) {
      float w[8];
      #pragma unroll
      for (int j = 0; j < 8; j++) w[j] = wc[(long)j * FCH * NTAPS + t];
      float v[4];
      #pragma unroll
      for (int k = 0; k < 4; k++) v[k] = inc[poff[t][k]] * pmsk[t][k];
      #pragma unroll
      for (int j = 0; j < 8; j++)
        #pragma unroll
        for (int k = 0; k < 4; k++)
          acc[j][k] = fmaf(w[j], v[k], acc[j][k]);
    }
  }

  #pragma unroll
  for (int j = 0; j < 8; j++) {
    const int o = obase + j;
    #pragma unroll
    for (int k = 0; k < 4; k++) {
      const int p = p0 + 64 * k;
      float r = acc[j][k];
      if (RESID) r += resid[(long)n * FCH * npx + (long)o * npx + p];
      r = gelu_f(r);
      long oidx = (long)n * out_n_stride + (long)o * npx + p;
      if (OBF16) ((__hip_bfloat16*)outv)[oidx] = __float2bfloat16(r);
      else       ((float*)outv)[oidx] = r;
    }
  }
}

// ---------------- 2x2 average pool
__global__ __launch_bounds__(256) void avgpool_kernel(
    const float* __restrict__ in, float* __restrict__ out, int logWo)
{
  const int lognpo = 2 * logWo;
  long t = (long)blockIdx.x * 256 + threadIdx.x;   // over 2*64*npo
  int p  = (int)(t & ((1 << lognpo) - 1));
  long nc = t >> lognpo;
  int y = p >> logWo, x = p & ((1 << logWo) - 1);
  int Wi = 2 << logWo;
  const float* ic = in + nc * ((long)4 << lognpo);
  int b = (2 * y) * Wi + 2 * x;
  float s = ic[b] + ic[b + 1] + ic[b + Wi] + ic[b + Wi + 1];
  out[t] = 0.25f * s;
}

// ---------------- bilinear upsample (Hs->256, clamped == jax renorm) fused
// with 1x1 conv64 + gelu -> bf16 slice of concat. Hs==256 degenerates to
// identity sampling (wy=wx=0, all taps equal).
__global__ __launch_bounds__(256) void ups_kernel(
    const float* __restrict__ in,        // [2][64][Hs][Hs]
    const float* __restrict__ w,         // [64][64]
    __hip_bfloat16* __restrict__ slice,  // concat + sidx*64*HPX, n-stride 576*HPX
    int Hs)
{
  const int lane = threadIdx.x & 63;
  const int wave = threadIdx.x >> 6;
  const int obase = blockIdx.y * 32 + wave * 8;
  const int n = blockIdx.z;
  const int p0 = blockIdx.x * 256 + lane;
  const float* inn = in + (long)n * FCH * Hs * Hs;

  int o00[4], o01[4], o10[4], o11[4];
  float fwx[4], fwy[4];
  const float s = (float)Hs * (1.0f / 256.0f);
  #pragma unroll
  for (int k = 0; k < 4; k++) {
    int p = p0 + 64 * k;
    int Y = p >> 8, X = p & 255;
    float fy = ((float)Y + 0.5f) * s - 0.5f;
    float fx = ((float)X + 0.5f) * s - 0.5f;
    int y0 = (int)floorf(fy), x0 = (int)floorf(fx);
    fwy[k] = fy - (float)y0; fwx[k] = fx - (float)x0;
    int y0c = min(max(y0, 0), Hs - 1), y1c = min(max(y0 + 1, 0), Hs - 1);
    int x0c = min(max(x0, 0), Hs - 1), x1c = min(max(x0 + 1, 0), Hs - 1);
    o00[k] = y0c * Hs + x0c; o01[k] = y0c * Hs + x1c;
    o10[k] = y1c * Hs + x0c; o11[k] = y1c * Hs + x1c;
  }

  float acc[8][4];
  #pragma unroll
  for (int j = 0; j < 8; j++)
    #pragma unroll
    for (int k = 0; k < 4; k++) acc[j][k] = 0.0f;

  for (int ci = 0; ci < FCH; ci++) {
    const float* inc = inn + (long)ci * Hs * Hs;
    float v[4];
    #pragma unroll
    for (int k = 0; k < 4; k++) {
      float v00 = inc[o00[k]], v01 = inc[o01[k]];
      float v10 = inc[o10[k]], v11 = inc[o11[k]];
      float a = v00 + fwx[k] * (v01 - v00);
      float b = v10 + fwx[k] * (v11 - v10);
      v[k] = a + fwy[k] * (b - a);
    }
    float wv[8];
    #pragma unroll
    for (int j = 0; j < 8; j++) wv[j] = w[(obase + j) * FCH + ci];
    #pragma unroll
    for (int j = 0; j < 8; j++)
      #pragma unroll
      for (int k = 0; k < 4; k++)
        acc[j][k] = fmaf(wv[j], v[k], acc[j][k]);
  }

  #pragma unroll
  for (int j = 0; j < 8; j++)
    #pragma unroll
    for (int k = 0; k < 4; k++)
      slice[(long)n * 576 * HPX + (long)(obase + j) * HPX + p0 + 64 * k] =
          __float2bfloat16(gelu_f(acc[j][k]));
}

// ---------------- tiny transpose: w[R][C] -> wt[C][R]
__global__ __launch_bounds__(256) void transpose_w_kernel(
    const float* __restrict__ w, float* __restrict__ wt, int R, int C)
{
  int t = blockIdx.x * 256 + threadIdx.x;
  if (t < R * C) {
    int r = t / C, c = t % C;
    wt[c * R + r] = w[t];
  }
}

// ---------------- fused head: out = W3 @ gelu(W2 @ gelu(W1 @ concat))
// block = 256 thr, 64 px. phase1: wave w computes h[w*72 .. +72][64px] -> LDS.
// phase2: 4 lanes/px cover 64 mid-channels in chunks of 16, shuffle-reduce.
__global__ __launch_bounds__(256) void head_kernel(
    const __hip_bfloat16* __restrict__ v,  // [2][576][65536]
    const float* __restrict__ w1t,         // [576][288]
    const float* __restrict__ w2t,         // [288][64]
    const float* __restrict__ w3,          // [64]
    float* __restrict__ out)               // [2][65536]
{
  __shared__ float h[288][64];   // 73,728 B
  const int lane = threadIdx.x & 63;
  const int wave = threadIdx.x >> 6;
  const int n = blockIdx.y;
  const int pxb = blockIdx.x * 64;
  const __hip_bfloat16* vn = v + (long)n * 576 * HPX + pxb;

  { // phase 1
    const int ocb = wave * 72;
    float acc[72];
    #pragma unroll
    for (int j = 0; j < 72; j++) acc[j] = 0.0f;
    for (int ci = 0; ci < 576; ci++) {
      float x = __bfloat162float(vn[(long)ci * HPX + lane]);
      const float4* wr = (const float4*)(w1t + (long)ci * 288 + ocb);
      #pragma unroll
      for (int j4 = 0; j4 < 18; j4++) {
        float4 wv = wr[j4];
        acc[4 * j4 + 0] = fmaf(wv.x, x, acc[4 * j4 + 0]);
        acc[4 * j4 + 1] = fmaf(wv.y, x, acc[4 * j4 + 1]);
        acc[4 * j4 + 2] = fmaf(wv.z, x, acc[4 * j4 + 2]);
        acc[4 * j4 + 3] = fmaf(wv.w, x, acc[4 * j4 + 3]);
      }
    }
    #pragma unroll
    for (int j = 0; j < 72; j++) h[ocb + j][lane] = gelu_f(acc[j]);
  }
  __syncthreads();
  { // phase 2
    const int px = wave * 16 + (lane & 15);
    const int q  = lane >> 4;          // 0..3
    const int ob = q * 16;
    float acc2[16];
    #pragma unroll
    for (int j = 0; j < 16; j++) acc2[j] = 0.0f;
    for (int c = 0; c < 288; c++) {
      float hv = h[c][px];
      const float4* wr = (const float4*)(w2t + c * 64 + ob);
      #pragma unroll
      for (int j4 = 0; j4 < 4; j4++) {
        float4 wv = wr[j4];
        acc2[4 * j4 + 0] = fmaf(wv.x, hv, acc2[4 * j4 + 0]);
        acc2[4 * j4 + 1] = fmaf(wv.y, hv, acc2[4 * j4 + 1]);
        acc2[4 * j4 + 2] = fmaf(wv.z, hv, acc2[4 * j4 + 2]);
        acc2[4 * j4 + 3] = fmaf(wv.w, hv, acc2[4 * j4 + 3]);
      }
    }
    float r = 0.0f;
    #pragma unroll
    for (int j = 0; j < 16; j++) r = fmaf(w3[ob + j], gelu_f(acc2[j]), r);
    r += __shfl_xor(r, 16);
    r += __shfl_xor(r, 32);
    if (q == 0) out[(long)n * HPX + pxb + px] = r;
  }
}

// ---------------------------------------------------------------------------
// host-side helpers
// ---------------------------------------------------------------------------
static inline void conv9(const float* in, const float* w, float* out,
                         int Hs, int logW, hipStream_t s) {
  int npx = Hs << logW;
  conv64_kernel<9, false, false><<<dim3(npx / 256, 2, 2), 256, 0, s>>>(
      in, w, nullptr, out, Hs, logW, 1, (long)FCH * npx);
}
// second conv of a resblock, residual add; out aliases resid (in-place safe)
static inline void conv9r(const float* in, const float* w, float* resid_out,
                          int Hs, int logW, hipStream_t s) {
  int npx = Hs << logW;
  conv64_kernel<9, true, false><<<dim3(npx / 256, 2, 2), 256, 0, s>>>(
      in, w, resid_out, resid_out, Hs, logW, 1, (long)FCH * npx);
}
static inline void donut_f(const float* in, const float* w, float* out,
                           int Hs, int logW, int dil, hipStream_t s) {
  int npx = Hs << logW;
  conv64_kernel<8, false, false><<<dim3(npx / 256, 2, 2), 256, 0, s>>>(
      in, w, nullptr, out, Hs, logW, dil, (long)FCH * npx);
}
static inline void donut_b(const float* in, const float* w, __hip_bfloat16* slice,
                           int dil, hipStream_t s) {
  conv64_kernel<8, false, true><<<dim3(256, 2, 2), 256, 0, s>>>(
      in, w, nullptr, slice, 256, 8, dil, (long)576 * HPX);
}
static inline void ups(const float* in, const float* w, __hip_bfloat16* slice,
                       int Hs, hipStream_t s) {
  ups_kernel<<<dim3(256, 2, 2), 256, 0, s>>>(in, w, slice, Hs);
}
static inline void avgpool(const float* in, float* out, int logWo, hipStream_t s) {
  long total = (long)2 * FCH * (1L << (2 * logWo));
  avgpool_kernel<<<(int)(total / 256), 256, 0, s>>>(in, out, logWo);
}

extern "C" void kernel_launch(void* const* d_in, const int* in_sizes, int n_in,
                              void* d_out, int out_size, void* d_ws, size_t ws_size,
                              hipStream_t stream) {
  const float* img      = (const float*)d_in[0];
  const float* w0a      = (const float*)d_in[1];
  const float* w0b      = (const float*)d_in[2];
  const float* first_p  = (const float*)d_in[3];
  const float* cl10     = (const float*)d_in[4];   // [4][2][64*64*9]
  const float* cl2      = (const float*)d_in[5];
  const float* dil_p    = (const float*)d_in[6];   // [4][64*64*8]
  const float* dilres_p = (const float*)d_in[7];
  const float* ups_w    = (const float*)d_in[8];   // [4][64*64]
  const float* w1       = (const float*)d_in[9];   // [288][576]
  const float* w2       = (const float*)d_in[10];  // [64][288]
  const float* w3       = (const float*)d_in[11];  // [64]

  const size_t CONCAT_B = 150994944ul;             // 2*576*65536*2
  const size_t PBUF_B   = 33554432ul;              // 2*64*65536*4
  const size_t W1T_B    = 576ul * 288 * 4;
  const size_t W2T_B    = 288ul * 64 * 4;
  const size_t NEED = CONCAT_B + 2 * PBUF_B + W1T_B + W2T_B;  // 218,841,088

  if (ws_size < NEED) {
    // diagnostic fallback: clean absmax failure instead of a page fault
    hipMemsetAsync(d_out, 0, (size_t)out_size * 4, stream);
    return;
  }

  char* wsb = (char*)d_ws;
  __hip_bfloat16* concat = (__hip_bfloat16*)wsb;
  float* A   = (float*)(wsb + CONCAT_B);
  float* B   = (float*)(wsb + CONCAT_B + PBUF_B);
  float* w1t = (float*)(wsb + CONCAT_B + 2 * PBUF_B);
  float* w2t = (float*)(wsb + CONCAT_B + 2 * PBUF_B + W1T_B);

  auto SL = [&](int sidx) { return concat + (long)sidx * FCH * HPX; };
  const int C9 = 64 * 64 * 9, C8 = 64 * 64 * 8, C1 = 64 * 64;

  transpose_w_kernel<<<(288 * 576 + 255) / 256, 256, 0, stream>>>(w1, w1t, 288, 576);
  transpose_w_kernel<<<(64 * 288 + 255) / 256, 256, 0, stream>>>(w2, w2t, 64, 288);

  conv0_kernel<<<(2 * FCH * HPX) / 256, 256, 0, stream>>>(img, w0a, w0b, A);

  // outs[0]; base = resblock(base, cl10[0]); outs[1]; base = resblock(base, cl2[0])
  donut_b(A, first_p, SL(0), 1, stream);
  conv9(A, cl10 + 0 * C9, B, 256, 8, stream);
  conv9r(B, cl10 + 1 * C9, A, 256, 8, stream);               // base = A @256
  donut_b(A, dilres_p + 0 * C8, SL(1), 3, stream);
  conv9(A, cl2 + 0 * C9, B, 256, 8, stream);
  conv9r(B, cl2 + 1 * C9, A, 256, 8, stream);                // base = A @256

  // ---- i = 0 (dil 5 @256)
  donut_f(A, dil_p + 0 * C8, B, 256, 8, 5, stream);
  ups(B, ups_w + 0 * C1, SL(2), 256, stream);                // scale 1 (identity)
  avgpool(A, B, 7, stream);                                  // base = B @128
  conv9(B, cl10 + 2 * C9, A, 128, 7, stream);
  conv9r(A, cl10 + 3 * C9, B, 128, 7, stream);               // base = B @128
  donut_f(B, dilres_p + 1 * C8, A, 128, 7, 6, stream);
  ups(A, ups_w + 1 * C1, SL(3), 128, stream);
  conv9(B, cl2 + 2 * C9, A, 128, 7, stream);
  conv9r(A, cl2 + 3 * C9, B, 128, 7, stream);                // base = B @128

  // ---- i = 1 (dil 8 @128)
  donut_f(B, dil_p + 1 * C8, A, 128, 7, 8, stream);
  ups(A, ups_w + 1 * C1, SL(4), 128, stream);
  avgpool(B, A, 6, stream);                                  // base = A @64
  conv9(A, cl10 + 4 * C9, B, 64, 6, stream);
  conv9r(B, cl10 + 5 * C9, A, 64, 6, stream);                // base = A @64
  donut_f(A, dilres_p + 2 * C8, B, 64, 6, 8, stream);
  ups(B, ups_w + 2 * C1, SL(5), 64, stream);
  conv9(A, cl2 + 4 * C9, B, 64, 6, stream);
  conv9r(B, cl2 + 5 * C9, A, 64, 6, stream);                 // base = A @64

  // ---- i = 2 (dil 10 @64)
  donut_f(A, dil_p + 2 * C8, B, 64, 6, 10, stream);
  ups(B, ups_w + 2 * C1, SL(6), 64, stream);
  avgpool(A, B, 5, stream);                                  // base = B @32
  conv9(B, cl10 + 6 * C9, A, 32, 5, stream);
  conv9r(A, cl10 + 7 * C9, B, 32, 5, stream);                // base = B @32
  donut_f(B, dilres_p + 3 * C8, A, 32, 5, 9, stream);
  ups(A, ups_w + 3 * C1, SL(7), 32, stream);
  conv9(B, cl2 + 6 * C9, A, 32, 5, stream);
  conv9r(A, cl2 + 7 * C9, B, 32, 5, stream);                 // base = B @32

  // ---- i = 3 (dil 11 @32)
  donut_f(B, dil_p + 3 * C8, A, 32, 5, 11, stream);
  ups(A, ups_w + 3 * C1, SL(8), 32, stream);

  // ---- fused head
  head_kernel<<<dim3(1024, 2), 256, 0, stream>>>(concat, w1t, w2t, w3,
                                                 (float*)d_out);
}

// Round 5
// 6383.975 us; speedup vs baseline: 1.0019x; 1.0001x over previous
//
#include <hip/hip_runtime.h>
#include <hip/hip_bf16.h>

// ---------------------------------------------------------------------------
// SHINE forward, fp32 direct-conv. Workspace (218,841,088 B total):
//   concat : bf16 [2][576][256][256]  150,994,944 B   (9 slices of 64ch)
//   A, B   : f32  [2][64][256][256]   2 x 33,554,432 B  (ping-pong, reused at
//                                      all scales; residual adds are in-place)
//   w1t    : f32  [576][288]              663,552 B
//   w2t    : f32  [288][64]                73,728 B
// ---------------------------------------------------------------------------

#define HPX 65536   // 256*256
#define FCH 64

__device__ __forceinline__ float gelu_f(float x) {
  return 0.5f * x * (1.0f + erff(x * 0.70710678118654752440f));
}

// ---------------- conv0: base = concat(gelu(1x1(target)), gelu(3x3(feats)))
__global__ __launch_bounds__(256) void conv0_kernel(
    const float* __restrict__ img,   // [2][5][256][256]
    const float* __restrict__ w0a,   // [16][4][3][3]
    const float* __restrict__ w0b,   // [48]
    float* __restrict__ base)        // [2][64][256][256]
{
  long t = (long)blockIdx.x * 256 + threadIdx.x;   // over 2*64*65536
  int px = (int)(t & (HPX - 1));
  int c  = (int)((t >> 16) & 63);
  int n  = (int)(t >> 22);
  const float* im = img + (long)n * 5 * HPX;
  float r;
  if (c < 48) {
    r = w0b[c] * im[2 * HPX + px];
  } else {
    int co = c - 48;
    int y = px >> 8, x = px & 255;
    r = 0.0f;
    const int map4[4] = {0, 1, 3, 4};
    #pragma unroll
    for (int fi = 0; fi < 4; fi++) {
      const float* imc = im + (long)map4[fi] * HPX;
      #pragma unroll
      for (int ky = 0; ky < 3; ky++) {
        int yy = y + ky - 1;
        #pragma unroll
        for (int kx = 0; kx < 3; kx++) {
          int xx = x + kx - 1;
          bool ok = ((unsigned)yy < 256u) && ((unsigned)xx < 256u);
          float v = ok ? imc[yy * 256 + xx] : 0.0f;
          r = fmaf(w0a[((co * 4 + fi) * 3 + ky) * 3 + kx], v, r);
        }
      }
    }
  }
  base[t] = gelu_f(r);
}

// ---------------- generic 64->64 direct conv (+gelu, opt residual, opt bf16 out)
// NTAPS: 9 = full 3x3, 8 = donut. thread: 4 px x 8 oc; block: 4 waves = 32 oc.
// RESID: out may alias resid (each (o,p) is read-then-written by one thread).
template <int NTAPS, bool RESID, bool OBF16>
__global__ __launch_bounds__(256) void conv64_kernel(
    const float* __restrict__ in,     // [2][64][Hs][Ws]
    const float* __restrict__ wgt,    // [64][64][NTAPS]
    const float* __restrict__ resid,  // [2][64][Hs][Ws] or null
    void* __restrict__ outv,
    int Hs, int logW, int dil, long out_n_stride /*elements*/)
{
  const int Ws   = 1 << logW;
  const int npx  = Hs << logW;
  const int lane = threadIdx.x & 63;
  const int wave = threadIdx.x >> 6;
  const int obase = blockIdx.y * 32 + wave * 8;
  const int n = blockIdx.z;
  const float* inn = in + (long)n * FCH * npx;

  const int p0 = blockIdx.x * 256 + lane;

  int   poff[NTAPS][4];
  float pmsk[NTAPS][4];
  #pragma unroll
  for (int t = 0; t < NTAPS; t++) {
    const int kk = (NTAPS == 9) ? t : (t < 4 ? t : t + 1);
    const int dy = kk / 3 - 1, dx = kk % 3 - 1;
    const int dyd = dy * dil, dxd = dx * dil;
    #pragma unroll
    for (int k = 0; k < 4; k++) {
      int p = p0 + 64 * k;
      int y = p >> logW, x = p & (Ws - 1);
      int yy = y + dyd, xx = x + dxd;
      bool ok = ((unsigned)yy < (unsigned)Hs) && ((unsigned)xx < (unsigned)Ws);
      poff[t][k] = ok ? ((yy << logW) + xx) : 0;
      pmsk[t][k] = ok ? 1.0f : 0.0f;
    }
  }

  float acc[8][4];
  #pragma unroll
  for (int j = 0; j < 8; j++)
    #pragma unroll
    for (int k = 0; k < 4; k++) acc[j][k] = 0.0f;

  for (int ci = 0; ci < FCH; ci++) {
    const float* inc = inn + (long)ci * npx;
    const float* wc  = wgt + ((long)obase * FCH + ci) * NTAPS;
    #pragma unroll
    for (int t = 0; t < NTAPS; t++) {
      float w[8];
      #pragma unroll
      for (int j = 0; j < 8; j++) w[j] = wc[(long)j * FCH * NTAPS + t];
      float v[4];
      #pragma unroll
      for (int k = 0; k < 4; k++) v[k] = inc[poff[t][k]] * pmsk[t][k];
      #pragma unroll
      for (int j = 0; j < 8; j++)
        #pragma unroll
        for (int k = 0; k < 4; k++)
          acc[j][k] = fmaf(w[j], v[k], acc[j][k]);
    }
  }

  #pragma unroll
  for (int j = 0; j < 8; j++) {
    const int o = obase + j;
    #pragma unroll
    for (int k = 0; k < 4; k++) {
      const int p = p0 + 64 * k;
      float r = acc[j][k];
      if (RESID) r += resid[(long)n * FCH * npx + (long)o * npx + p];
      r = gelu_f(r);
      long oidx = (long)n * out_n_stride + (long)o * npx + p;
      if (OBF16) ((__hip_bfloat16*)outv)[oidx] = __float2bfloat16(r);
      else       ((float*)outv)[oidx] = r;
    }
  }
}

// ---------------- 2x2 average pool
__global__ __launch_bounds__(256) void avgpool_kernel(
    const float* __restrict__ in, float* __restrict__ out, int logWo)
{
  const int lognpo = 2 * logWo;
  long t = (long)blockIdx.x * 256 + threadIdx.x;   // over 2*64*npo
  int p  = (int)(t & ((1 << lognpo) - 1));
  long nc = t >> lognpo;
  int y = p >> logWo, x = p & ((1 << logWo) - 1);
  int Wi = 2 << logWo;
  const float* ic = in + nc * ((long)4 << lognpo);
  int b = (2 * y) * Wi + 2 * x;
  float s = ic[b] + ic[b + 1] + ic[b + Wi] + ic[b + Wi + 1];
  out[t] = 0.25f * s;
}

// ---------------- bilinear upsample (Hs->256, clamped == jax renorm) fused
// with 1x1 conv64 + gelu -> bf16 slice of concat. Hs==256 degenerates to
// identity sampling (wy=wx=0, all taps equal).
__global__ __launch_bounds__(256) void ups_kernel(
    const float* __restrict__ in,        // [2][64][Hs][Hs]
    const float* __restrict__ w,         // [64][64]
    __hip_bfloat16* __restrict__ slice,  // concat + sidx*64*HPX, n-stride 576*HPX
    int Hs)
{
  const int lane = threadIdx.x & 63;
  const int wave = threadIdx.x >> 6;
  const int obase = blockIdx.y * 32 + wave * 8;
  const int n = blockIdx.z;
  const int p0 = blockIdx.x * 256 + lane;
  const float* inn = in + (long)n * FCH * Hs * Hs;

  int o00[4], o01[4], o10[4], o11[4];
  float fwx[4], fwy[4];
  const float s = (float)Hs * (1.0f / 256.0f);
  #pragma unroll
  for (int k = 0; k < 4; k++) {
    int p = p0 + 64 * k;
    int Y = p >> 8, X = p & 255;
    float fy = ((float)Y + 0.5f) * s - 0.5f;
    float fx = ((float)X + 0.5f) * s - 0.5f;
    int y0 = (int)floorf(fy), x0 = (int)floorf(fx);
    fwy[k] = fy - (float)y0; fwx[k] = fx - (float)x0;
    int y0c = min(max(y0, 0), Hs - 1), y1c = min(max(y0 + 1, 0), Hs - 1);
    int x0c = min(max(x0, 0), Hs - 1), x1c = min(max(x0 + 1, 0), Hs - 1);
    o00[k] = y0c * Hs + x0c; o01[k] = y0c * Hs + x1c;
    o10[k] = y1c * Hs + x0c; o11[k] = y1c * Hs + x1c;
  }

  float acc[8][4];
  #pragma unroll
  for (int j = 0; j < 8; j++)
    #pragma unroll
    for (int k = 0; k < 4; k++) acc[j][k] = 0.0f;

  for (int ci = 0; ci < FCH; ci++) {
    const float* inc = inn + (long)ci * Hs * Hs;
    float v[4];
    #pragma unroll
    for (int k = 0; k < 4; k++) {
      float v00 = inc[o00[k]], v01 = inc[o01[k]];
      float v10 = inc[o10[k]], v11 = inc[o11[k]];
      float a = v00 + fwx[k] * (v01 - v00);
      float b = v10 + fwx[k] * (v11 - v10);
      v[k] = a + fwy[k] * (b - a);
    }
    float wv[8];
    #pragma unroll
    for (int j = 0; j < 8; j++) wv[j] = w[(obase + j) * FCH + ci];
    #pragma unroll
    for (int j = 0; j < 8; j++)
      #pragma unroll
      for (int k = 0; k < 4; k++)
        acc[j][k] = fmaf(wv[j], v[k], acc[j][k]);
  }

  #pragma unroll
  for (int j = 0; j < 8; j++)
    #pragma unroll
    for (int k = 0; k < 4; k++)
      slice[(long)n * 576 * HPX + (long)(obase + j) * HPX + p0 + 64 * k] =
          __float2bfloat16(gelu_f(acc[j][k]));
}

// ---------------- tiny transpose: w[R][C] -> wt[C][R]
__global__ __launch_bounds__(256) void transpose_w_kernel(
    const float* __restrict__ w, float* __restrict__ wt, int R, int C)
{
  int t = blockIdx.x * 256 + threadIdx.x;
  if (t < R * C) {
    int r = t / C, c = t % C;
    wt[c * R + r] = w[t];
  }
}

// ---------------- fused head: out = W3 @ gelu(W2 @ gelu(W1 @ concat))
// block = 256 thr, 64 px. phase1: wave w computes h[w*72 .. +72][64px] -> LDS.
// phase2: 4 lanes/px cover 64 mid-channels in chunks of 16, shuffle-reduce.
__global__ __launch_bounds__(256) void head_kernel(
    const __hip_bfloat16* __restrict__ v,  // [2][576][65536]
    const float* __restrict__ w1t,         // [576][288]
    const float* __restrict__ w2t,         // [288][64]
    const float* __restrict__ w3,          // [64]
    float* __restrict__ out)               // [2][65536]
{
  __shared__ float h[288][64];   // 73,728 B
  const int lane = threadIdx.x & 63;
  const int wave = threadIdx.x >> 6;
  const int n = blockIdx.y;
  const int pxb = blockIdx.x * 64;
  const __hip_bfloat16* vn = v + (long)n * 576 * HPX + pxb;

  { // phase 1
    const int ocb = wave * 72;
    float acc[72];
    #pragma unroll
    for (int j = 0; j < 72; j++) acc[j] = 0.0f;
    for (int ci = 0; ci < 576; ci++) {
      float x = __bfloat162float(vn[(long)ci * HPX + lane]);
      const float4* wr = (const float4*)(w1t + (long)ci * 288 + ocb);
      #pragma unroll
      for (int j4 = 0; j4 < 18; j4++) {
        float4 wv = wr[j4];
        acc[4 * j4 + 0] = fmaf(wv.x, x, acc[4 * j4 + 0]);
        acc[4 * j4 + 1] = fmaf(wv.y, x, acc[4 * j4 + 1]);
        acc[4 * j4 + 2] = fmaf(wv.z, x, acc[4 * j4 + 2]);
        acc[4 * j4 + 3] = fmaf(wv.w, x, acc[4 * j4 + 3]);
      }
    }
    #pragma unroll
    for (int j = 0; j < 72; j++) h[ocb + j][lane] = gelu_f(acc[j]);
  }
  __syncthreads();
  { // phase 2
    const int px = wave * 16 + (lane & 15);
    const int q  = lane >> 4;          // 0..3
    const int ob = q * 16;
    float acc2[16];
    #pragma unroll
    for (int j = 0; j < 16; j++) acc2[j] = 0.0f;
    for (int c = 0; c < 288; c++) {
      float hv = h[c][px];
      const float4* wr = (const float4*)(w2t + c * 64 + ob);
      #pragma unroll
      for (int j4 = 0; j4 < 4; j4++) {
        float4 wv = wr[j4];
        acc2[4 * j4 + 0] = fmaf(wv.x, hv, acc2[4 * j4 + 0]);
        acc2[4 * j4 + 1] = fmaf(wv.y, hv, acc2[4 * j4 + 1]);
        acc2[4 * j4 + 2] = fmaf(wv.z, hv, acc2[4 * j4 + 2]);
        acc2[4 * j4 + 3] = fmaf(wv.w, hv, acc2[4 * j4 + 3]);
      }
    }
    float r = 0.0f;
    #pragma unroll
    for (int j = 0; j < 16; j++) r = fmaf(w3[ob + j], gelu_f(acc2[j]), r);
    r += __shfl_xor(r, 16);
    r += __shfl_xor(r, 32);
    if (q == 0) out[(long)n * HPX + pxb + px] = r;
  }
}

// ---------------------------------------------------------------------------
// host-side helpers
// ---------------------------------------------------------------------------
static inline void conv9(const float* in, const float* w, float* out,
                         int Hs, int logW, hipStream_t s) {
  int npx = Hs << logW;
  conv64_kernel<9, false, false><<<dim3(npx / 256, 2, 2), 256, 0, s>>>(
      in, w, nullptr, out, Hs, logW, 1, (long)FCH * npx);
}
// second conv of a resblock, residual add; out aliases resid (in-place safe)
static inline void conv9r(const float* in, const float* w, float* resid_out,
                          int Hs, int logW, hipStream_t s) {
  int npx = Hs << logW;
  conv64_kernel<9, true, false><<<dim3(npx / 256, 2, 2), 256, 0, s>>>(
      in, w, resid_out, resid_out, Hs, logW, 1, (long)FCH * npx);
}
static inline void donut_f(const float* in, const float* w, float* out,
                           int Hs, int logW, int dil, hipStream_t s) {
  int npx = Hs << logW;
  conv64_kernel<8, false, false><<<dim3(npx / 256, 2, 2), 256, 0, s>>>(
      in, w, nullptr, out, Hs, logW, dil, (long)FCH * npx);
}
static inline void donut_b(const float* in, const float* w, __hip_bfloat16* slice,
                           int dil, hipStream_t s) {
  conv64_kernel<8, false, true><<<dim3(256, 2, 2), 256, 0, s>>>(
      in, w, nullptr, slice, 256, 8, dil, (long)576 * HPX);
}
static inline void ups(const float* in, const float* w, __hip_bfloat16* slice,
                       int Hs, hipStream_t s) {
  ups_kernel<<<dim3(256, 2, 2), 256, 0, s>>>(in, w, slice, Hs);
}
static inline void avgpool(const float* in, float* out, int logWo, hipStream_t s) {
  long total = (long)2 * FCH * (1L << (2 * logWo));
  avgpool_kernel<<<(int)(total / 256), 256, 0, s>>>(in, out, logWo);
}

extern "C" void kernel_launch(void* const* d_in, const int* in_sizes, int n_in,
                              void* d_out, int out_size, void* d_ws, size_t ws_size,
                              hipStream_t stream) {
  const float* img      = (const float*)d_in[0];
  const float* w0a      = (const float*)d_in[1];
  const float* w0b      = (const float*)d_in[2];
  const float* first_p  = (const float*)d_in[3];
  const float* cl10     = (const float*)d_in[4];   // [4][2][64*64*9]
  const float* cl2      = (const float*)d_in[5];
  const float* dil_p    = (const float*)d_in[6];   // [4][64*64*8]
  const float* dilres_p = (const float*)d_in[7];
  const float* ups_w    = (const float*)d_in[8];   // [4][64*64]
  const float* w1       = (const float*)d_in[9];   // [288][576]
  const float* w2       = (const float*)d_in[10];  // [64][288]
  const float* w3       = (const float*)d_in[11];  // [64]

  const size_t CONCAT_B = 150994944ul;             // 2*576*65536*2
  const size_t PBUF_B   = 33554432ul;              // 2*64*65536*4
  const size_t W1T_B    = 576ul * 288 * 4;
  const size_t W2T_B    = 288ul * 64 * 4;
  const size_t NEED = CONCAT_B + 2 * PBUF_B + W1T_B + W2T_B;  // 218,841,088

  if (ws_size < NEED) {
    // diagnostic fallback: clean absmax failure instead of a page fault
    hipMemsetAsync(d_out, 0, (size_t)out_size * 4, stream);
    return;
  }

  char* wsb = (char*)d_ws;
  __hip_bfloat16* concat = (__hip_bfloat16*)wsb;
  float* A   = (float*)(wsb + CONCAT_B);
  float* B   = (float*)(wsb + CONCAT_B + PBUF_B);
  float* w1t = (float*)(wsb + CONCAT_B + 2 * PBUF_B);
  float* w2t = (float*)(wsb + CONCAT_B + 2 * PBUF_B + W1T_B);

  auto SL = [&](int sidx) { return concat + (long)sidx * FCH * HPX; };
  const int C9 = 64 * 64 * 9, C8 = 64 * 64 * 8, C1 = 64 * 64;

  transpose_w_kernel<<<(288 * 576 + 255) / 256, 256, 0, stream>>>(w1, w1t, 288, 576);
  transpose_w_kernel<<<(64 * 288 + 255) / 256, 256, 0, stream>>>(w2, w2t, 64, 288);

  conv0_kernel<<<(2 * FCH * HPX) / 256, 256, 0, stream>>>(img, w0a, w0b, A);

  // outs[0]; base = resblock(base, cl10[0]); outs[1]; base = resblock(base, cl2[0])
  donut_b(A, first_p, SL(0), 1, stream);
  conv9(A, cl10 + 0 * C9, B, 256, 8, stream);
  conv9r(B, cl10 + 1 * C9, A, 256, 8, stream);               // base = A @256
  donut_b(A, dilres_p + 0 * C8, SL(1), 3, stream);
  conv9(A, cl2 + 0 * C9, B, 256, 8, stream);
  conv9r(B, cl2 + 1 * C9, A, 256, 8, stream);                // base = A @256

  // ---- i = 0 (dil 5 @256)
  donut_f(A, dil_p + 0 * C8, B, 256, 8, 5, stream);
  ups(B, ups_w + 0 * C1, SL(2), 256, stream);                // scale 1 (identity)
  avgpool(A, B, 7, stream);                                  // base = B @128
  conv9(B, cl10 + 2 * C9, A, 128, 7, stream);
  conv9r(A, cl10 + 3 * C9, B, 128, 7, stream);               // base = B @128
  donut_f(B, dilres_p + 1 * C8, A, 128, 7, 6, stream);
  ups(A, ups_w + 1 * C1, SL(3), 128, stream);
  conv9(B, cl2 + 2 * C9, A, 128, 7, stream);
  conv9r(A, cl2 + 3 * C9, B, 128, 7, stream);                // base = B @128

  // ---- i = 1 (dil 8 @128)
  donut_f(B, dil_p + 1 * C8, A, 128, 7, 8, stream);
  ups(A, ups_w + 1 * C1, SL(4), 128, stream);
  avgpool(B, A, 6, stream);                                  // base = A @64
  conv9(A, cl10 + 4 * C9, B, 64, 6, stream);
  conv9r(B, cl10 + 5 * C9, A, 64, 6, stream);                // base = A @64
  donut_f(A, dilres_p + 2 * C8, B, 64, 6, 8, stream);
  ups(B, ups_w + 2 * C1, SL(5), 64, stream);
  conv9(A, cl2 + 4 * C9, B, 64, 6, stream);
  conv9r(B, cl2 + 5 * C9, A, 64, 6, stream);                 // base = A @64

  // ---- i = 2 (dil 10 @64)
  donut_f(A, dil_p + 2 * C8, B, 64, 6, 10, stream);
  ups(B, ups_w + 2 * C1, SL(6), 64, stream);
  avgpool(A, B, 5, stream);                                  // base = B @32
  conv9(B, cl10 + 6 * C9, A, 32, 5, stream);
  conv9r(A, cl10 + 7 * C9, B, 32, 5, stream);                // base = B @32
  donut_f(B, dilres_p + 3 * C8, A, 32, 5, 9, stream);
  ups(A, ups_w + 3 * C1, SL(7), 32, stream);
  conv9(B, cl2 + 6 * C9, A, 32, 5, stream);
  conv9r(A, cl2 + 7 * C9, B, 32, 5, stream);                 // base = B @32

  // ---- i = 3 (dil 11 @32)
  donut_f(B, dil_p + 3 * C8, A, 32, 5, 11, stream);
  ups(A, ups_w + 3 * C1, SL(8), 32, stream);

  // ---- fused head
  head_kernel<<<dim3(1024, 2), 256, 0, stream>>>(concat, w1t, w2t, w3,
                                                 (float*)d_out);
}

// Round 6
// 4074.885 us; speedup vs baseline: 1.5697x; 1.5667x over previous
//
#include <hip/hip_runtime.h>
#include <hip/hip_bf16.h>

// ---------------------------------------------------------------------------
// SHINE forward. Workspace (218,914,816 B total):
//   concat : bf16 [2][576][256][256]  150,994,944 B   (9 slices of 64ch)
//   A, B   : f32  [2][64][256][256]   2 x 33,554,432 B  (ping-pong)
//   w1p    : bf16 packed MFMA frags [18kt][18mt][2(hi,lo)][64][8]  663,552 B
//   w2p    : bf16 packed MFMA frags [9kt][4ot][2(hi,lo)][64][8]    147,456 B
// Head = MFMA (16x16x32 bf16); weights split hi+lo to kill rounding error.
// ---------------------------------------------------------------------------

#define HPX 65536   // 256*256
#define FCH 64

typedef __attribute__((ext_vector_type(8))) short  short8;
typedef __attribute__((ext_vector_type(4))) float  floatx4;

__device__ __forceinline__ float gelu_f(float x) {
  return 0.5f * x * (1.0f + erff(x * 0.70710678118654752440f));
}
__device__ __forceinline__ unsigned short f2bf(float x) {  // RNE
  unsigned u = __float_as_uint(x);
  unsigned r = (u + 0x7FFFu + ((u >> 16) & 1u)) >> 16;
  return (unsigned short)r;
}
__device__ __forceinline__ float bf2f(unsigned short h) {
  return __uint_as_float(((unsigned)h) << 16);
}

// ---------------- conv0: base = concat(gelu(1x1(target)), gelu(3x3(feats)))
__global__ __launch_bounds__(256) void conv0_kernel(
    const float* __restrict__ img,   // [2][5][256][256]
    const float* __restrict__ w0a,   // [16][4][3][3]
    const float* __restrict__ w0b,   // [48]
    float* __restrict__ base)        // [2][64][256][256]
{
  long t = (long)blockIdx.x * 256 + threadIdx.x;
  int px = (int)(t & (HPX - 1));
  int c  = (int)((t >> 16) & 63);
  int n  = (int)(t >> 22);
  const float* im = img + (long)n * 5 * HPX;
  float r;
  if (c < 48) {
    r = w0b[c] * im[2 * HPX + px];
  } else {
    int co = c - 48;
    int y = px >> 8, x = px & 255;
    r = 0.0f;
    const int map4[4] = {0, 1, 3, 4};
    #pragma unroll
    for (int fi = 0; fi < 4; fi++) {
      const float* imc = im + (long)map4[fi] * HPX;
      #pragma unroll
      for (int ky = 0; ky < 3; ky++) {
        int yy = y + ky - 1;
        #pragma unroll
        for (int kx = 0; kx < 3; kx++) {
          int xx = x + kx - 1;
          bool ok = ((unsigned)yy < 256u) && ((unsigned)xx < 256u);
          float v = ok ? imc[yy * 256 + xx] : 0.0f;
          r = fmaf(w0a[((co * 4 + fi) * 3 + ky) * 3 + kx], v, r);
        }
      }
    }
  }
  base[t] = gelu_f(r);
}

// ---------------- generic 64->64 direct conv (+gelu, opt residual, opt bf16 out)
template <int NTAPS, bool RESID, bool OBF16>
__global__ __launch_bounds__(256) void conv64_kernel(
    const float* __restrict__ in,
    const float* __restrict__ wgt,    // [64][64][NTAPS]
    const float* __restrict__ resid,
    void* __restrict__ outv,
    int Hs, int logW, int dil, long out_n_stride)
{
  const int Ws   = 1 << logW;
  const int npx  = Hs << logW;
  const int lane = threadIdx.x & 63;
  const int wave = threadIdx.x >> 6;
  const int obase = blockIdx.y * 32 + wave * 8;
  const int n = blockIdx.z;
  const float* inn = in + (long)n * FCH * npx;

  const int p0 = blockIdx.x * 256 + lane;

  int   poff[NTAPS][4];
  float pmsk[NTAPS][4];
  #pragma unroll
  for (int t = 0; t < NTAPS; t++) {
    const int kk = (NTAPS == 9) ? t : (t < 4 ? t : t + 1);
    const int dy = kk / 3 - 1, dx = kk % 3 - 1;
    const int dyd = dy * dil, dxd = dx * dil;
    #pragma unroll
    for (int k = 0; k < 4; k++) {
      int p = p0 + 64 * k;
      int y = p >> logW, x = p & (Ws - 1);
      int yy = y + dyd, xx = x + dxd;
      bool ok = ((unsigned)yy < (unsigned)Hs) && ((unsigned)xx < (unsigned)Ws);
      poff[t][k] = ok ? ((yy << logW) + xx) : 0;
      pmsk[t][k] = ok ? 1.0f : 0.0f;
    }
  }

  float acc[8][4];
  #pragma unroll
  for (int j = 0; j < 8; j++)
    #pragma unroll
    for (int k = 0; k < 4; k++) acc[j][k] = 0.0f;

  for (int ci = 0; ci < FCH; ci++) {
    const float* inc = inn + (long)ci * npx;
    const float* wc  = wgt + ((long)obase * FCH + ci) * NTAPS;
    #pragma unroll
    for (int t = 0; t < NTAPS; t++) {
      float w[8];
      #pragma unroll
      for (int j = 0; j < 8; j++) w[j] = wc[(long)j * FCH * NTAPS + t];
      float v[4];
      #pragma unroll
      for (int k = 0; k < 4; k++) v[k] = inc[poff[t][k]] * pmsk[t][k];
      #pragma unroll
      for (int j = 0; j < 8; j++)
        #pragma unroll
        for (int k = 0; k < 4; k++)
          acc[j][k] = fmaf(w[j], v[k], acc[j][k]);
    }
  }

  #pragma unroll
  for (int j = 0; j < 8; j++) {
    const int o = obase + j;
    #pragma unroll
    for (int k = 0; k < 4; k++) {
      const int p = p0 + 64 * k;
      float r = acc[j][k];
      if (RESID) r += resid[(long)n * FCH * npx + (long)o * npx + p];
      r = gelu_f(r);
      long oidx = (long)n * out_n_stride + (long)o * npx + p;
      if (OBF16) ((__hip_bfloat16*)outv)[oidx] = __float2bfloat16(r);
      else       ((float*)outv)[oidx] = r;
    }
  }
}

// ---------------- 2x2 average pool
__global__ __launch_bounds__(256) void avgpool_kernel(
    const float* __restrict__ in, float* __restrict__ out, int logWo)
{
  const int lognpo = 2 * logWo;
  long t = (long)blockIdx.x * 256 + threadIdx.x;
  int p  = (int)(t & ((1 << lognpo) - 1));
  long nc = t >> lognpo;
  int y = p >> logWo, x = p & ((1 << logWo) - 1);
  int Wi = 2 << logWo;
  const float* ic = in + nc * ((long)4 << lognpo);
  int b = (2 * y) * Wi + 2 * x;
  float s = ic[b] + ic[b + 1] + ic[b + Wi] + ic[b + Wi + 1];
  out[t] = 0.25f * s;
}

// ---------------- bilinear upsample fused with 1x1 conv64 + gelu -> bf16 slice
__global__ __launch_bounds__(256) void ups_kernel(
    const float* __restrict__ in,        // [2][64][Hs][Hs]
    const float* __restrict__ w,         // [64][64]
    __hip_bfloat16* __restrict__ slice,
    int Hs)
{
  const int lane = threadIdx.x & 63;
  const int wave = threadIdx.x >> 6;
  const int obase = blockIdx.y * 32 + wave * 8;
  const int n = blockIdx.z;
  const int p0 = blockIdx.x * 256 + lane;
  const float* inn = in + (long)n * FCH * Hs * Hs;

  int o00[4], o01[4], o10[4], o11[4];
  float fwx[4], fwy[4];
  const float s = (float)Hs * (1.0f / 256.0f);
  #pragma unroll
  for (int k = 0; k < 4; k++) {
    int p = p0 + 64 * k;
    int Y = p >> 8, X = p & 255;
    float fy = ((float)Y + 0.5f) * s - 0.5f;
    float fx = ((float)X + 0.5f) * s - 0.5f;
    int y0 = (int)floorf(fy), x0 = (int)floorf(fx);
    fwy[k] = fy - (float)y0; fwx[k] = fx - (float)x0;
    int y0c = min(max(y0, 0), Hs - 1), y1c = min(max(y0 + 1, 0), Hs - 1);
    int x0c = min(max(x0, 0), Hs - 1), x1c = min(max(x0 + 1, 0), Hs - 1);
    o00[k] = y0c * Hs + x0c; o01[k] = y0c * Hs + x1c;
    o10[k] = y1c * Hs + x0c; o11[k] = y1c * Hs + x1c;
  }

  float acc[8][4];
  #pragma unroll
  for (int j = 0; j < 8; j++)
    #pragma unroll
    for (int k = 0; k < 4; k++) acc[j][k] = 0.0f;

  for (int ci = 0; ci < FCH; ci++) {
    const float* inc = inn + (long)ci * Hs * Hs;
    float v[4];
    #pragma unroll
    for (int k = 0; k < 4; k++) {
      float v00 = inc[o00[k]], v01 = inc[o01[k]];
      float v10 = inc[o10[k]], v11 = inc[o11[k]];
      float a = v00 + fwx[k] * (v01 - v00);
      float b = v10 + fwx[k] * (v11 - v10);
      v[k] = a + fwy[k] * (b - a);
    }
    float wv[8];
    #pragma unroll
    for (int j = 0; j < 8; j++) wv[j] = w[(obase + j) * FCH + ci];
    #pragma unroll
    for (int j = 0; j < 8; j++)
      #pragma unroll
      for (int k = 0; k < 4; k++)
        acc[j][k] = fmaf(wv[j], v[k], acc[j][k]);
  }

  #pragma unroll
  for (int j = 0; j < 8; j++)
    #pragma unroll
    for (int k = 0; k < 4; k++)
      slice[(long)n * 576 * HPX + (long)(obase + j) * HPX + p0 + 64 * k] =
          __float2bfloat16(gelu_f(acc[j][k]));
}

// ---------------- weight packing into MFMA B-fragment layout (hi+lo bf16)
// B-frag for 16x16x32: lane l holds B[k][col]: col=l&15, k=kt*32+(l>>4)*8+j.
// w1: [288][576] -> w1p[((kt*18+mt)*2+s)*512 + l*8 + j], oc=mt*16+col, k as above.
__global__ __launch_bounds__(256) void pack_w1_kernel(
    const float* __restrict__ w1, unsigned short* __restrict__ w1p)
{
  int t = blockIdx.x * 256 + threadIdx.x;      // 18*18*512 = 165,888
  if (t >= 18 * 18 * 512) return;
  int j = t & 7, l = (t >> 3) & 63;
  int mt = (t >> 9) % 18, kt = (t >> 9) / 18;
  int oc = mt * 16 + (l & 15);
  int k  = kt * 32 + (l >> 4) * 8 + j;
  float w = w1[oc * 576 + k];
  unsigned short hi = f2bf(w);
  unsigned short lo = f2bf(w - bf2f(hi));
  long base = ((long)(kt * 18 + mt) * 2) * 512 + l * 8 + j;
  w1p[base] = hi;
  w1p[base + 512] = lo;
}
__global__ __launch_bounds__(256) void pack_w2_kernel(
    const float* __restrict__ w2, unsigned short* __restrict__ w2p)
{
  int t = blockIdx.x * 256 + threadIdx.x;      // 9*4*512 = 18,432
  if (t >= 9 * 4 * 512) return;
  int j = t & 7, l = (t >> 3) & 63;
  int ot = (t >> 9) % 4, kt = (t >> 9) / 4;
  int oc = ot * 16 + (l & 15);
  int k  = kt * 32 + (l >> 4) * 8 + j;
  float w = w2[oc * 288 + k];
  unsigned short hi = f2bf(w);
  unsigned short lo = f2bf(w - bf2f(hi));
  long base = ((long)(kt * 4 + ot) * 2) * 512 + l * 8 + j;
  w2p[base] = hi;
  w2p[base + 512] = lo;
}

// ---------------- MFMA head: out = w3 . gelu(W2 @ gelu(W1 @ V))
// Block: 4 waves, 128 px. Wave: 32 px (2 M-tiles). Phase 1: D[px][oc] over
// K=576 (18 kt), 18 oc-tiles, hi+lo -> 72 MFMA/kt. h -> LDS bf16 [128][296].
// Phase 2: D2[px][oc2], K=288 (9 kt), 4 oc2-tiles, hi+lo. Then w3-dot +
// 16-lane shuffle reduce.
__global__ __launch_bounds__(256, 2) void head_mfma_kernel(
    const __hip_bfloat16* __restrict__ v,       // [2][576][65536] bf16
    const unsigned short* __restrict__ w1p,
    const unsigned short* __restrict__ w2p,
    const float* __restrict__ w3,               // [64]
    float* __restrict__ out)                    // [2][65536]
{
  __shared__ unsigned short hs[128][296];       // 75,776 B (pad: stride 148 dw)
  const int lane = threadIdx.x & 63;
  const int wave = threadIdx.x >> 6;
  const int col  = lane & 15;
  const int g    = lane >> 4;                   // 0..3
  const int n    = blockIdx.y;
  const int pxb  = blockIdx.x * 128;
  const unsigned short* vn =
      (const unsigned short*)v + (long)n * 576 * HPX + pxb + wave * 32;
  const short8* w1v = (const short8*)w1p;
  const short8* w2v = (const short8*)w2p;

  // ---- phase 1: h[px][0..288] for this wave's 32 px
  floatx4 acc[2][18];
  #pragma unroll
  for (int t = 0; t < 2; t++)
    #pragma unroll
    for (int mt = 0; mt < 18; mt++) acc[t][mt] = (floatx4){0.f, 0.f, 0.f, 0.f};

  for (int kt = 0; kt < 18; kt++) {
    short8 a0, a1;
    const unsigned short* vr = vn + (long)(kt * 32 + g * 8) * HPX + col;
    #pragma unroll
    for (int j = 0; j < 8; j++) {
      a0[j] = (short)vr[(long)j * HPX];
      a1[j] = (short)vr[(long)j * HPX + 16];
    }
    #pragma unroll
    for (int mt = 0; mt < 18; mt++) {
      short8 bhi = w1v[((kt * 18 + mt) * 2 + 0) * 64 + lane];
      short8 blo = w1v[((kt * 18 + mt) * 2 + 1) * 64 + lane];
      acc[0][mt] = __builtin_amdgcn_mfma_f32_16x16x32_bf16(a0, bhi, acc[0][mt], 0, 0, 0);
      acc[0][mt] = __builtin_amdgcn_mfma_f32_16x16x32_bf16(a0, blo, acc[0][mt], 0, 0, 0);
      acc[1][mt] = __builtin_amdgcn_mfma_f32_16x16x32_bf16(a1, bhi, acc[1][mt], 0, 0, 0);
      acc[1][mt] = __builtin_amdgcn_mfma_f32_16x16x32_bf16(a1, blo, acc[1][mt], 0, 0, 0);
    }
  }
  // gelu + store h to LDS (D layout: row px = g*4+r, col oc = mt*16+col)
  #pragma unroll
  for (int t = 0; t < 2; t++)
    #pragma unroll
    for (int mt = 0; mt < 18; mt++)
      #pragma unroll
      for (int r = 0; r < 4; r++)
        hs[wave * 32 + t * 16 + g * 4 + r][mt * 16 + col] =
            f2bf(gelu_f(acc[t][mt][r]));
  __syncthreads();

  // ---- phase 2: D2[px][oc2] = h @ W2^T, K=288
  floatx4 acc2[2][4];
  #pragma unroll
  for (int t = 0; t < 2; t++)
    #pragma unroll
    for (int ot = 0; ot < 4; ot++) acc2[t][ot] = (floatx4){0.f, 0.f, 0.f, 0.f};

  for (int kt = 0; kt < 9; kt++) {
    short8 a[2];
    #pragma unroll
    for (int t = 0; t < 2; t++)
      a[t] = *(const short8*)&hs[wave * 32 + t * 16 + col][kt * 32 + g * 8];
    #pragma unroll
    for (int ot = 0; ot < 4; ot++) {
      short8 bhi = w2v[((kt * 4 + ot) * 2 + 0) * 64 + lane];
      short8 blo = w2v[((kt * 4 + ot) * 2 + 1) * 64 + lane];
      acc2[0][ot] = __builtin_amdgcn_mfma_f32_16x16x32_bf16(a[0], bhi, acc2[0][ot], 0, 0, 0);
      acc2[0][ot] = __builtin_amdgcn_mfma_f32_16x16x32_bf16(a[0], blo, acc2[0][ot], 0, 0, 0);
      acc2[1][ot] = __builtin_amdgcn_mfma_f32_16x16x32_bf16(a[1], bhi, acc2[1][ot], 0, 0, 0);
      acc2[1][ot] = __builtin_amdgcn_mfma_f32_16x16x32_bf16(a[1], blo, acc2[1][ot], 0, 0, 0);
    }
  }

  // ---- w3 dot + reduce over oc2 (cols live across 16 lanes of same g-group)
  float w3r[4];
  #pragma unroll
  for (int ot = 0; ot < 4; ot++) w3r[ot] = w3[ot * 16 + col];
  #pragma unroll
  for (int t = 0; t < 2; t++) {
    float r[4] = {0.f, 0.f, 0.f, 0.f};
    #pragma unroll
    for (int ot = 0; ot < 4; ot++)
      #pragma unroll
      for (int rr = 0; rr < 4; rr++)
        r[rr] = fmaf(w3r[ot], gelu_f(acc2[t][ot][rr]), r[rr]);
    #pragma unroll
    for (int rr = 0; rr < 4; rr++) {
      r[rr] += __shfl_xor(r[rr], 1);
      r[rr] += __shfl_xor(r[rr], 2);
      r[rr] += __shfl_xor(r[rr], 4);
      r[rr] += __shfl_xor(r[rr], 8);
    }
    if (col == 0) {
      int px = pxb + wave * 32 + t * 16 + g * 4;
      #pragma unroll
      for (int rr = 0; rr < 4; rr++)
        out[(long)n * HPX + px + rr] = r[rr];
    }
  }
}

// ---------------------------------------------------------------------------
// host-side helpers
// ---------------------------------------------------------------------------
static inline void conv9(const float* in, const float* w, float* out,
                         int Hs, int logW, hipStream_t s) {
  int npx = Hs << logW;
  conv64_kernel<9, false, false><<<dim3(npx / 256, 2, 2), 256, 0, s>>>(
      in, w, nullptr, out, Hs, logW, 1, (long)FCH * npx);
}
static inline void conv9r(const float* in, const float* w, float* resid_out,
                          int Hs, int logW, hipStream_t s) {
  int npx = Hs << logW;
  conv64_kernel<9, true, false><<<dim3(npx / 256, 2, 2), 256, 0, s>>>(
      in, w, resid_out, resid_out, Hs, logW, 1, (long)FCH * npx);
}
static inline void donut_f(const float* in, const float* w, float* out,
                           int Hs, int logW, int dil, hipStream_t s) {
  int npx = Hs << logW;
  conv64_kernel<8, false, false><<<dim3(npx / 256, 2, 2), 256, 0, s>>>(
      in, w, nullptr, out, Hs, logW, dil, (long)FCH * npx);
}
static inline void donut_b(const float* in, const float* w, __hip_bfloat16* slice,
                           int dil, hipStream_t s) {
  conv64_kernel<8, false, true><<<dim3(256, 2, 2), 256, 0, s>>>(
      in, w, nullptr, slice, 256, 8, dil, (long)576 * HPX);
}
static inline void ups(const float* in, const float* w, __hip_bfloat16* slice,
                       int Hs, hipStream_t s) {
  ups_kernel<<<dim3(256, 2, 2), 256, 0, s>>>(in, w, slice, Hs);
}
static inline void avgpool(const float* in, float* out, int logWo, hipStream_t s) {
  long total = (long)2 * FCH * (1L << (2 * logWo));
  avgpool_kernel<<<(int)(total / 256), 256, 0, s>>>(in, out, logWo);
}

extern "C" void kernel_launch(void* const* d_in, const int* in_sizes, int n_in,
                              void* d_out, int out_size, void* d_ws, size_t ws_size,
                              hipStream_t stream) {
  const float* img      = (const float*)d_in[0];
  const float* w0a      = (const float*)d_in[1];
  const float* w0b      = (const float*)d_in[2];
  const float* first_p  = (const float*)d_in[3];
  const float* cl10     = (const float*)d_in[4];
  const float* cl2      = (const float*)d_in[5];
  const float* dil_p    = (const float*)d_in[6];
  const float* dilres_p = (const float*)d_in[7];
  const float* ups_w    = (const float*)d_in[8];
  const float* w1       = (const float*)d_in[9];   // [288][576]
  const float* w2       = (const float*)d_in[10];  // [64][288]
  const float* w3       = (const float*)d_in[11];  // [64]

  const size_t CONCAT_B = 150994944ul;
  const size_t PBUF_B   = 33554432ul;
  const size_t W1P_B    = 18ul * 18 * 2 * 512 * 2;   // 663,552
  const size_t W2P_B    = 9ul * 4 * 2 * 512 * 2;     // 147,456
  const size_t NEED = CONCAT_B + 2 * PBUF_B + W1P_B + W2P_B;  // 218,914,816

  if (ws_size < NEED) {
    hipMemsetAsync(d_out, 0, (size_t)out_size * 4, stream);
    return;
  }

  char* wsb = (char*)d_ws;
  __hip_bfloat16* concat = (__hip_bfloat16*)wsb;
  float* A = (float*)(wsb + CONCAT_B);
  float* B = (float*)(wsb + CONCAT_B + PBUF_B);
  unsigned short* w1p = (unsigned short*)(wsb + CONCAT_B + 2 * PBUF_B);
  unsigned short* w2p = (unsigned short*)(wsb + CONCAT_B + 2 * PBUF_B + W1P_B);

  auto SL = [&](int sidx) { return concat + (long)sidx * FCH * HPX; };
  const int C9 = 64 * 64 * 9, C8 = 64 * 64 * 8, C1 = 64 * 64;

  pack_w1_kernel<<<(18 * 18 * 512 + 255) / 256, 256, 0, stream>>>(w1, w1p);
  pack_w2_kernel<<<(9 * 4 * 512 + 255) / 256, 256, 0, stream>>>(w2, w2p);

  conv0_kernel<<<(2 * FCH * HPX) / 256, 256, 0, stream>>>(img, w0a, w0b, A);

  donut_b(A, first_p, SL(0), 1, stream);
  conv9(A, cl10 + 0 * C9, B, 256, 8, stream);
  conv9r(B, cl10 + 1 * C9, A, 256, 8, stream);               // base = A @256
  donut_b(A, dilres_p + 0 * C8, SL(1), 3, stream);
  conv9(A, cl2 + 0 * C9, B, 256, 8, stream);
  conv9r(B, cl2 + 1 * C9, A, 256, 8, stream);                // base = A @256

  // ---- i = 0 (dil 5 @256)
  donut_f(A, dil_p + 0 * C8, B, 256, 8, 5, stream);
  ups(B, ups_w + 0 * C1, SL(2), 256, stream);
  avgpool(A, B, 7, stream);                                  // base = B @128
  conv9(B, cl10 + 2 * C9, A, 128, 7, stream);
  conv9r(A, cl10 + 3 * C9, B, 128, 7, stream);               // base = B @128
  donut_f(B, dilres_p + 1 * C8, A, 128, 7, 6, stream);
  ups(A, ups_w + 1 * C1, SL(3), 128, stream);
  conv9(B, cl2 + 2 * C9, A, 128, 7, stream);
  conv9r(A, cl2 + 3 * C9, B, 128, 7, stream);                // base = B @128

  // ---- i = 1 (dil 8 @128)
  donut_f(B, dil_p + 1 * C8, A, 128, 7, 8, stream);
  ups(A, ups_w + 1 * C1, SL(4), 128, stream);
  avgpool(B, A, 6, stream);                                  // base = A @64
  conv9(A, cl10 + 4 * C9, B, 64, 6, stream);
  conv9r(B, cl10 + 5 * C9, A, 64, 6, stream);                // base = A @64
  donut_f(A, dilres_p + 2 * C8, B, 64, 6, 8, stream);
  ups(B, ups_w + 2 * C1, SL(5), 64, stream);
  conv9(A, cl2 + 4 * C9, B, 64, 6, stream);
  conv9r(B, cl2 + 5 * C9, A, 64, 6, stream);                 // base = A @64

  // ---- i = 2 (dil 10 @64)
  donut_f(A, dil_p + 2 * C8, B, 64, 6, 10, stream);
  ups(B, ups_w + 2 * C1, SL(6), 64, stream);
  avgpool(A, B, 5, stream);                                  // base = B @32
  conv9(B, cl10 + 6 * C9, A, 32, 5, stream);
  conv9r(A, cl10 + 7 * C9, B, 32, 5, stream);                // base = B @32
  donut_f(B, dilres_p + 3 * C8, A, 32, 5, 9, stream);
  ups(A, ups_w + 3 * C1, SL(7), 32, stream);
  conv9(B, cl2 + 6 * C9, A, 32, 5, stream);
  conv9r(A, cl2 + 7 * C9, B, 32, 5, stream);                 // base = B @32

  // ---- i = 3 (dil 11 @32)
  donut_f(B, dil_p + 3 * C8, A, 32, 5, 11, stream);
  ups(A, ups_w + 3 * C1, SL(8), 32, stream);

  // ---- MFMA head
  head_mfma_kernel<<<dim3(512, 2), 256, 0, stream>>>(concat, w1p, w2p, w3,
                                                     (float*)d_out);
}

// Round 7
// 1308.216 us; speedup vs baseline: 4.8894x; 3.1148x over previous
//
#include <hip/hip_runtime.h>
#include <hip/hip_bf16.h>

// ---------------------------------------------------------------------------
// SHINE forward, full bf16-MFMA version with hi/lo-split activations+weights.
// Workspace (222,445,568 B total):
//   concat : bf16 NHWC [2][65536][576]          150,994,944 B
//   Xhi,Xlo,Yhi,Ylo : bf16 NHWC [2][65536][64]  4 x 16,777,216 B
//   packs  : conv B-frags (hi,lo)                 3,604,480 B
//   w1p    : head W1 frags                          663,552 B
//   w2p    : head W2 frags                           73,728 B
// Activations are stored as hi+lo bf16 pairs (~fp32 precision); each MFMA
// fragment product uses 3 mfma ops (drops lo*lo ~ 2^-18 relative).
// ---------------------------------------------------------------------------

#define HPX 65536   // 256*256
#define FCH 64

typedef __attribute__((ext_vector_type(8))) short  short8;
typedef __attribute__((ext_vector_type(4))) float  floatx4;

__device__ __forceinline__ float gelu_f(float x) {
  return 0.5f * x * (1.0f + erff(x * 0.70710678118654752440f));
}
__device__ __forceinline__ unsigned short f2bf(float x) {  // RNE
  unsigned u = __float_as_uint(x);
  unsigned r = (u + 0x7FFFu + ((u >> 16) & 1u)) >> 16;
  return (unsigned short)r;
}
__device__ __forceinline__ float bf2f(unsigned short h) {
  return __uint_as_float(((unsigned)h) << 16);
}

// ---------------- conv0: base = concat(gelu(1x1(target)), gelu(3x3(feats)))
// writes NHWC hi/lo act planes
__global__ __launch_bounds__(256) void conv0_nhwc_kernel(
    const float* __restrict__ img,   // [2][5][256][256]
    const float* __restrict__ w0a,   // [16][4][3][3]
    const float* __restrict__ w0b,   // [48]
    unsigned short* __restrict__ ohi,  // [2][65536][64]
    unsigned short* __restrict__ olo)
{
  long t = (long)blockIdx.x * 256 + threadIdx.x;   // over 2*65536*64
  int c  = (int)(t & 63);
  int px = (int)((t >> 6) & (HPX - 1));
  int n  = (int)(t >> 22);
  const float* im = img + (long)n * 5 * HPX;
  float r;
  if (c < 48) {
    r = w0b[c] * im[2 * HPX + px];
  } else {
    int co = c - 48;
    int y = px >> 8, x = px & 255;
    r = 0.0f;
    const int map4[4] = {0, 1, 3, 4};
    #pragma unroll
    for (int fi = 0; fi < 4; fi++) {
      const float* imc = im + (long)map4[fi] * HPX;
      #pragma unroll
      for (int ky = 0; ky < 3; ky++) {
        int yy = y + ky - 1;
        #pragma unroll
        for (int kx = 0; kx < 3; kx++) {
          int xx = x + kx - 1;
          bool ok = ((unsigned)yy < 256u) && ((unsigned)xx < 256u);
          float v = ok ? imc[yy * 256 + xx] : 0.0f;
          r = fmaf(w0a[((co * 4 + fi) * 3 + ky) * 3 + kx], v, r);
        }
      }
    }
  }
  float v = gelu_f(r);
  unsigned short hb = f2bf(v);
  ohi[t] = hb;
  olo[t] = f2bf(v - bf2f(hb));
}

// ---------------- batched conv-weight packing into MFMA B-frags (hi,lo)
// frag layout: idx = ((((tap*2+kt)*4+nt)*2+s)*64 + lane)*8 + j
//   oc = nt*16 + (lane&15), ci = kt*32 + (lane>>4)*8 + j
// src layout: w[(oc*64+ci)*ntaps + tap]
struct JobArr { int4 j[29]; };   // {src_sel, src_off, ntaps, dst_off}

__global__ __launch_bounds__(256) void pack_conv_kernel(
    const float* __restrict__ cl10, const float* __restrict__ cl2,
    const float* __restrict__ first_p, const float* __restrict__ dilres_p,
    const float* __restrict__ dil_p, const float* __restrict__ ups_w,
    unsigned short* __restrict__ packs, JobArr jobs)
{
  int4 jb = jobs.j[blockIdx.y];
  int ntaps = jb.z;
  int idx = blockIdx.x * 256 + threadIdx.x;
  if (idx >= ntaps * 8192) return;
  int j  = idx & 7;
  int l  = (idx >> 3) & 63;
  int s  = (idx >> 9) & 1;
  int nt = (idx >> 10) & 3;
  int kt = (idx >> 12) & 1;
  int tap = idx >> 13;
  int oc = nt * 16 + (l & 15);
  int ci = kt * 32 + (l >> 4) * 8 + j;
  const float* src;
  switch (jb.x) {
    case 0: src = cl10; break;
    case 1: src = cl2; break;
    case 2: src = first_p; break;
    case 3: src = dilres_p; break;
    case 4: src = dil_p; break;
    default: src = ups_w; break;
  }
  float w = src[jb.y + (oc * 64 + ci) * ntaps + tap];
  unsigned short hi = f2bf(w);
  unsigned short v = (s == 0) ? hi : f2bf(w - bf2f(hi));
  packs[jb.w + idx] = v;
}

// ---------------- head weight packing (hi+lo), as round 6 (proven)
__global__ __launch_bounds__(256) void pack_w1_kernel(
    const float* __restrict__ w1, unsigned short* __restrict__ w1p)
{
  int t = blockIdx.x * 256 + threadIdx.x;      // 18*18*512
  if (t >= 18 * 18 * 512) return;
  int j = t & 7, l = (t >> 3) & 63;
  int mt = (t >> 9) % 18, kt = (t >> 9) / 18;
  int oc = mt * 16 + (l & 15);
  int k  = kt * 32 + (l >> 4) * 8 + j;
  float w = w1[oc * 576 + k];
  unsigned short hi = f2bf(w);
  unsigned short lo = f2bf(w - bf2f(hi));
  long base = ((long)(kt * 18 + mt) * 2) * 512 + l * 8 + j;
  w1p[base] = hi;
  w1p[base + 512] = lo;
}
__global__ __launch_bounds__(256) void pack_w2_kernel(
    const float* __restrict__ w2, unsigned short* __restrict__ w2p)
{
  int t = blockIdx.x * 256 + threadIdx.x;      // 9*4*512
  if (t >= 9 * 4 * 512) return;
  int j = t & 7, l = (t >> 3) & 63;
  int ot = (t >> 9) % 4, kt = (t >> 9) / 4;
  int oc = ot * 16 + (l & 15);
  int k  = kt * 32 + (l >> 4) * 8 + j;
  float w = w2[oc * 288 + k];
  unsigned short hi = f2bf(w);
  unsigned short lo = f2bf(w - bf2f(hi));
  long base = ((long)(kt * 4 + ot) * 2) * 512 + l * 8 + j;
  w2p[base] = hi;
  w2p[base + 512] = lo;
}

// ---------------- universal MFMA conv (implicit GEMM, 16x16x32 bf16)
// NTAPS: 9 full 3x3 / 8 donut / 1 pointwise. MT: m-tiles per wave (16px each).
// BILIN: bilinear-sample input (scale Hs -> 256 output grid), for ups.
// TO_CONCAT: write single-bf16 into concat slice at column ccol; else write
// hi/lo act planes. RESID: pointwise residual (hi+lo) added pre-gelu;
// out may alias resid (pointwise read-then-write per thread).
// Fragment conventions (proven in head kernel): A row=lane&15, k=(lane>>4)*8+j;
// B col=lane&15, k same; D row=(lane>>4)*4+r, col=lane&15.
template <int NTAPS, int MT, bool RESID, bool BILIN, bool TO_CONCAT>
__global__ __launch_bounds__(256) void conv_mfma_kernel(
    const unsigned short* __restrict__ in_hi,   // NHWC [n][npx_in][64]
    const unsigned short* __restrict__ in_lo,
    const unsigned short* __restrict__ wp,      // packed frags
    const unsigned short* __restrict__ res_hi,
    const unsigned short* __restrict__ res_lo,
    unsigned short* __restrict__ out_hi,        // act hi or concat
    unsigned short* __restrict__ out_lo,
    int Hs, int logW, int dil, int ccol)
{
  const int lane = threadIdx.x & 63;
  const int wave = threadIdx.x >> 6;
  const int row  = lane & 15;
  const int g    = lane >> 4;
  const int n    = blockIdx.z;
  const int Ws   = 1 << logW;
  const int npx_in = Hs << logW;
  const int opx0 = blockIdx.x * (64 * MT) + wave * (16 * MT);

  const unsigned short* ihi = in_hi + (long)n * npx_in * 64;
  const unsigned short* ilo = in_lo + (long)n * npx_in * 64;

  int ry[MT], rx[MT];
  int b00[MT], b01[MT], b10[MT], b11[MT];
  float bwx[MT], bwy[MT];
  #pragma unroll
  for (int mt = 0; mt < MT; mt++) {
    int p = opx0 + mt * 16 + row;
    if (BILIN) {
      int Y = p >> 8, X = p & 255;
      float sc = (float)Hs * (1.0f / 256.0f);
      float fy = ((float)Y + 0.5f) * sc - 0.5f;
      float fx = ((float)X + 0.5f) * sc - 0.5f;
      int y0 = (int)floorf(fy), x0 = (int)floorf(fx);
      bwy[mt] = fy - (float)y0; bwx[mt] = fx - (float)x0;
      int y0c = min(max(y0, 0), Hs - 1), y1c = min(max(y0 + 1, 0), Hs - 1);
      int x0c = min(max(x0, 0), Hs - 1), x1c = min(max(x0 + 1, 0), Hs - 1);
      b00[mt] = (y0c * Hs + x0c) * 64; b01[mt] = (y0c * Hs + x1c) * 64;
      b10[mt] = (y1c * Hs + x0c) * 64; b11[mt] = (y1c * Hs + x1c) * 64;
    } else {
      ry[mt] = p >> logW; rx[mt] = p & (Ws - 1);
    }
  }

  floatx4 acc[MT][4];
  #pragma unroll
  for (int mt = 0; mt < MT; mt++)
    #pragma unroll
    for (int nt = 0; nt < 4; nt++) acc[mt][nt] = (floatx4){0.f, 0.f, 0.f, 0.f};

  const short8* wv = (const short8*)wp;
  const short8 zz = {0, 0, 0, 0, 0, 0, 0, 0};

  #pragma unroll 1   // keep code size bounded; inner loops fully unrolled
  for (int t = 0; t < NTAPS; t++) {
    int aoff[MT];
    if (!BILIN) {
      const int kk  = (NTAPS == 9) ? t : ((NTAPS == 8) ? (t < 4 ? t : t + 1) : 4);
      const int dyd = (kk / 3 - 1) * dil, dxd = (kk % 3 - 1) * dil;
      #pragma unroll
      for (int mt = 0; mt < MT; mt++) {
        int yy = ry[mt] + dyd, xx = rx[mt] + dxd;
        bool ok = ((unsigned)yy < (unsigned)Hs) && ((unsigned)xx < (unsigned)Ws);
        aoff[mt] = ok ? ((yy << logW) + xx) * 64 : -1;
      }
    }
    #pragma unroll
    for (int kt = 0; kt < 2; kt++) {
      const int ko = kt * 32 + g * 8;
      short8 ah[MT], al[MT];
      #pragma unroll
      for (int mt = 0; mt < MT; mt++) {
        if (BILIN) {
          short8 h00 = *(const short8*)(ihi + b00[mt] + ko);
          short8 l00 = *(const short8*)(ilo + b00[mt] + ko);
          short8 h01 = *(const short8*)(ihi + b01[mt] + ko);
          short8 l01 = *(const short8*)(ilo + b01[mt] + ko);
          short8 h10 = *(const short8*)(ihi + b10[mt] + ko);
          short8 l10 = *(const short8*)(ilo + b10[mt] + ko);
          short8 h11 = *(const short8*)(ihi + b11[mt] + ko);
          short8 l11 = *(const short8*)(ilo + b11[mt] + ko);
          short8 hh, ll;
          #pragma unroll
          for (int j = 0; j < 8; j++) {
            float v00 = bf2f((unsigned short)h00[j]) + bf2f((unsigned short)l00[j]);
            float v01 = bf2f((unsigned short)h01[j]) + bf2f((unsigned short)l01[j]);
            float v10 = bf2f((unsigned short)h10[j]) + bf2f((unsigned short)l10[j]);
            float v11 = bf2f((unsigned short)h11[j]) + bf2f((unsigned short)l11[j]);
            float v0 = v00 + bwx[mt] * (v01 - v00);
            float v1 = v10 + bwx[mt] * (v11 - v10);
            float v  = v0 + bwy[mt] * (v1 - v0);
            unsigned short hb = f2bf(v);
            hh[j] = (short)hb;
            ll[j] = (short)f2bf(v - bf2f(hb));
          }
          ah[mt] = hh; al[mt] = ll;
        } else {
          int ao = aoff[mt];
          long a = (long)(ao < 0 ? 0 : ao) + ko;
          short8 h = *(const short8*)(ihi + a);
          short8 l = *(const short8*)(ilo + a);
          ah[mt] = (ao < 0) ? zz : h;
          al[mt] = (ao < 0) ? zz : l;
        }
      }
      const short8* wf = wv + (long)((t * 2 + kt) * 4) * 2 * 64;
      #pragma unroll
      for (int nt = 0; nt < 4; nt++) {
        short8 bh = wf[(nt * 2 + 0) * 64 + lane];
        short8 bl = wf[(nt * 2 + 1) * 64 + lane];
        #pragma unroll
        for (int mt = 0; mt < MT; mt++) {
          acc[mt][nt] = __builtin_amdgcn_mfma_f32_16x16x32_bf16(ah[mt], bh, acc[mt][nt], 0, 0, 0);
          acc[mt][nt] = __builtin_amdgcn_mfma_f32_16x16x32_bf16(ah[mt], bl, acc[mt][nt], 0, 0, 0);
          acc[mt][nt] = __builtin_amdgcn_mfma_f32_16x16x32_bf16(al[mt], bh, acc[mt][nt], 0, 0, 0);
        }
      }
    }
  }

  // epilogue: (+resid) -> gelu -> store
  #pragma unroll
  for (int mt = 0; mt < MT; mt++) {
    #pragma unroll
    for (int nt = 0; nt < 4; nt++) {
      #pragma unroll
      for (int r = 0; r < 4; r++) {
        int px = opx0 + mt * 16 + g * 4 + r;
        int oc = nt * 16 + row;
        float v = acc[mt][nt][r];
        if (RESID) {
          long ri = ((long)n * npx_in + px) * 64 + oc;
          v += bf2f(res_hi[ri]) + bf2f(res_lo[ri]);
        }
        v = gelu_f(v);
        if (TO_CONCAT) {
          out_hi[((long)n * HPX + px) * 576 + ccol + oc] = f2bf(v);
        } else {
          long oi = ((long)n * npx_in + px) * 64 + oc;
          unsigned short hb = f2bf(v);
          out_hi[oi] = hb;
          out_lo[oi] = f2bf(v - bf2f(hb));
        }
      }
    }
  }
}

// ---------------- 2x2 average pool, NHWC hi/lo -> NHWC hi/lo
__global__ __launch_bounds__(256) void avgpool_nhwc_kernel(
    const unsigned short* __restrict__ ihi, const unsigned short* __restrict__ ilo,
    unsigned short* __restrict__ ohi, unsigned short* __restrict__ olo,
    int logWo)
{
  const int lognpo = 2 * logWo;
  long t = (long)blockIdx.x * 256 + threadIdx.x;   // over 2*npo*8
  int cg = (int)(t & 7);
  int p  = (int)((t >> 3) & ((1 << lognpo) - 1));
  int n  = (int)(t >> (3 + lognpo));
  int y = p >> logWo, x = p & ((1 << logWo) - 1);
  int Wi = 2 << logWo;
  long ib = ((long)n * (4 << lognpo) + (long)(2 * y) * Wi + 2 * x) * 64 + cg * 8;
  short8 h00 = *(const short8*)(ihi + ib);
  short8 h01 = *(const short8*)(ihi + ib + 64);
  short8 h10 = *(const short8*)(ihi + ib + (long)Wi * 64);
  short8 h11 = *(const short8*)(ihi + ib + (long)Wi * 64 + 64);
  short8 l00 = *(const short8*)(ilo + ib);
  short8 l01 = *(const short8*)(ilo + ib + 64);
  short8 l10 = *(const short8*)(ilo + ib + (long)Wi * 64);
  short8 l11 = *(const short8*)(ilo + ib + (long)Wi * 64 + 64);
  short8 oh, ol;
  #pragma unroll
  for (int j = 0; j < 8; j++) {
    float v = 0.25f * ((bf2f((unsigned short)h00[j]) + bf2f((unsigned short)l00[j])) +
                       (bf2f((unsigned short)h01[j]) + bf2f((unsigned short)l01[j])) +
                       (bf2f((unsigned short)h10[j]) + bf2f((unsigned short)l10[j])) +
                       (bf2f((unsigned short)h11[j]) + bf2f((unsigned short)l11[j])));
    unsigned short hb = f2bf(v);
    oh[j] = (short)hb;
    ol[j] = (short)f2bf(v - bf2f(hb));
  }
  long ob = (((long)n << lognpo) + p) * 64 + cg * 8;
  *(short8*)(ohi + ob) = oh;
  *(short8*)(olo + ob) = ol;
}

// ---------------- MFMA head: out = w3 . gelu(W2 @ gelu(W1 @ V))  (NHWC concat)
__global__ __launch_bounds__(256, 2) void head_mfma_kernel(
    const unsigned short* __restrict__ v,       // NHWC [2][65536][576] bf16
    const unsigned short* __restrict__ w1p,
    const unsigned short* __restrict__ w2p,
    const float* __restrict__ w3,               // [64]
    float* __restrict__ out)                    // [2][65536]
{
  __shared__ unsigned short hs[128][296];       // 75,776 B
  const int lane = threadIdx.x & 63;
  const int wave = threadIdx.x >> 6;
  const int col  = lane & 15;
  const int g    = lane >> 4;
  const int n    = blockIdx.y;
  const int pxb  = blockIdx.x * 128;
  const unsigned short* vn = v + ((long)n * HPX + pxb + wave * 32) * 576;
  const short8* w1v = (const short8*)w1p;
  const short8* w2v = (const short8*)w2p;

  floatx4 acc[2][18];
  #pragma unroll
  for (int t = 0; t < 2; t++)
    #pragma unroll
    for (int mt = 0; mt < 18; mt++) acc[t][mt] = (floatx4){0.f, 0.f, 0.f, 0.f};

  for (int kt = 0; kt < 18; kt++) {
    const int ko = kt * 32 + g * 8;
    short8 a0 = *(const short8*)(vn + (long)col * 576 + ko);
    short8 a1 = *(const short8*)(vn + (long)(col + 16) * 576 + ko);
    #pragma unroll
    for (int mt = 0; mt < 18; mt++) {
      short8 bhi = w1v[((kt * 18 + mt) * 2 + 0) * 64 + lane];
      short8 blo = w1v[((kt * 18 + mt) * 2 + 1) * 64 + lane];
      acc[0][mt] = __builtin_amdgcn_mfma_f32_16x16x32_bf16(a0, bhi, acc[0][mt], 0, 0, 0);
      acc[0][mt] = __builtin_amdgcn_mfma_f32_16x16x32_bf16(a0, blo, acc[0][mt], 0, 0, 0);
      acc[1][mt] = __builtin_amdgcn_mfma_f32_16x16x32_bf16(a1, bhi, acc[1][mt], 0, 0, 0);
      acc[1][mt] = __builtin_amdgcn_mfma_f32_16x16x32_bf16(a1, blo, acc[1][mt], 0, 0, 0);
    }
  }
  #pragma unroll
  for (int t = 0; t < 2; t++)
    #pragma unroll
    for (int mt = 0; mt < 18; mt++)
      #pragma unroll
      for (int r = 0; r < 4; r++)
        hs[wave * 32 + t * 16 + g * 4 + r][mt * 16 + col] =
            f2bf(gelu_f(acc[t][mt][r]));
  __syncthreads();

  floatx4 acc2[2][4];
  #pragma unroll
  for (int t = 0; t < 2; t++)
    #pragma unroll
    for (int ot = 0; ot < 4; ot++) acc2[t][ot] = (floatx4){0.f, 0.f, 0.f, 0.f};

  for (int kt = 0; kt < 9; kt++) {
    short8 a[2];
    #pragma unroll
    for (int t = 0; t < 2; t++)
      a[t] = *(const short8*)&hs[wave * 32 + t * 16 + col][kt * 32 + g * 8];
    #pragma unroll
    for (int ot = 0; ot < 4; ot++) {
      short8 bhi = w2v[((kt * 4 + ot) * 2 + 0) * 64 + lane];
      short8 blo = w2v[((kt * 4 + ot) * 2 + 1) * 64 + lane];
      acc2[0][ot] = __builtin_amdgcn_mfma_f32_16x16x32_bf16(a[0], bhi, acc2[0][ot], 0, 0, 0);
      acc2[0][ot] = __builtin_amdgcn_mfma_f32_16x16x32_bf16(a[0], blo, acc2[0][ot], 0, 0, 0);
      acc2[1][ot] = __builtin_amdgcn_mfma_f32_16x16x32_bf16(a[1], bhi, acc2[1][ot], 0, 0, 0);
      acc2[1][ot] = __builtin_amdgcn_mfma_f32_16x16x32_bf16(a[1], blo, acc2[1][ot], 0, 0, 0);
    }
  }

  float w3r[4];
  #pragma unroll
  for (int ot = 0; ot < 4; ot++) w3r[ot] = w3[ot * 16 + col];
  #pragma unroll
  for (int t = 0; t < 2; t++) {
    float r[4] = {0.f, 0.f, 0.f, 0.f};
    #pragma unroll
    for (int ot = 0; ot < 4; ot++)
      #pragma unroll
      for (int rr = 0; rr < 4; rr++)
        r[rr] = fmaf(w3r[ot], gelu_f(acc2[t][ot][rr]), r[rr]);
    #pragma unroll
    for (int rr = 0; rr < 4; rr++) {
      r[rr] += __shfl_xor(r[rr], 1);
      r[rr] += __shfl_xor(r[rr], 2);
      r[rr] += __shfl_xor(r[rr], 4);
      r[rr] += __shfl_xor(r[rr], 8);
    }
    if (col == 0) {
      int px = pxb + wave * 32 + t * 16 + g * 4;
      #pragma unroll
      for (int rr = 0; rr < 4; rr++)
        out[(long)n * HPX + px + rr] = r[rr];
    }
  }
}

// ---------------------------------------------------------------------------
extern "C" void kernel_launch(void* const* d_in, const int* in_sizes, int n_in,
                              void* d_out, int out_size, void* d_ws, size_t ws_size,
                              hipStream_t stream) {
  const float* img      = (const float*)d_in[0];
  const float* w0a      = (const float*)d_in[1];
  const float* w0b      = (const float*)d_in[2];
  const float* first_p  = (const float*)d_in[3];
  const float* cl10     = (const float*)d_in[4];   // [4][2][64][64][9]
  const float* cl2      = (const float*)d_in[5];
  const float* dil_p    = (const float*)d_in[6];   // [4][64][64][8]
  const float* dilres_p = (const float*)d_in[7];
  const float* ups_w    = (const float*)d_in[8];   // [4][64][64]
  const float* w1       = (const float*)d_in[9];   // [288][576]
  const float* w2       = (const float*)d_in[10];  // [64][288]
  const float* w3       = (const float*)d_in[11];  // [64]

  const size_t CONCAT_B = 150994944ul;             // 2*65536*576*2
  const size_t ACT_B    = 16777216ul;              // 2*65536*64*2 per plane
  const size_t PACKS_B  = 3604480ul;               // 1,802,240 elems
  const size_t W1P_B    = 663552ul;
  const size_t W2P_B    = 73728ul;
  const size_t NEED = CONCAT_B + 4 * ACT_B + PACKS_B + W1P_B + W2P_B; // 222,445,568

  if (ws_size < NEED) {
    hipMemsetAsync(d_out, 0, (size_t)out_size * 4, stream);
    return;
  }

  char* wsb = (char*)d_ws;
  unsigned short* concat = (unsigned short*)wsb;
  unsigned short* Xhi = (unsigned short*)(wsb + CONCAT_B);
  unsigned short* Xlo = (unsigned short*)(wsb + CONCAT_B + ACT_B);
  unsigned short* Yhi = (unsigned short*)(wsb + CONCAT_B + 2 * ACT_B);
  unsigned short* Ylo = (unsigned short*)(wsb + CONCAT_B + 3 * ACT_B);
  unsigned short* packs = (unsigned short*)(wsb + CONCAT_B + 4 * ACT_B);
  unsigned short* w1p = (unsigned short*)(wsb + CONCAT_B + 4 * ACT_B + PACKS_B);
  unsigned short* w2p = (unsigned short*)(wsb + CONCAT_B + 4 * ACT_B + PACKS_B + W1P_B);

  // pack-destination offsets (elems)
  auto off_cl10   = [](int c) { return (long)c * 73728; };
  auto off_cl2    = [](int c) { return 589824l + (long)c * 73728; };
  const long OFF_FIRST = 1179648;
  auto off_dilres = [](int k) { return 1245184l + (long)k * 65536; };
  auto off_dil    = [](int k) { return 1507328l + (long)k * 65536; };
  auto off_ups    = [](int k) { return 1769472l + (long)k * 8192; };

  // ---- weight packing (one batched kernel + head packs)
  JobArr jobs;
  for (int c = 0; c < 8; c++) jobs.j[c]     = {0, c * 36864, 9, (int)off_cl10(c)};
  for (int c = 0; c < 8; c++) jobs.j[8 + c] = {1, c * 36864, 9, (int)off_cl2(c)};
  jobs.j[16] = {2, 0, 8, (int)OFF_FIRST};
  for (int k = 0; k < 4; k++) jobs.j[17 + k] = {3, k * 32768, 8, (int)off_dilres(k)};
  for (int k = 0; k < 4; k++) jobs.j[21 + k] = {4, k * 32768, 8, (int)off_dil(k)};
  for (int k = 0; k < 4; k++) jobs.j[25 + k] = {5, k * 4096, 1, (int)off_ups(k)};
  pack_conv_kernel<<<dim3(288, 29), 256, 0, stream>>>(
      cl10, cl2, first_p, dilres_p, dil_p, ups_w, packs, jobs);
  pack_w1_kernel<<<(18 * 18 * 512 + 255) / 256, 256, 0, stream>>>(w1, w1p);
  pack_w2_kernel<<<(9 * 4 * 512 + 255) / 256, 256, 0, stream>>>(w2, w2p);

  // ---- conv0 -> X @256
  conv0_nhwc_kernel<<<(2 * HPX * 64) / 256, 256, 0, stream>>>(img, w0a, w0b, Xhi, Xlo);

  // ---- launch helpers
  auto conv9_4 = [&](const unsigned short* ih, const unsigned short* il, long wo,
                     unsigned short* oh, unsigned short* ol) {
    conv_mfma_kernel<9, 4, false, false, false><<<dim3(256, 1, 2), 256, 0, stream>>>(
        ih, il, packs + wo, nullptr, nullptr, oh, ol, 256, 8, 1, 0);
  };
  auto conv9r_4 = [&](const unsigned short* ih, const unsigned short* il, long wo,
                      unsigned short* rh, unsigned short* rl) {
    conv_mfma_kernel<9, 4, true, false, false><<<dim3(256, 1, 2), 256, 0, stream>>>(
        ih, il, packs + wo, rh, rl, rh, rl, 256, 8, 1, 0);
  };
  auto conv9_2 = [&](const unsigned short* ih, const unsigned short* il, long wo,
                     unsigned short* oh, unsigned short* ol, int Hs, int logW) {
    conv_mfma_kernel<9, 2, false, false, false><<<dim3((Hs << logW) / 128, 1, 2), 256, 0, stream>>>(
        ih, il, packs + wo, nullptr, nullptr, oh, ol, Hs, logW, 1, 0);
  };
  auto conv9r_2 = [&](const unsigned short* ih, const unsigned short* il, long wo,
                      unsigned short* rh, unsigned short* rl, int Hs, int logW) {
    conv_mfma_kernel<9, 2, true, false, false><<<dim3((Hs << logW) / 128, 1, 2), 256, 0, stream>>>(
        ih, il, packs + wo, rh, rl, rh, rl, Hs, logW, 1, 0);
  };
  auto donutC = [&](const unsigned short* ih, const unsigned short* il, long wo,
                    int dil, int ccol) {  // @256 -> concat
    conv_mfma_kernel<8, 4, false, false, true><<<dim3(256, 1, 2), 256, 0, stream>>>(
        ih, il, packs + wo, nullptr, nullptr, concat, nullptr, 256, 8, dil, ccol);
  };
  auto donutA_4 = [&](const unsigned short* ih, const unsigned short* il, long wo,
                      int dil, unsigned short* oh, unsigned short* ol) {  // @256
    conv_mfma_kernel<8, 4, false, false, false><<<dim3(256, 1, 2), 256, 0, stream>>>(
        ih, il, packs + wo, nullptr, nullptr, oh, ol, 256, 8, dil, 0);
  };
  auto donutA_2 = [&](const unsigned short* ih, const unsigned short* il, long wo,
                      int dil, unsigned short* oh, unsigned short* ol, int Hs, int logW) {
    conv_mfma_kernel<8, 2, false, false, false><<<dim3((Hs << logW) / 128, 1, 2), 256, 0, stream>>>(
        ih, il, packs + wo, nullptr, nullptr, oh, ol, Hs, logW, dil, 0);
  };
  auto upsC = [&](const unsigned short* ih, const unsigned short* il, long wo,
                  int Hs, int logW, int ccol) {
    conv_mfma_kernel<1, 4, false, true, true><<<dim3(256, 1, 2), 256, 0, stream>>>(
        ih, il, packs + wo, nullptr, nullptr, concat, nullptr, Hs, logW, 1, ccol);
  };
  auto avgp = [&](const unsigned short* ih, const unsigned short* il,
                  unsigned short* oh, unsigned short* ol, int logWo) {
    long total = 2l * (1l << (2 * logWo)) * 8;
    avgpool_nhwc_kernel<<<(int)(total / 256), 256, 0, stream>>>(ih, il, oh, ol, logWo);
  };

  // ---- @256: outs[0], resblock cl10[0], outs[1], resblock cl2[0]
  donutC(Xhi, Xlo, OFF_FIRST, 1, 0);
  conv9_4(Xhi, Xlo, off_cl10(0), Yhi, Ylo);
  conv9r_4(Yhi, Ylo, off_cl10(1), Xhi, Xlo);                 // base = X @256
  donutC(Xhi, Xlo, off_dilres(0), 3, 64);
  conv9_4(Xhi, Xlo, off_cl2(0), Yhi, Ylo);
  conv9r_4(Yhi, Ylo, off_cl2(1), Xhi, Xlo);                  // base = X @256

  // ---- i = 0 (dil 5 @256)
  donutA_4(Xhi, Xlo, off_dil(0), 5, Yhi, Ylo);
  upsC(Yhi, Ylo, off_ups(0), 256, 8, 128);
  avgp(Xhi, Xlo, Yhi, Ylo, 7);                               // base = Y @128
  conv9_2(Yhi, Ylo, off_cl10(2), Xhi, Xlo, 128, 7);
  conv9r_2(Xhi, Xlo, off_cl10(3), Yhi, Ylo, 128, 7);         // base = Y @128
  donutA_2(Yhi, Ylo, off_dilres(1), 6, Xhi, Xlo, 128, 7);
  upsC(Xhi, Xlo, off_ups(1), 128, 7, 192);
  conv9_2(Yhi, Ylo, off_cl2(2), Xhi, Xlo, 128, 7);
  conv9r_2(Xhi, Xlo, off_cl2(3), Yhi, Ylo, 128, 7);          // base = Y @128

  // ---- i = 1 (dil 8 @128)
  donutA_2(Yhi, Ylo, off_dil(1), 8, Xhi, Xlo, 128, 7);
  upsC(Xhi, Xlo, off_ups(1), 128, 7, 256);
  avgp(Yhi, Ylo, Xhi, Xlo, 6);                               // base = X @64
  conv9_2(Xhi, Xlo, off_cl10(4), Yhi, Ylo, 64, 6);
  conv9r_2(Yhi, Ylo, off_cl10(5), Xhi, Xlo, 64, 6);          // base = X @64
  donutA_2(Xhi, Xlo, off_dilres(2), 8, Yhi, Ylo, 64, 6);
  upsC(Yhi, Ylo, off_ups(2), 64, 6, 320);
  conv9_2(Xhi, Xlo, off_cl2(4), Yhi, Ylo, 64, 6);
  conv9r_2(Yhi, Ylo, off_cl2(5), Xhi, Xlo, 64, 6);           // base = X @64

  // ---- i = 2 (dil 10 @64)
  donutA_2(Xhi, Xlo, off_dil(2), 10, Yhi, Ylo, 64, 6);
  upsC(Yhi, Ylo, off_ups(2), 64, 6, 384);
  avgp(Xhi, Xlo, Yhi, Ylo, 5);                               // base = Y @32
  conv9_2(Yhi, Ylo, off_cl10(6), Xhi, Xlo, 32, 5);
  conv9r_2(Xhi, Xlo, off_cl10(7), Yhi, Ylo, 32, 5);          // base = Y @32
  donutA_2(Yhi, Ylo, off_dilres(3), 9, Xhi, Xlo, 32, 5);
  upsC(Xhi, Xlo, off_ups(3), 32, 5, 448);
  conv9_2(Yhi, Ylo, off_cl2(6), Xhi, Xlo, 32, 5);
  conv9r_2(Xhi, Xlo, off_cl2(7), Yhi, Ylo, 32, 5);           // base = Y @32

  // ---- i = 3 (dil 11 @32)
  donutA_2(Yhi, Ylo, off_dil(3), 11, Xhi, Xlo, 32, 5);
  upsC(Xhi, Xlo, off_ups(3), 32, 5, 512);

  // ---- MFMA head
  head_mfma_kernel<<<dim3(512, 2), 256, 0, stream>>>(concat, w1p, w2p, w3,
                                                     (float*)d_out);
}

// Round 8
// 1252.942 us; speedup vs baseline: 5.1051x; 1.0441x over previous
//
#include <hip/hip_runtime.h>
#include <hip/hip_bf16.h>

// ---------------------------------------------------------------------------
// SHINE forward, full bf16-MFMA version with hi/lo-split activations+weights.
// Workspace (222,445,568 B total):
//   concat : bf16 NHWC [2][65536][576]          150,994,944 B
//   Xhi,Xlo,Yhi,Ylo : bf16 NHWC [2][65536][64]  4 x 16,777,216 B
//   packs  : conv B-frags (hi,lo)                 3,604,480 B
//   w1p    : head W1 frags                          663,552 B
//   w2p    : head W2 frags                           73,728 B
// Activations are stored as hi+lo bf16 pairs (~fp32 precision); each MFMA
// fragment product uses 3 mfma ops (drops lo*lo ~ 2^-18 relative).
// R8: conv B-frags staged per-tap in LDS (16 KB), shared by all 4 waves ->
//     4x less L1/L2 weight traffic, ds_read_b128 conflict-free.
// ---------------------------------------------------------------------------

#define HPX 65536   // 256*256
#define FCH 64

typedef __attribute__((ext_vector_type(8))) short  short8;
typedef __attribute__((ext_vector_type(4))) float  floatx4;

__device__ __forceinline__ float gelu_f(float x) {
  return 0.5f * x * (1.0f + erff(x * 0.70710678118654752440f));
}
__device__ __forceinline__ unsigned short f2bf(float x) {  // RNE
  unsigned u = __float_as_uint(x);
  unsigned r = (u + 0x7FFFu + ((u >> 16) & 1u)) >> 16;
  return (unsigned short)r;
}
__device__ __forceinline__ float bf2f(unsigned short h) {
  return __uint_as_float(((unsigned)h) << 16);
}

// ---------------- conv0: base = concat(gelu(1x1(target)), gelu(3x3(feats)))
// writes NHWC hi/lo act planes
__global__ __launch_bounds__(256) void conv0_nhwc_kernel(
    const float* __restrict__ img,   // [2][5][256][256]
    const float* __restrict__ w0a,   // [16][4][3][3]
    const float* __restrict__ w0b,   // [48]
    unsigned short* __restrict__ ohi,  // [2][65536][64]
    unsigned short* __restrict__ olo)
{
  long t = (long)blockIdx.x * 256 + threadIdx.x;   // over 2*65536*64
  int c  = (int)(t & 63);
  int px = (int)((t >> 6) & (HPX - 1));
  int n  = (int)(t >> 22);
  const float* im = img + (long)n * 5 * HPX;
  float r;
  if (c < 48) {
    r = w0b[c] * im[2 * HPX + px];
  } else {
    int co = c - 48;
    int y = px >> 8, x = px & 255;
    r = 0.0f;
    const int map4[4] = {0, 1, 3, 4};
    #pragma unroll
    for (int fi = 0; fi < 4; fi++) {
      const float* imc = im + (long)map4[fi] * HPX;
      #pragma unroll
      for (int ky = 0; ky < 3; ky++) {
        int yy = y + ky - 1;
        #pragma unroll
        for (int kx = 0; kx < 3; kx++) {
          int xx = x + kx - 1;
          bool ok = ((unsigned)yy < 256u) && ((unsigned)xx < 256u);
          float v = ok ? imc[yy * 256 + xx] : 0.0f;
          r = fmaf(w0a[((co * 4 + fi) * 3 + ky) * 3 + kx], v, r);
        }
      }
    }
  }
  float v = gelu_f(r);
  unsigned short hb = f2bf(v);
  ohi[t] = hb;
  olo[t] = f2bf(v - bf2f(hb));
}

// ---------------- batched conv-weight packing into MFMA B-frags (hi,lo)
// frag layout: idx = ((((tap*2+kt)*4+nt)*2+s)*64 + lane)*8 + j
//   oc = nt*16 + (lane&15), ci = kt*32 + (lane>>4)*8 + j
// src layout: w[(oc*64+ci)*ntaps + tap]
struct JobArr { int4 j[29]; };   // {src_sel, src_off, ntaps, dst_off}

__global__ __launch_bounds__(256) void pack_conv_kernel(
    const float* __restrict__ cl10, const float* __restrict__ cl2,
    const float* __restrict__ first_p, const float* __restrict__ dilres_p,
    const float* __restrict__ dil_p, const float* __restrict__ ups_w,
    unsigned short* __restrict__ packs, JobArr jobs)
{
  int4 jb = jobs.j[blockIdx.y];
  int ntaps = jb.z;
  int idx = blockIdx.x * 256 + threadIdx.x;
  if (idx >= ntaps * 8192) return;
  int j  = idx & 7;
  int l  = (idx >> 3) & 63;
  int s  = (idx >> 9) & 1;
  int nt = (idx >> 10) & 3;
  int kt = (idx >> 12) & 1;
  int tap = idx >> 13;
  int oc = nt * 16 + (l & 15);
  int ci = kt * 32 + (l >> 4) * 8 + j;
  const float* src;
  switch (jb.x) {
    case 0: src = cl10; break;
    case 1: src = cl2; break;
    case 2: src = first_p; break;
    case 3: src = dilres_p; break;
    case 4: src = dil_p; break;
    default: src = ups_w; break;
  }
  float w = src[jb.y + (oc * 64 + ci) * ntaps + tap];
  unsigned short hi = f2bf(w);
  unsigned short v = (s == 0) ? hi : f2bf(w - bf2f(hi));
  packs[jb.w + idx] = v;
}

// ---------------- head weight packing (hi+lo), proven r6
__global__ __launch_bounds__(256) void pack_w1_kernel(
    const float* __restrict__ w1, unsigned short* __restrict__ w1p)
{
  int t = blockIdx.x * 256 + threadIdx.x;      // 18*18*512
  if (t >= 18 * 18 * 512) return;
  int j = t & 7, l = (t >> 3) & 63;
  int mt = (t >> 9) % 18, kt = (t >> 9) / 18;
  int oc = mt * 16 + (l & 15);
  int k  = kt * 32 + (l >> 4) * 8 + j;
  float w = w1[oc * 576 + k];
  unsigned short hi = f2bf(w);
  unsigned short lo = f2bf(w - bf2f(hi));
  long base = ((long)(kt * 18 + mt) * 2) * 512 + l * 8 + j;
  w1p[base] = hi;
  w1p[base + 512] = lo;
}
__global__ __launch_bounds__(256) void pack_w2_kernel(
    const float* __restrict__ w2, unsigned short* __restrict__ w2p)
{
  int t = blockIdx.x * 256 + threadIdx.x;      // 9*4*512
  if (t >= 9 * 4 * 512) return;
  int j = t & 7, l = (t >> 3) & 63;
  int ot = (t >> 9) % 4, kt = (t >> 9) / 4;
  int oc = ot * 16 + (l & 15);
  int k  = kt * 32 + (l >> 4) * 8 + j;
  float w = w2[oc * 288 + k];
  unsigned short hi = f2bf(w);
  unsigned short lo = f2bf(w - bf2f(hi));
  long base = ((long)(kt * 4 + ot) * 2) * 512 + l * 8 + j;
  w2p[base] = hi;
  w2p[base + 512] = lo;
}

// ---------------- universal MFMA conv (implicit GEMM, 16x16x32 bf16)
// NTAPS: 9 full 3x3 / 8 donut / 1 pointwise. MT: m-tiles per wave (16px each).
// BILIN: bilinear-sample input (scale Hs -> 256 output grid), for ups.
// TO_CONCAT: write single-bf16 into concat slice at column ccol; else write
// hi/lo act planes. RESID: pointwise residual (hi+lo) added pre-gelu;
// out may alias resid (pointwise read-then-write per thread).
// B-frags for the current tap are staged in LDS (16 KB), shared by all waves.
template <int NTAPS, int MT, bool RESID, bool BILIN, bool TO_CONCAT>
__global__ __launch_bounds__(256) void conv_mfma_kernel(
    const unsigned short* __restrict__ in_hi,   // NHWC [n][npx_in][64]
    const unsigned short* __restrict__ in_lo,
    const unsigned short* __restrict__ wp,      // packed frags
    const unsigned short* __restrict__ res_hi,
    const unsigned short* __restrict__ res_lo,
    unsigned short* __restrict__ out_hi,        // act hi or concat
    unsigned short* __restrict__ out_lo,
    int Hs, int logW, int dil, int ccol)
{
  __shared__ short8 wst[1024];                  // 16 KB: one tap's 16 frags
  const int tid  = threadIdx.x;
  const int lane = threadIdx.x & 63;
  const int wave = threadIdx.x >> 6;
  const int row  = lane & 15;
  const int g    = lane >> 4;
  const int n    = blockIdx.z;
  const int Ws   = 1 << logW;
  const int npx_in = Hs << logW;
  const int opx0 = blockIdx.x * (64 * MT) + wave * (16 * MT);

  const unsigned short* ihi = in_hi + (long)n * npx_in * 64;
  const unsigned short* ilo = in_lo + (long)n * npx_in * 64;
  const short8* wpv = (const short8*)wp;

  int ry[MT], rx[MT];
  int b00[MT], b01[MT], b10[MT], b11[MT];
  float bwx[MT], bwy[MT];
  #pragma unroll
  for (int mt = 0; mt < MT; mt++) {
    int p = opx0 + mt * 16 + row;
    if (BILIN) {
      int Y = p >> 8, X = p & 255;
      float sc = (float)Hs * (1.0f / 256.0f);
      float fy = ((float)Y + 0.5f) * sc - 0.5f;
      float fx = ((float)X + 0.5f) * sc - 0.5f;
      int y0 = (int)floorf(fy), x0 = (int)floorf(fx);
      bwy[mt] = fy - (float)y0; bwx[mt] = fx - (float)x0;
      int y0c = min(max(y0, 0), Hs - 1), y1c = min(max(y0 + 1, 0), Hs - 1);
      int x0c = min(max(x0, 0), Hs - 1), x1c = min(max(x0 + 1, 0), Hs - 1);
      b00[mt] = (y0c * Hs + x0c) * 64; b01[mt] = (y0c * Hs + x1c) * 64;
      b10[mt] = (y1c * Hs + x0c) * 64; b11[mt] = (y1c * Hs + x1c) * 64;
    } else {
      ry[mt] = p >> logW; rx[mt] = p & (Ws - 1);
    }
  }

  floatx4 acc[MT][4];
  #pragma unroll
  for (int mt = 0; mt < MT; mt++)
    #pragma unroll
    for (int nt = 0; nt < 4; nt++) acc[mt][nt] = (floatx4){0.f, 0.f, 0.f, 0.f};

  const short8 zz = {0, 0, 0, 0, 0, 0, 0, 0};

  #pragma unroll 1   // keep code size bounded; inner loops fully unrolled
  for (int t = 0; t < NTAPS; t++) {
    // ---- stage this tap's 16 B-frags (16 KB) into LDS, all 256 threads
    __syncthreads();   // previous tap's LDS reads complete
    #pragma unroll
    for (int p = 0; p < 4; p++)
      wst[tid + p * 256] = wpv[(long)t * 1024 + tid + p * 256];
    __syncthreads();

    int aoff[MT];
    if (!BILIN) {
      const int kk  = (NTAPS == 9) ? t : ((NTAPS == 8) ? (t < 4 ? t : t + 1) : 4);
      const int dyd = (kk / 3 - 1) * dil, dxd = (kk % 3 - 1) * dil;
      #pragma unroll
      for (int mt = 0; mt < MT; mt++) {
        int yy = ry[mt] + dyd, xx = rx[mt] + dxd;
        bool ok = ((unsigned)yy < (unsigned)Hs) && ((unsigned)xx < (unsigned)Ws);
        aoff[mt] = ok ? ((yy << logW) + xx) * 64 : -1;
      }
    }
    #pragma unroll
    for (int kt = 0; kt < 2; kt++) {
      const int ko = kt * 32 + g * 8;
      short8 ah[MT], al[MT];
      #pragma unroll
      for (int mt = 0; mt < MT; mt++) {
        if (BILIN) {
          short8 h00 = *(const short8*)(ihi + b00[mt] + ko);
          short8 l00 = *(const short8*)(ilo + b00[mt] + ko);
          short8 h01 = *(const short8*)(ihi + b01[mt] + ko);
          short8 l01 = *(const short8*)(ilo + b01[mt] + ko);
          short8 h10 = *(const short8*)(ihi + b10[mt] + ko);
          short8 l10 = *(const short8*)(ilo + b10[mt] + ko);
          short8 h11 = *(const short8*)(ihi + b11[mt] + ko);
          short8 l11 = *(const short8*)(ilo + b11[mt] + ko);
          short8 hh, ll;
          #pragma unroll
          for (int j = 0; j < 8; j++) {
            float v00 = bf2f((unsigned short)h00[j]) + bf2f((unsigned short)l00[j]);
            float v01 = bf2f((unsigned short)h01[j]) + bf2f((unsigned short)l01[j]);
            float v10 = bf2f((unsigned short)h10[j]) + bf2f((unsigned short)l10[j]);
            float v11 = bf2f((unsigned short)h11[j]) + bf2f((unsigned short)l11[j]);
            float v0 = v00 + bwx[mt] * (v01 - v00);
            float v1 = v10 + bwx[mt] * (v11 - v10);
            float v  = v0 + bwy[mt] * (v1 - v0);
            unsigned short hb = f2bf(v);
            hh[j] = (short)hb;
            ll[j] = (short)f2bf(v - bf2f(hb));
          }
          ah[mt] = hh; al[mt] = ll;
        } else {
          int ao = aoff[mt];
          long a = (long)(ao < 0 ? 0 : ao) + ko;
          short8 h = *(const short8*)(ihi + a);
          short8 l = *(const short8*)(ilo + a);
          ah[mt] = (ao < 0) ? zz : h;
          al[mt] = (ao < 0) ? zz : l;
        }
      }
      #pragma unroll
      for (int nt = 0; nt < 4; nt++) {
        short8 bh = wst[(kt * 512 + nt * 128 + 0) / 8 * 8 / 8 * 8 + 0];  // placeholder
        bh = wst[kt * 64 * 8 / 8 * 8 + 0];                               // placeholder
        bh = wst[(kt * 4 + nt) * 2 * 64 + 0 * 64 + lane];
        short8 bl = wst[((kt * 4 + nt) * 2 + 1) * 64 + lane];
        #pragma unroll
        for (int mt = 0; mt < MT; mt++) {
          acc[mt][nt] = __builtin_amdgcn_mfma_f32_16x16x32_bf16(ah[mt], bh, acc[mt][nt], 0, 0, 0);
          acc[mt][nt] = __builtin_amdgcn_mfma_f32_16x16x32_bf16(ah[mt], bl, acc[mt][nt], 0, 0, 0);
          acc[mt][nt] = __builtin_amdgcn_mfma_f32_16x16x32_bf16(al[mt], bh, acc[mt][nt], 0, 0, 0);
        }
      }
    }
  }

  // epilogue: (+resid) -> gelu -> store
  #pragma unroll
  for (int mt = 0; mt < MT; mt++) {
    #pragma unroll
    for (int nt = 0; nt < 4; nt++) {
      #pragma unroll
      for (int r = 0; r < 4; r++) {
        int px = opx0 + mt * 16 + g * 4 + r;
        int oc = nt * 16 + row;
        float v = acc[mt][nt][r];
        if (RESID) {
          long ri = ((long)n * npx_in + px) * 64 + oc;
          v += bf2f(res_hi[ri]) + bf2f(res_lo[ri]);
        }
        v = gelu_f(v);
        if (TO_CONCAT) {
          out_hi[((long)n * HPX + px) * 576 + ccol + oc] = f2bf(v);
        } else {
          long oi = ((long)n * npx_in + px) * 64 + oc;
          unsigned short hb = f2bf(v);
          out_hi[oi] = hb;
          out_lo[oi] = f2bf(v - bf2f(hb));
        }
      }
    }
  }
}

// ---------------- 2x2 average pool, NHWC hi/lo -> NHWC hi/lo
__global__ __launch_bounds__(256) void avgpool_nhwc_kernel(
    const unsigned short* __restrict__ ihi, const unsigned short* __restrict__ ilo,
    unsigned short* __restrict__ ohi, unsigned short* __restrict__ olo,
    int logWo)
{
  const int lognpo = 2 * logWo;
  long t = (long)blockIdx.x * 256 + threadIdx.x;   // over 2*npo*8
  int cg = (int)(t & 7);
  int p  = (int)((t >> 3) & ((1 << lognpo) - 1));
  int n  = (int)(t >> (3 + lognpo));
  int y = p >> logWo, x = p & ((1 << logWo) - 1);
  int Wi = 2 << logWo;
  long ib = ((long)n * (4 << lognpo) + (long)(2 * y) * Wi + 2 * x) * 64 + cg * 8;
  short8 h00 = *(const short8*)(ihi + ib);
  short8 h01 = *(const short8*)(ihi + ib + 64);
  short8 h10 = *(const short8*)(ihi + ib + (long)Wi * 64);
  short8 h11 = *(const short8*)(ihi + ib + (long)Wi * 64 + 64);
  short8 l00 = *(const short8*)(ilo + ib);
  short8 l01 = *(const short8*)(ilo + ib + 64);
  short8 l10 = *(const short8*)(ilo + ib + (long)Wi * 64);
  short8 l11 = *(const short8*)(ilo + ib + (long)Wi * 64 + 64);
  short8 oh, ol;
  #pragma unroll
  for (int j = 0; j < 8; j++) {
    float v = 0.25f * ((bf2f((unsigned short)h00[j]) + bf2f((unsigned short)l00[j])) +
                       (bf2f((unsigned short)h01[j]) + bf2f((unsigned short)l01[j])) +
                       (bf2f((unsigned short)h10[j]) + bf2f((unsigned short)l10[j])) +
                       (bf2f((unsigned short)h11[j]) + bf2f((unsigned short)l11[j])));
    unsigned short hb = f2bf(v);
    oh[j] = (short)hb;
    ol[j] = (short)f2bf(v - bf2f(hb));
  }
  long ob = (((long)n << lognpo) + p) * 64 + cg * 8;
  *(short8*)(ohi + ob) = oh;
  *(short8*)(olo + ob) = ol;
}

// ---------------- MFMA head: out = w3 . gelu(W2 @ gelu(W1 @ V))  (NHWC concat)
__global__ __launch_bounds__(256, 2) void head_mfma_kernel(
    const unsigned short* __restrict__ v,       // NHWC [2][65536][576] bf16
    const unsigned short* __restrict__ w1p,
    const unsigned short* __restrict__ w2p,
    const float* __restrict__ w3,               // [64]
    float* __restrict__ out)                    // [2][65536]
{
  __shared__ unsigned short hs[128][296];       // 75,776 B
  const int lane = threadIdx.x & 63;
  const int wave = threadIdx.x >> 6;
  const int col  = lane & 15;
  const int g    = lane >> 4;
  const int n    = blockIdx.y;
  const int pxb  = blockIdx.x * 128;
  const unsigned short* vn = v + ((long)n * HPX + pxb + wave * 32) * 576;
  const short8* w1v = (const short8*)w1p;
  const short8* w2v = (const short8*)w2p;

  floatx4 acc[2][18];
  #pragma unroll
  for (int t = 0; t < 2; t++)
    #pragma unroll
    for (int mt = 0; mt < 18; mt++) acc[t][mt] = (floatx4){0.f, 0.f, 0.f, 0.f};

  for (int kt = 0; kt < 18; kt++) {
    const int ko = kt * 32 + g * 8;
    short8 a0 = *(const short8*)(vn + (long)col * 576 + ko);
    short8 a1 = *(const short8*)(vn + (long)(col + 16) * 576 + ko);
    #pragma unroll
    for (int mt = 0; mt < 18; mt++) {
      short8 bhi = w1v[((kt * 18 + mt) * 2 + 0) * 64 + lane];
      short8 blo = w1v[((kt * 18 + mt) * 2 + 1) * 64 + lane];
      acc[0][mt] = __builtin_amdgcn_mfma_f32_16x16x32_bf16(a0, bhi, acc[0][mt], 0, 0, 0);
      acc[0][mt] = __builtin_amdgcn_mfma_f32_16x16x32_bf16(a0, blo, acc[0][mt], 0, 0, 0);
      acc[1][mt] = __builtin_amdgcn_mfma_f32_16x16x32_bf16(a1, bhi, acc[1][mt], 0, 0, 0);
      acc[1][mt] = __builtin_amdgcn_mfma_f32_16x16x32_bf16(a1, blo, acc[1][mt], 0, 0, 0);
    }
  }
  #pragma unroll
  for (int t = 0; t < 2; t++)
    #pragma unroll
    for (int mt = 0; mt < 18; mt++)
      #pragma unroll
      for (int r = 0; r < 4; r++)
        hs[wave * 32 + t * 16 + g * 4 + r][mt * 16 + col] =
            f2bf(gelu_f(acc[t][mt][r]));
  __syncthreads();

  floatx4 acc2[2][4];
  #pragma unroll
  for (int t = 0; t < 2; t++)
    #pragma unroll
    for (int ot = 0; ot < 4; ot++) acc2[t][ot] = (floatx4){0.f, 0.f, 0.f, 0.f};

  for (int kt = 0; kt < 9; kt++) {
    short8 a[2];
    #pragma unroll
    for (int t = 0; t < 2; t++)
      a[t] = *(const short8*)&hs[wave * 32 + t * 16 + col][kt * 32 + g * 8];
    #pragma unroll
    for (int ot = 0; ot < 4; ot++) {
      short8 bhi = w2v[((kt * 4 + ot) * 2 + 0) * 64 + lane];
      short8 blo = w2v[((kt * 4 + ot) * 2 + 1) * 64 + lane];
      acc2[0][ot] = __builtin_amdgcn_mfma_f32_16x16x32_bf16(a[0], bhi, acc2[0][ot], 0, 0, 0);
      acc2[0][ot] = __builtin_amdgcn_mfma_f32_16x16x32_bf16(a[0], blo, acc2[0][ot], 0, 0, 0);
      acc2[1][ot] = __builtin_amdgcn_mfma_f32_16x16x32_bf16(a[1], bhi, acc2[1][ot], 0, 0, 0);
      acc2[1][ot] = __builtin_amdgcn_mfma_f32_16x16x32_bf16(a[1], blo, acc2[1][ot], 0, 0, 0);
    }
  }

  float w3r[4];
  #pragma unroll
  for (int ot = 0; ot < 4; ot++) w3r[ot] = w3[ot * 16 + col];
  #pragma unroll
  for (int t = 0; t < 2; t++) {
    float r[4] = {0.f, 0.f, 0.f, 0.f};
    #pragma unroll
    for (int ot = 0; ot < 4; ot++)
      #pragma unroll
      for (int rr = 0; rr < 4; rr++)
        r[rr] = fmaf(w3r[ot], gelu_f(acc2[t][ot][rr]), r[rr]);
    #pragma unroll
    for (int rr = 0; rr < 4; rr++) {
      r[rr] += __shfl_xor(r[rr], 1);
      r[rr] += __shfl_xor(r[rr], 2);
      r[rr] += __shfl_xor(r[rr], 4);
      r[rr] += __shfl_xor(r[rr], 8);
    }
    if (col == 0) {
      int px = pxb + wave * 32 + t * 16 + g * 4;
      #pragma unroll
      for (int rr = 0; rr < 4; rr++)
        out[(long)n * HPX + px + rr] = r[rr];
    }
  }
}

// ---------------------------------------------------------------------------
extern "C" void kernel_launch(void* const* d_in, const int* in_sizes, int n_in,
                              void* d_out, int out_size, void* d_ws, size_t ws_size,
                              hipStream_t stream) {
  const float* img      = (const float*)d_in[0];
  const float* w0a      = (const float*)d_in[1];
  const float* w0b      = (const float*)d_in[2];
  const float* first_p  = (const float*)d_in[3];
  const float* cl10     = (const float*)d_in[4];   // [4][2][64][64][9]
  const float* cl2      = (const float*)d_in[5];
  const float* dil_p    = (const float*)d_in[6];   // [4][64][64][8]
  const float* dilres_p = (const float*)d_in[7];
  const float* ups_w    = (const float*)d_in[8];   // [4][64][64]
  const float* w1       = (const float*)d_in[9];   // [288][576]
  const float* w2       = (const float*)d_in[10];  // [64][288]
  const float* w3       = (const float*)d_in[11];  // [64]

  const size_t CONCAT_B = 150994944ul;             // 2*65536*576*2
  const size_t ACT_B    = 16777216ul;              // 2*65536*64*2 per plane
  const size_t PACKS_B  = 3604480ul;               // 1,802,240 elems
  const size_t W1P_B    = 663552ul;
  const size_t W2P_B    = 73728ul;
  const size_t NEED = CONCAT_B + 4 * ACT_B + PACKS_B + W1P_B + W2P_B; // 222,445,568

  if (ws_size < NEED) {
    hipMemsetAsync(d_out, 0, (size_t)out_size * 4, stream);
    return;
  }

  char* wsb = (char*)d_ws;
  unsigned short* concat = (unsigned short*)wsb;
  unsigned short* Xhi = (unsigned short*)(wsb + CONCAT_B);
  unsigned short* Xlo = (unsigned short*)(wsb + CONCAT_B + ACT_B);
  unsigned short* Yhi = (unsigned short*)(wsb + CONCAT_B + 2 * ACT_B);
  unsigned short* Ylo = (unsigned short*)(wsb + CONCAT_B + 3 * ACT_B);
  unsigned short* packs = (unsigned short*)(wsb + CONCAT_B + 4 * ACT_B);
  unsigned short* w1p = (unsigned short*)(wsb + CONCAT_B + 4 * ACT_B + PACKS_B);
  unsigned short* w2p = (unsigned short*)(wsb + CONCAT_B + 4 * ACT_B + PACKS_B + W1P_B);

  // pack-destination offsets (elems)
  auto off_cl10   = [](int c) { return (long)c * 73728; };
  auto off_cl2    = [](int c) { return 589824l + (long)c * 73728; };
  const long OFF_FIRST = 1179648;
  auto off_dilres = [](int k) { return 1245184l + (long)k * 65536; };
  auto off_dil    = [](int k) { return 1507328l + (long)k * 65536; };
  auto off_ups    = [](int k) { return 1769472l + (long)k * 8192; };

  // ---- weight packing (one batched kernel + head packs)
  JobArr jobs;
  for (int c = 0; c < 8; c++) jobs.j[c]     = {0, c * 36864, 9, (int)off_cl10(c)};
  for (int c = 0; c < 8; c++) jobs.j[8 + c] = {1, c * 36864, 9, (int)off_cl2(c)};
  jobs.j[16] = {2, 0, 8, (int)OFF_FIRST};
  for (int k = 0; k < 4; k++) jobs.j[17 + k] = {3, k * 32768, 8, (int)off_dilres(k)};
  for (int k = 0; k < 4; k++) jobs.j[21 + k] = {4, k * 32768, 8, (int)off_dil(k)};
  for (int k = 0; k < 4; k++) jobs.j[25 + k] = {5, k * 4096, 1, (int)off_ups(k)};
  pack_conv_kernel<<<dim3(288, 29), 256, 0, stream>>>(
      cl10, cl2, first_p, dilres_p, dil_p, ups_w, packs, jobs);
  pack_w1_kernel<<<(18 * 18 * 512 + 255) / 256, 256, 0, stream>>>(w1, w1p);
  pack_w2_kernel<<<(9 * 4 * 512 + 255) / 256, 256, 0, stream>>>(w2, w2p);

  // ---- conv0 -> X @256
  conv0_nhwc_kernel<<<(2 * HPX * 64) / 256, 256, 0, stream>>>(img, w0a, w0b, Xhi, Xlo);

  // ---- launch helpers
  auto conv9_4 = [&](const unsigned short* ih, const unsigned short* il, long wo,
                     unsigned short* oh, unsigned short* ol) {
    conv_mfma_kernel<9, 4, false, false, false><<<dim3(256, 1, 2), 256, 0, stream>>>(
        ih, il, packs + wo, nullptr, nullptr, oh, ol, 256, 8, 1, 0);
  };
  auto conv9r_4 = [&](const unsigned short* ih, const unsigned short* il, long wo,
                      unsigned short* rh, unsigned short* rl) {
    conv_mfma_kernel<9, 4, true, false, false><<<dim3(256, 1, 2), 256, 0, stream>>>(
        ih, il, packs + wo, rh, rl, rh, rl, 256, 8, 1, 0);
  };
  auto conv9_2 = [&](const unsigned short* ih, const unsigned short* il, long wo,
                     unsigned short* oh, unsigned short* ol, int Hs, int logW) {
    conv_mfma_kernel<9, 2, false, false, false><<<dim3((Hs << logW) / 128, 1, 2), 256, 0, stream>>>(
        ih, il, packs + wo, nullptr, nullptr, oh, ol, Hs, logW, 1, 0);
  };
  auto conv9r_2 = [&](const unsigned short* ih, const unsigned short* il, long wo,
                      unsigned short* rh, unsigned short* rl, int Hs, int logW) {
    conv_mfma_kernel<9, 2, true, false, false><<<dim3((Hs << logW) / 128, 1, 2), 256, 0, stream>>>(
        ih, il, packs + wo, rh, rl, rh, rl, Hs, logW, 1, 0);
  };
  auto donutC = [&](const unsigned short* ih, const unsigned short* il, long wo,
                    int dil, int ccol) {  // @256 -> concat
    conv_mfma_kernel<8, 4, false, false, true><<<dim3(256, 1, 2), 256, 0, stream>>>(
        ih, il, packs + wo, nullptr, nullptr, concat, nullptr, 256, 8, dil, ccol);
  };
  auto donutA_4 = [&](const unsigned short* ih, const unsigned short* il, long wo,
                      int dil, unsigned short* oh, unsigned short* ol) {  // @256
    conv_mfma_kernel<8, 4, false, false, false><<<dim3(256, 1, 2), 256, 0, stream>>>(
        ih, il, packs + wo, nullptr, nullptr, oh, ol, 256, 8, dil, 0);
  };
  auto donutA_2 = [&](const unsigned short* ih, const unsigned short* il, long wo,
                      int dil, unsigned short* oh, unsigned short* ol, int Hs, int logW) {
    conv_mfma_kernel<8, 2, false, false, false><<<dim3((Hs << logW) / 128, 1, 2), 256, 0, stream>>>(
        ih, il, packs + wo, nullptr, nullptr, oh, ol, Hs, logW, dil, 0);
  };
  auto upsC = [&](const unsigned short* ih, const unsigned short* il, long wo,
                  int Hs, int logW, int ccol) {
    conv_mfma_kernel<1, 4, false, true, true><<<dim3(256, 1, 2), 256, 0, stream>>>(
        ih, il, packs + wo, nullptr, nullptr, concat, nullptr, Hs, logW, 1, ccol);
  };
  auto avgp = [&](const unsigned short* ih, const unsigned short* il,
                  unsigned short* oh, unsigned short* ol, int logWo) {
    long total = 2l * (1l << (2 * logWo)) * 8;
    avgpool_nhwc_kernel<<<(int)(total / 256), 256, 0, stream>>>(ih, il, oh, ol, logWo);
  };

  // ---- @256: outs[0], resblock cl10[0], outs[1], resblock cl2[0]
  donutC(Xhi, Xlo, OFF_FIRST, 1, 0);
  conv9_4(Xhi, Xlo, off_cl10(0), Yhi, Ylo);
  conv9r_4(Yhi, Ylo, off_cl10(1), Xhi, Xlo);                 // base = X @256
  donutC(Xhi, Xlo, off_dilres(0), 3, 64);
  conv9_4(Xhi, Xlo, off_cl2(0), Yhi, Ylo);
  conv9r_4(Yhi, Ylo, off_cl2(1), Xhi, Xlo);                  // base = X @256

  // ---- i = 0 (dil 5 @256)
  donutA_4(Xhi, Xlo, off_dil(0), 5, Yhi, Ylo);
  upsC(Yhi, Ylo, off_ups(0), 256, 8, 128);
  avgp(Xhi, Xlo, Yhi, Ylo, 7);                               // base = Y @128
  conv9_2(Yhi, Ylo, off_cl10(2), Xhi, Xlo, 128, 7);
  conv9r_2(Xhi, Xlo, off_cl10(3), Yhi, Ylo, 128, 7);         // base = Y @128
  donutA_2(Yhi, Ylo, off_dilres(1), 6, Xhi, Xlo, 128, 7);
  upsC(Xhi, Xlo, off_ups(1), 128, 7, 192);
  conv9_2(Yhi, Ylo, off_cl2(2), Xhi, Xlo, 128, 7);
  conv9r_2(Xhi, Xlo, off_cl2(3), Yhi, Ylo, 128, 7);          // base = Y @128

  // ---- i = 1 (dil 8 @128)
  donutA_2(Yhi, Ylo, off_dil(1), 8, Xhi, Xlo, 128, 7);
  upsC(Xhi, Xlo, off_ups(1), 128, 7, 256);
  avgp(Yhi, Ylo, Xhi, Xlo, 6);                               // base = X @64
  conv9_2(Xhi, Xlo, off_cl10(4), Yhi, Ylo, 64, 6);
  conv9r_2(Yhi, Ylo, off_cl10(5), Xhi, Xlo, 64, 6);          // base = X @64
  donutA_2(Xhi, Xlo, off_dilres(2), 8, Yhi, Ylo, 64, 6);
  upsC(Yhi, Ylo, off_ups(2), 64, 6, 320);
  conv9_2(Xhi, Xlo, off_cl2(4), Yhi, Ylo, 64, 6);
  conv9r_2(Yhi, Ylo, off_cl2(5), Xhi, Xlo, 64, 6);           // base = X @64

  // ---- i = 2 (dil 10 @64)
  donutA_2(Xhi, Xlo, off_dil(2), 10, Yhi, Ylo, 64, 6);
  upsC(Yhi, Ylo, off_ups(2), 64, 6, 384);
  avgp(Xhi, Xlo, Yhi, Ylo, 5);                               // base = Y @32
  conv9_2(Yhi, Ylo, off_cl10(6), Xhi, Xlo, 32, 5);
  conv9r_2(Xhi, Xlo, off_cl10(7), Yhi, Ylo, 32, 5);          // base = Y @32
  donutA_2(Yhi, Ylo, off_dilres(3), 9, Xhi, Xlo, 32, 5);
  upsC(Xhi, Xlo, off_ups(3), 32, 5, 448);
  conv9_2(Yhi, Ylo, off_cl2(6), Xhi, Xlo, 32, 5);
  conv9r_2(Xhi, Xlo, off_cl2(7), Yhi, Ylo, 32, 5);           // base = Y @32

  // ---- i = 3 (dil 11 @32)
  donutA_2(Yhi, Ylo, off_dil(3), 11, Xhi, Xlo, 32, 5);
  upsC(Xhi, Xlo, off_ups(3), 32, 5, 512);

  // ---- MFMA head
  head_mfma_kernel<<<dim3(512, 2), 256, 0, stream>>>(concat, w1p, w2p, w3,
                                                     (float*)d_out);
}

// Round 9
// 1134.707 us; speedup vs baseline: 5.6370x; 1.1042x over previous
//
#include <hip/hip_runtime.h>
#include <hip/hip_bf16.h>

// ---------------------------------------------------------------------------
// SHINE forward, full bf16-MFMA version with hi/lo-split activations+weights.
// Workspace (222,445,568 B total):
//   concat : bf16 NHWC [2][65536][576]          150,994,944 B
//   Xhi,Xlo,Yhi,Ylo : bf16 NHWC [2][65536][64]  4 x 16,777,216 B
//   packs  : conv B-frags (hi,lo)                 3,604,480 B
//   w1p    : head W1 frags                          663,552 B
//   w2p    : head W2 frags                           73,728 B
// R9: conv kernels software-pipelined: double-buffered LDS weight stage
//     (issue-early / write-late, ONE barrier per tap) + A-fragment register
//     prefetch one tap ahead. Math order identical to R8 (same absmax).
// ---------------------------------------------------------------------------

#define HPX 65536   // 256*256
#define FCH 64

typedef __attribute__((ext_vector_type(8))) short  short8;
typedef __attribute__((ext_vector_type(4))) float  floatx4;

__device__ __forceinline__ float gelu_f(float x) {
  return 0.5f * x * (1.0f + erff(x * 0.70710678118654752440f));
}
__device__ __forceinline__ unsigned short f2bf(float x) {  // RNE
  unsigned u = __float_as_uint(x);
  unsigned r = (u + 0x7FFFu + ((u >> 16) & 1u)) >> 16;
  return (unsigned short)r;
}
__device__ __forceinline__ float bf2f(unsigned short h) {
  return __uint_as_float(((unsigned)h) << 16);
}

// ---------------- conv0: base = concat(gelu(1x1(target)), gelu(3x3(feats)))
__global__ __launch_bounds__(256) void conv0_nhwc_kernel(
    const float* __restrict__ img,   // [2][5][256][256]
    const float* __restrict__ w0a,   // [16][4][3][3]
    const float* __restrict__ w0b,   // [48]
    unsigned short* __restrict__ ohi,  // [2][65536][64]
    unsigned short* __restrict__ olo)
{
  long t = (long)blockIdx.x * 256 + threadIdx.x;   // over 2*65536*64
  int c  = (int)(t & 63);
  int px = (int)((t >> 6) & (HPX - 1));
  int n  = (int)(t >> 22);
  const float* im = img + (long)n * 5 * HPX;
  float r;
  if (c < 48) {
    r = w0b[c] * im[2 * HPX + px];
  } else {
    int co = c - 48;
    int y = px >> 8, x = px & 255;
    r = 0.0f;
    const int map4[4] = {0, 1, 3, 4};
    #pragma unroll
    for (int fi = 0; fi < 4; fi++) {
      const float* imc = im + (long)map4[fi] * HPX;
      #pragma unroll
      for (int ky = 0; ky < 3; ky++) {
        int yy = y + ky - 1;
        #pragma unroll
        for (int kx = 0; kx < 3; kx++) {
          int xx = x + kx - 1;
          bool ok = ((unsigned)yy < 256u) && ((unsigned)xx < 256u);
          float v = ok ? imc[yy * 256 + xx] : 0.0f;
          r = fmaf(w0a[((co * 4 + fi) * 3 + ky) * 3 + kx], v, r);
        }
      }
    }
  }
  float v = gelu_f(r);
  unsigned short hb = f2bf(v);
  ohi[t] = hb;
  olo[t] = f2bf(v - bf2f(hb));
}

// ---------------- batched conv-weight packing into MFMA B-frags (hi,lo)
// frag layout: idx = ((((tap*2+kt)*4+nt)*2+s)*64 + lane)*8 + j
//   oc = nt*16 + (lane&15), ci = kt*32 + (lane>>4)*8 + j
struct JobArr { int4 j[29]; };   // {src_sel, src_off, ntaps, dst_off}

__global__ __launch_bounds__(256) void pack_conv_kernel(
    const float* __restrict__ cl10, const float* __restrict__ cl2,
    const float* __restrict__ first_p, const float* __restrict__ dilres_p,
    const float* __restrict__ dil_p, const float* __restrict__ ups_w,
    unsigned short* __restrict__ packs, JobArr jobs)
{
  int4 jb = jobs.j[blockIdx.y];
  int ntaps = jb.z;
  int idx = blockIdx.x * 256 + threadIdx.x;
  if (idx >= ntaps * 8192) return;
  int j  = idx & 7;
  int l  = (idx >> 3) & 63;
  int s  = (idx >> 9) & 1;
  int nt = (idx >> 10) & 3;
  int kt = (idx >> 12) & 1;
  int tap = idx >> 13;
  int oc = nt * 16 + (l & 15);
  int ci = kt * 32 + (l >> 4) * 8 + j;
  const float* src;
  switch (jb.x) {
    case 0: src = cl10; break;
    case 1: src = cl2; break;
    case 2: src = first_p; break;
    case 3: src = dilres_p; break;
    case 4: src = dil_p; break;
    default: src = ups_w; break;
  }
  float w = src[jb.y + (oc * 64 + ci) * ntaps + tap];
  unsigned short hi = f2bf(w);
  unsigned short v = (s == 0) ? hi : f2bf(w - bf2f(hi));
  packs[jb.w + idx] = v;
}

// ---------------- head weight packing (hi+lo), proven r6
__global__ __launch_bounds__(256) void pack_w1_kernel(
    const float* __restrict__ w1, unsigned short* __restrict__ w1p)
{
  int t = blockIdx.x * 256 + threadIdx.x;      // 18*18*512
  if (t >= 18 * 18 * 512) return;
  int j = t & 7, l = (t >> 3) & 63;
  int mt = (t >> 9) % 18, kt = (t >> 9) / 18;
  int oc = mt * 16 + (l & 15);
  int k  = kt * 32 + (l >> 4) * 8 + j;
  float w = w1[oc * 576 + k];
  unsigned short hi = f2bf(w);
  unsigned short lo = f2bf(w - bf2f(hi));
  long base = ((long)(kt * 18 + mt) * 2) * 512 + l * 8 + j;
  w1p[base] = hi;
  w1p[base + 512] = lo;
}
__global__ __launch_bounds__(256) void pack_w2_kernel(
    const float* __restrict__ w2, unsigned short* __restrict__ w2p)
{
  int t = blockIdx.x * 256 + threadIdx.x;      // 9*4*512
  if (t >= 9 * 4 * 512) return;
  int j = t & 7, l = (t >> 3) & 63;
  int ot = (t >> 9) % 4, kt = (t >> 9) / 4;
  int oc = ot * 16 + (l & 15);
  int k  = kt * 32 + (l >> 4) * 8 + j;
  float w = w2[oc * 288 + k];
  unsigned short hi = f2bf(w);
  unsigned short lo = f2bf(w - bf2f(hi));
  long base = ((long)(kt * 4 + ot) * 2) * 512 + l * 8 + j;
  w2p[base] = hi;
  w2p[base + 512] = lo;
}

// ---------------- software-pipelined MFMA conv (implicit GEMM, 16x16x32 bf16)
// NTAPS: 9 full 3x3 / 8 donut. MT m-tiles (16 px) per wave.
// Pipeline per tap: {issue stage-loads(t+1) + A-loads(t+1)} -> compute(t)
// -> {ds_write stage(t+1) into buf^1} -> ONE barrier. Static A-reg parity
// (full unroll) avoids scratch. Math order identical to r8.
template <int NTAPS, int MT, bool RESID, bool TO_CONCAT>
__global__ __launch_bounds__(256) void conv_pipe_kernel(
    const unsigned short* __restrict__ in_hi,   // NHWC [n][npx_in][64]
    const unsigned short* __restrict__ in_lo,
    const unsigned short* __restrict__ wp,      // packed frags
    const unsigned short* __restrict__ res_hi,
    const unsigned short* __restrict__ res_lo,
    unsigned short* __restrict__ out_hi,        // act hi or concat
    unsigned short* __restrict__ out_lo,
    int Hs, int logW, int dil, int ccol)
{
  __shared__ short8 wst[2][1024];               // 2 x 16 KB double buffer
  const int tid  = threadIdx.x;
  const int lane = tid & 63;
  const int wave = tid >> 6;
  const int row  = lane & 15;
  const int g    = lane >> 4;
  const int n    = blockIdx.z;
  const int Ws   = 1 << logW;
  const int npx_in = Hs << logW;
  const int opx0 = blockIdx.x * (64 * MT) + wave * (16 * MT);

  const unsigned short* ihi = in_hi + (long)n * npx_in * 64;
  const unsigned short* ilo = in_lo + (long)n * npx_in * 64;
  const short8* wpv = (const short8*)wp;

  int ry[MT], rx[MT];
  #pragma unroll
  for (int mt = 0; mt < MT; mt++) {
    int p = opx0 + mt * 16 + row;
    ry[mt] = p >> logW;
    rx[mt] = p & (Ws - 1);
  }

  floatx4 acc[MT][4];
  #pragma unroll
  for (int mt = 0; mt < MT; mt++)
    #pragma unroll
    for (int nt = 0; nt < 4; nt++) acc[mt][nt] = (floatx4){0.f, 0.f, 0.f, 0.f};

  const short8 zz = {0, 0, 0, 0, 0, 0, 0, 0};
  short8 sreg[4];
  short8 ahA[MT][2], alA[MT][2], ahB[MT][2], alB[MT][2];

  auto stage_issue = [&](int t) {
    #pragma unroll
    for (int p = 0; p < 4; p++)
      sreg[p] = wpv[(long)t * 1024 + tid + p * 256];
  };
  auto stage_write = [&](int b) {
    #pragma unroll
    for (int p = 0; p < 4; p++)
      wst[b][tid + p * 256] = sreg[p];
  };
  auto a_load = [&](short8 (&ah)[MT][2], short8 (&al)[MT][2], int t) {
    const int kk  = (NTAPS == 9) ? t : (t < 4 ? t : t + 1);
    const int dyd = (kk / 3 - 1) * dil, dxd = (kk % 3 - 1) * dil;
    #pragma unroll
    for (int mt = 0; mt < MT; mt++) {
      int yy = ry[mt] + dyd, xx = rx[mt] + dxd;
      bool ok = ((unsigned)yy < (unsigned)Hs) && ((unsigned)xx < (unsigned)Ws);
      long base = ok ? (long)((yy << logW) + xx) * 64 : 0;
      #pragma unroll
      for (int kt = 0; kt < 2; kt++) {
        long a = base + kt * 32 + g * 8;
        short8 h = *(const short8*)(ihi + a);
        short8 l = *(const short8*)(ilo + a);
        ah[mt][kt] = ok ? h : zz;
        al[mt][kt] = ok ? l : zz;
      }
    }
  };
  auto compute = [&](int b, short8 (&ah)[MT][2], short8 (&al)[MT][2]) {
    #pragma unroll
    for (int kt = 0; kt < 2; kt++)
      #pragma unroll
      for (int nt = 0; nt < 4; nt++) {
        short8 bh = wst[b][(kt * 4 + nt) * 128 + lane];
        short8 bl = wst[b][(kt * 4 + nt) * 128 + 64 + lane];
        #pragma unroll
        for (int mt = 0; mt < MT; mt++) {
          acc[mt][nt] = __builtin_amdgcn_mfma_f32_16x16x32_bf16(ah[mt][kt], bh, acc[mt][nt], 0, 0, 0);
          acc[mt][nt] = __builtin_amdgcn_mfma_f32_16x16x32_bf16(ah[mt][kt], bl, acc[mt][nt], 0, 0, 0);
          acc[mt][nt] = __builtin_amdgcn_mfma_f32_16x16x32_bf16(al[mt][kt], bh, acc[mt][nt], 0, 0, 0);
        }
      }
  };

  // prologue: stage + A for tap 0
  stage_issue(0);
  a_load(ahA, alA, 0);
  stage_write(0);
  __syncthreads();

  #pragma unroll
  for (int tt = 0; tt < NTAPS; tt++) {
    const int b = tt & 1;
    if (tt + 1 < NTAPS) {
      stage_issue(tt + 1);                       // global loads, early
      if ((tt & 1) == 0) a_load(ahB, alB, tt + 1);
      else               a_load(ahA, alA, tt + 1);
    }
    if ((tt & 1) == 0) compute(b, ahA, alA);     // hides the loads above
    else               compute(b, ahB, alB);
    if (tt + 1 < NTAPS) {
      stage_write(b ^ 1);                        // write-late into other buf
      __syncthreads();                           // ONE barrier per tap
    }
  }

  // epilogue: (+resid) -> gelu -> store
  #pragma unroll
  for (int mt = 0; mt < MT; mt++) {
    #pragma unroll
    for (int nt = 0; nt < 4; nt++) {
      #pragma unroll
      for (int r = 0; r < 4; r++) {
        int px = opx0 + mt * 16 + g * 4 + r;
        int oc = nt * 16 + row;
        float v = acc[mt][nt][r];
        if (RESID) {
          long ri = ((long)n * npx_in + px) * 64 + oc;
          v += bf2f(res_hi[ri]) + bf2f(res_lo[ri]);
        }
        v = gelu_f(v);
        if (TO_CONCAT) {
          out_hi[((long)n * HPX + px) * 576 + ccol + oc] = f2bf(v);
        } else {
          long oi = ((long)n * npx_in + px) * 64 + oc;
          unsigned short hb = f2bf(v);
          out_hi[oi] = hb;
          out_lo[oi] = f2bf(v - bf2f(hb));
        }
      }
    }
  }
}

// ---------------- bilinear-upsample 1x1 conv (NTAPS=1), unchanged from r8
template <int NTAPS, int MT, bool RESID, bool BILIN, bool TO_CONCAT>
__global__ __launch_bounds__(256) void conv_mfma_kernel(
    const unsigned short* __restrict__ in_hi,   // NHWC [n][npx_in][64]
    const unsigned short* __restrict__ in_lo,
    const unsigned short* __restrict__ wp,      // packed frags
    const unsigned short* __restrict__ res_hi,
    const unsigned short* __restrict__ res_lo,
    unsigned short* __restrict__ out_hi,        // act hi or concat
    unsigned short* __restrict__ out_lo,
    int Hs, int logW, int dil, int ccol)
{
  __shared__ short8 wst[1024];                  // 16 KB: one tap's 16 frags
  const int tid  = threadIdx.x;
  const int lane = threadIdx.x & 63;
  const int wave = threadIdx.x >> 6;
  const int row  = lane & 15;
  const int g    = lane >> 4;
  const int n    = blockIdx.z;
  const int npx_in = Hs << logW;
  const int opx0 = blockIdx.x * (64 * MT) + wave * (16 * MT);

  const unsigned short* ihi = in_hi + (long)n * npx_in * 64;
  const unsigned short* ilo = in_lo + (long)n * npx_in * 64;
  const short8* wpv = (const short8*)wp;

  int b00[MT], b01[MT], b10[MT], b11[MT];
  float bwx[MT], bwy[MT];
  #pragma unroll
  for (int mt = 0; mt < MT; mt++) {
    int p = opx0 + mt * 16 + row;
    int Y = p >> 8, X = p & 255;
    float sc = (float)Hs * (1.0f / 256.0f);
    float fy = ((float)Y + 0.5f) * sc - 0.5f;
    float fx = ((float)X + 0.5f) * sc - 0.5f;
    int y0 = (int)floorf(fy), x0 = (int)floorf(fx);
    bwy[mt] = fy - (float)y0; bwx[mt] = fx - (float)x0;
    int y0c = min(max(y0, 0), Hs - 1), y1c = min(max(y0 + 1, 0), Hs - 1);
    int x0c = min(max(x0, 0), Hs - 1), x1c = min(max(x0 + 1, 0), Hs - 1);
    b00[mt] = (y0c * Hs + x0c) * 64; b01[mt] = (y0c * Hs + x1c) * 64;
    b10[mt] = (y1c * Hs + x0c) * 64; b11[mt] = (y1c * Hs + x1c) * 64;
  }

  floatx4 acc[MT][4];
  #pragma unroll
  for (int mt = 0; mt < MT; mt++)
    #pragma unroll
    for (int nt = 0; nt < 4; nt++) acc[mt][nt] = (floatx4){0.f, 0.f, 0.f, 0.f};

  // stage the single tap's 16 B-frags
  #pragma unroll
  for (int p = 0; p < 4; p++)
    wst[tid + p * 256] = wpv[tid + p * 256];
  __syncthreads();

  #pragma unroll
  for (int kt = 0; kt < 2; kt++) {
    const int ko = kt * 32 + g * 8;
    short8 ah[MT], al[MT];
    #pragma unroll
    for (int mt = 0; mt < MT; mt++) {
      short8 h00 = *(const short8*)(ihi + b00[mt] + ko);
      short8 l00 = *(const short8*)(ilo + b00[mt] + ko);
      short8 h01 = *(const short8*)(ihi + b01[mt] + ko);
      short8 l01 = *(const short8*)(ilo + b01[mt] + ko);
      short8 h10 = *(const short8*)(ihi + b10[mt] + ko);
      short8 l10 = *(const short8*)(ilo + b10[mt] + ko);
      short8 h11 = *(const short8*)(ihi + b11[mt] + ko);
      short8 l11 = *(const short8*)(ilo + b11[mt] + ko);
      short8 hh, ll;
      #pragma unroll
      for (int j = 0; j < 8; j++) {
        float v00 = bf2f((unsigned short)h00[j]) + bf2f((unsigned short)l00[j]);
        float v01 = bf2f((unsigned short)h01[j]) + bf2f((unsigned short)l01[j]);
        float v10 = bf2f((unsigned short)h10[j]) + bf2f((unsigned short)l10[j]);
        float v11 = bf2f((unsigned short)h11[j]) + bf2f((unsigned short)l11[j]);
        float v0 = v00 + bwx[mt] * (v01 - v00);
        float v1 = v10 + bwx[mt] * (v11 - v10);
        float v  = v0 + bwy[mt] * (v1 - v0);
        unsigned short hb = f2bf(v);
        hh[j] = (short)hb;
        ll[j] = (short)f2bf(v - bf2f(hb));
      }
      ah[mt] = hh; al[mt] = ll;
    }
    #pragma unroll
    for (int nt = 0; nt < 4; nt++) {
      short8 bh = wst[(kt * 4 + nt) * 2 * 64 + lane];
      short8 bl = wst[((kt * 4 + nt) * 2 + 1) * 64 + lane];
      #pragma unroll
      for (int mt = 0; mt < MT; mt++) {
        acc[mt][nt] = __builtin_amdgcn_mfma_f32_16x16x32_bf16(ah[mt], bh, acc[mt][nt], 0, 0, 0);
        acc[mt][nt] = __builtin_amdgcn_mfma_f32_16x16x32_bf16(ah[mt], bl, acc[mt][nt], 0, 0, 0);
        acc[mt][nt] = __builtin_amdgcn_mfma_f32_16x16x32_bf16(al[mt], bh, acc[mt][nt], 0, 0, 0);
      }
    }
  }

  #pragma unroll
  for (int mt = 0; mt < MT; mt++) {
    #pragma unroll
    for (int nt = 0; nt < 4; nt++) {
      #pragma unroll
      for (int r = 0; r < 4; r++) {
        int px = opx0 + mt * 16 + g * 4 + r;
        int oc = nt * 16 + row;
        float v = gelu_f(acc[mt][nt][r]);
        out_hi[((long)n * HPX + px) * 576 + ccol + oc] = f2bf(v);
      }
    }
  }
}

// ---------------- 2x2 average pool, NHWC hi/lo -> NHWC hi/lo
__global__ __launch_bounds__(256) void avgpool_nhwc_kernel(
    const unsigned short* __restrict__ ihi, const unsigned short* __restrict__ ilo,
    unsigned short* __restrict__ ohi, unsigned short* __restrict__ olo,
    int logWo)
{
  const int lognpo = 2 * logWo;
  long t = (long)blockIdx.x * 256 + threadIdx.x;   // over 2*npo*8
  int cg = (int)(t & 7);
  int p  = (int)((t >> 3) & ((1 << lognpo) - 1));
  int n  = (int)(t >> (3 + lognpo));
  int y = p >> logWo, x = p & ((1 << logWo) - 1);
  int Wi = 2 << logWo;
  long ib = ((long)n * (4 << lognpo) + (long)(2 * y) * Wi + 2 * x) * 64 + cg * 8;
  short8 h00 = *(const short8*)(ihi + ib);
  short8 h01 = *(const short8*)(ihi + ib + 64);
  short8 h10 = *(const short8*)(ihi + ib + (long)Wi * 64);
  short8 h11 = *(const short8*)(ihi + ib + (long)Wi * 64 + 64);
  short8 l00 = *(const short8*)(ilo + ib);
  short8 l01 = *(const short8*)(ilo + ib + 64);
  short8 l10 = *(const short8*)(ilo + ib + (long)Wi * 64);
  short8 l11 = *(const short8*)(ilo + ib + (long)Wi * 64 + 64);
  short8 oh, ol;
  #pragma unroll
  for (int j = 0; j < 8; j++) {
    float v = 0.25f * ((bf2f((unsigned short)h00[j]) + bf2f((unsigned short)l00[j])) +
                       (bf2f((unsigned short)h01[j]) + bf2f((unsigned short)l01[j])) +
                       (bf2f((unsigned short)h10[j]) + bf2f((unsigned short)l10[j])) +
                       (bf2f((unsigned short)h11[j]) + bf2f((unsigned short)l11[j])));
    unsigned short hb = f2bf(v);
    oh[j] = (short)hb;
    ol[j] = (short)f2bf(v - bf2f(hb));
  }
  long ob = (((long)n << lognpo) + p) * 64 + cg * 8;
  *(short8*)(ohi + ob) = oh;
  *(short8*)(olo + ob) = ol;
}

// ---------------- MFMA head: out = w3 . gelu(W2 @ gelu(W1 @ V))  (NHWC concat)
__global__ __launch_bounds__(256, 2) void head_mfma_kernel(
    const unsigned short* __restrict__ v,       // NHWC [2][65536][576] bf16
    const unsigned short* __restrict__ w1p,
    const unsigned short* __restrict__ w2p,
    const float* __restrict__ w3,               // [64]
    float* __restrict__ out)                    // [2][65536]
{
  __shared__ unsigned short hs[128][296];       // 75,776 B
  const int lane = threadIdx.x & 63;
  const int wave = threadIdx.x >> 6;
  const int col  = lane & 15;
  const int g    = lane >> 4;
  const int n    = blockIdx.y;
  const int pxb  = blockIdx.x * 128;
  const unsigned short* vn = v + ((long)n * HPX + pxb + wave * 32) * 576;
  const short8* w1v = (const short8*)w1p;
  const short8* w2v = (const short8*)w2p;

  floatx4 acc[2][18];
  #pragma unroll
  for (int t = 0; t < 2; t++)
    #pragma unroll
    for (int mt = 0; mt < 18; mt++) acc[t][mt] = (floatx4){0.f, 0.f, 0.f, 0.f};

  for (int kt = 0; kt < 18; kt++) {
    const int ko = kt * 32 + g * 8;
    short8 a0 = *(const short8*)(vn + (long)col * 576 + ko);
    short8 a1 = *(const short8*)(vn + (long)(col + 16) * 576 + ko);
    #pragma unroll
    for (int mt = 0; mt < 18; mt++) {
      short8 bhi = w1v[((kt * 18 + mt) * 2 + 0) * 64 + lane];
      short8 blo = w1v[((kt * 18 + mt) * 2 + 1) * 64 + lane];
      acc[0][mt] = __builtin_amdgcn_mfma_f32_16x16x32_bf16(a0, bhi, acc[0][mt], 0, 0, 0);
      acc[0][mt] = __builtin_amdgcn_mfma_f32_16x16x32_bf16(a0, blo, acc[0][mt], 0, 0, 0);
      acc[1][mt] = __builtin_amdgcn_mfma_f32_16x16x32_bf16(a1, bhi, acc[1][mt], 0, 0, 0);
      acc[1][mt] = __builtin_amdgcn_mfma_f32_16x16x32_bf16(a1, blo, acc[1][mt], 0, 0, 0);
    }
  }
  #pragma unroll
  for (int t = 0; t < 2; t++)
    #pragma unroll
    for (int mt = 0; mt < 18; mt++)
      #pragma unroll
      for (int r = 0; r < 4; r++)
        hs[wave * 32 + t * 16 + g * 4 + r][mt * 16 + col] =
            f2bf(gelu_f(acc[t][mt][r]));
  __syncthreads();

  floatx4 acc2[2][4];
  #pragma unroll
  for (int t = 0; t < 2; t++)
    #pragma unroll
    for (int ot = 0; ot < 4; ot++) acc2[t][ot] = (floatx4){0.f, 0.f, 0.f, 0.f};

  for (int kt = 0; kt < 9; kt++) {
    short8 a[2];
    #pragma unroll
    for (int t = 0; t < 2; t++)
      a[t] = *(const short8*)&hs[wave * 32 + t * 16 + col][kt * 32 + g * 8];
    #pragma unroll
    for (int ot = 0; ot < 4; ot++) {
      short8 bhi = w2v[((kt * 4 + ot) * 2 + 0) * 64 + lane];
      short8 blo = w2v[((kt * 4 + ot) * 2 + 1) * 64 + lane];
      acc2[0][ot] = __builtin_amdgcn_mfma_f32_16x16x32_bf16(a[0], bhi, acc2[0][ot], 0, 0, 0);
      acc2[0][ot] = __builtin_amdgcn_mfma_f32_16x16x32_bf16(a[0], blo, acc2[0][ot], 0, 0, 0);
      acc2[1][ot] = __builtin_amdgcn_mfma_f32_16x16x32_bf16(a[1], bhi, acc2[1][ot], 0, 0, 0);
      acc2[1][ot] = __builtin_amdgcn_mfma_f32_16x16x32_bf16(a[1], blo, acc2[1][ot], 0, 0, 0);
    }
  }

  float w3r[4];
  #pragma unroll
  for (int ot = 0; ot < 4; ot++) w3r[ot] = w3[ot * 16 + col];
  #pragma unroll
  for (int t = 0; t < 2; t++) {
    float r[4] = {0.f, 0.f, 0.f, 0.f};
    #pragma unroll
    for (int ot = 0; ot < 4; ot++)
      #pragma unroll
      for (int rr = 0; rr < 4; rr++)
        r[rr] = fmaf(w3r[ot], gelu_f(acc2[t][ot][rr]), r[rr]);
    #pragma unroll
    for (int rr = 0; rr < 4; rr++) {
      r[rr] += __shfl_xor(r[rr], 1);
      r[rr] += __shfl_xor(r[rr], 2);
      r[rr] += __shfl_xor(r[rr], 4);
      r[rr] += __shfl_xor(r[rr], 8);
    }
    if (col == 0) {
      int px = pxb + wave * 32 + t * 16 + g * 4;
      #pragma unroll
      for (int rr = 0; rr < 4; rr++)
        out[(long)n * HPX + px + rr] = r[rr];
    }
  }
}

// ---------------------------------------------------------------------------
extern "C" void kernel_launch(void* const* d_in, const int* in_sizes, int n_in,
                              void* d_out, int out_size, void* d_ws, size_t ws_size,
                              hipStream_t stream) {
  const float* img      = (const float*)d_in[0];
  const float* w0a      = (const float*)d_in[1];
  const float* w0b      = (const float*)d_in[2];
  const float* first_p  = (const float*)d_in[3];
  const float* cl10     = (const float*)d_in[4];   // [4][2][64][64][9]
  const float* cl2      = (const float*)d_in[5];
  const float* dil_p    = (const float*)d_in[6];   // [4][64][64][8]
  const float* dilres_p = (const float*)d_in[7];
  const float* ups_w    = (const float*)d_in[8];   // [4][64][64]
  const float* w1       = (const float*)d_in[9];   // [288][576]
  const float* w2       = (const float*)d_in[10];  // [64][288]
  const float* w3       = (const float*)d_in[11];  // [64]

  const size_t CONCAT_B = 150994944ul;             // 2*65536*576*2
  const size_t ACT_B    = 16777216ul;              // 2*65536*64*2 per plane
  const size_t PACKS_B  = 3604480ul;               // 1,802,240 elems
  const size_t W1P_B    = 663552ul;
  const size_t W2P_B    = 73728ul;
  const size_t NEED = CONCAT_B + 4 * ACT_B + PACKS_B + W1P_B + W2P_B; // 222,445,568

  if (ws_size < NEED) {
    hipMemsetAsync(d_out, 0, (size_t)out_size * 4, stream);
    return;
  }

  char* wsb = (char*)d_ws;
  unsigned short* concat = (unsigned short*)wsb;
  unsigned short* Xhi = (unsigned short*)(wsb + CONCAT_B);
  unsigned short* Xlo = (unsigned short*)(wsb + CONCAT_B + ACT_B);
  unsigned short* Yhi = (unsigned short*)(wsb + CONCAT_B + 2 * ACT_B);
  unsigned short* Ylo = (unsigned short*)(wsb + CONCAT_B + 3 * ACT_B);
  unsigned short* packs = (unsigned short*)(wsb + CONCAT_B + 4 * ACT_B);
  unsigned short* w1p = (unsigned short*)(wsb + CONCAT_B + 4 * ACT_B + PACKS_B);
  unsigned short* w2p = (unsigned short*)(wsb + CONCAT_B + 4 * ACT_B + PACKS_B + W1P_B);

  // pack-destination offsets (elems)
  auto off_cl10   = [](int c) { return (long)c * 73728; };
  auto off_cl2    = [](int c) { return 589824l + (long)c * 73728; };
  const long OFF_FIRST = 1179648;
  auto off_dilres = [](int k) { return 1245184l + (long)k * 65536; };
  auto off_dil    = [](int k) { return 1507328l + (long)k * 65536; };
  auto off_ups    = [](int k) { return 1769472l + (long)k * 8192; };

  // ---- weight packing
  JobArr jobs;
  for (int c = 0; c < 8; c++) jobs.j[c]     = {0, c * 36864, 9, (int)off_cl10(c)};
  for (int c = 0; c < 8; c++) jobs.j[8 + c] = {1, c * 36864, 9, (int)off_cl2(c)};
  jobs.j[16] = {2, 0, 8, (int)OFF_FIRST};
  for (int k = 0; k < 4; k++) jobs.j[17 + k] = {3, k * 32768, 8, (int)off_dilres(k)};
  for (int k = 0; k < 4; k++) jobs.j[21 + k] = {4, k * 32768, 8, (int)off_dil(k)};
  for (int k = 0; k < 4; k++) jobs.j[25 + k] = {5, k * 4096, 1, (int)off_ups(k)};
  pack_conv_kernel<<<dim3(288, 29), 256, 0, stream>>>(
      cl10, cl2, first_p, dilres_p, dil_p, ups_w, packs, jobs);
  pack_w1_kernel<<<(18 * 18 * 512 + 255) / 256, 256, 0, stream>>>(w1, w1p);
  pack_w2_kernel<<<(9 * 4 * 512 + 255) / 256, 256, 0, stream>>>(w2, w2p);

  // ---- conv0 -> X @256
  conv0_nhwc_kernel<<<(2 * HPX * 64) / 256, 256, 0, stream>>>(img, w0a, w0b, Xhi, Xlo);

  // ---- launch helpers (pipelined convs; MT=2 @256, MT=1 below)
  auto conv9 = [&](const unsigned short* ih, const unsigned short* il, long wo,
                   unsigned short* oh, unsigned short* ol, int Hs, int logW) {
    int npx = Hs << logW;
    if (npx == HPX)
      conv_pipe_kernel<9, 2, false, false><<<dim3(npx / 128, 1, 2), 256, 0, stream>>>(
          ih, il, packs + wo, nullptr, nullptr, oh, ol, Hs, logW, 1, 0);
    else
      conv_pipe_kernel<9, 1, false, false><<<dim3(npx / 64, 1, 2), 256, 0, stream>>>(
          ih, il, packs + wo, nullptr, nullptr, oh, ol, Hs, logW, 1, 0);
  };
  auto conv9r = [&](const unsigned short* ih, const unsigned short* il, long wo,
                    unsigned short* rh, unsigned short* rl, int Hs, int logW) {
    int npx = Hs << logW;
    if (npx == HPX)
      conv_pipe_kernel<9, 2, true, false><<<dim3(npx / 128, 1, 2), 256, 0, stream>>>(
          ih, il, packs + wo, rh, rl, rh, rl, Hs, logW, 1, 0);
    else
      conv_pipe_kernel<9, 1, true, false><<<dim3(npx / 64, 1, 2), 256, 0, stream>>>(
          ih, il, packs + wo, rh, rl, rh, rl, Hs, logW, 1, 0);
  };
  auto donutC = [&](const unsigned short* ih, const unsigned short* il, long wo,
                    int dil, int ccol) {  // @256 -> concat
    conv_pipe_kernel<8, 2, false, true><<<dim3(512, 1, 2), 256, 0, stream>>>(
        ih, il, packs + wo, nullptr, nullptr, concat, nullptr, 256, 8, dil, ccol);
  };
  auto donutA = [&](const unsigned short* ih, const unsigned short* il, long wo,
                    int dil, unsigned short* oh, unsigned short* ol, int Hs, int logW) {
    int npx = Hs << logW;
    if (npx == HPX)
      conv_pipe_kernel<8, 2, false, false><<<dim3(npx / 128, 1, 2), 256, 0, stream>>>(
          ih, il, packs + wo, nullptr, nullptr, oh, ol, Hs, logW, dil, 0);
    else
      conv_pipe_kernel<8, 1, false, false><<<dim3(npx / 64, 1, 2), 256, 0, stream>>>(
          ih, il, packs + wo, nullptr, nullptr, oh, ol, Hs, logW, dil, 0);
  };
  auto upsC = [&](const unsigned short* ih, const unsigned short* il, long wo,
                  int Hs, int logW, int ccol) {
    conv_mfma_kernel<1, 4, false, true, true><<<dim3(256, 1, 2), 256, 0, stream>>>(
        ih, il, packs + wo, nullptr, nullptr, concat, nullptr, Hs, logW, 1, ccol);
  };
  auto avgp = [&](const unsigned short* ih, const unsigned short* il,
                  unsigned short* oh, unsigned short* ol, int logWo) {
    long total = 2l * (1l << (2 * logWo)) * 8;
    avgpool_nhwc_kernel<<<(int)(total / 256), 256, 0, stream>>>(ih, il, oh, ol, logWo);
  };

  // ---- @256: outs[0], resblock cl10[0], outs[1], resblock cl2[0]
  donutC(Xhi, Xlo, OFF_FIRST, 1, 0);
  conv9(Xhi, Xlo, off_cl10(0), Yhi, Ylo, 256, 8);
  conv9r(Yhi, Ylo, off_cl10(1), Xhi, Xlo, 256, 8);           // base = X @256
  donutC(Xhi, Xlo, off_dilres(0), 3, 64);
  conv9(Xhi, Xlo, off_cl2(0), Yhi, Ylo, 256, 8);
  conv9r(Yhi, Ylo, off_cl2(1), Xhi, Xlo, 256, 8);            // base = X @256

  // ---- i = 0 (dil 5 @256)
  donutA(Xhi, Xlo, off_dil(0), 5, Yhi, Ylo, 256, 8);
  upsC(Yhi, Ylo, off_ups(0), 256, 8, 128);
  avgp(Xhi, Xlo, Yhi, Ylo, 7);                               // base = Y @128
  conv9(Yhi, Ylo, off_cl10(2), Xhi, Xlo, 128, 7);
  conv9r(Xhi, Xlo, off_cl10(3), Yhi, Ylo, 128, 7);           // base = Y @128
  donutA(Yhi, Ylo, off_dilres(1), 6, Xhi, Xlo, 128, 7);
  upsC(Xhi, Xlo, off_ups(1), 128, 7, 192);
  conv9(Yhi, Ylo, off_cl2(2), Xhi, Xlo, 128, 7);
  conv9r(Xhi, Xlo, off_cl2(3), Yhi, Ylo, 128, 7);            // base = Y @128

  // ---- i = 1 (dil 8 @128)
  donutA(Yhi, Ylo, off_dil(1), 8, Xhi, Xlo, 128, 7);
  upsC(Xhi, Xlo, off_ups(1), 128, 7, 256);
  avgp(Yhi, Ylo, Xhi, Xlo, 6);                               // base = X @64
  conv9(Xhi, Xlo, off_cl10(4), Yhi, Ylo, 64, 6);
  conv9r(Yhi, Ylo, off_cl10(5), Xhi, Xlo, 64, 6);            // base = X @64
  donutA(Xhi, Xlo, off_dilres(2), 8, Yhi, Ylo, 64, 6);
  upsC(Yhi, Ylo, off_ups(2), 64, 6, 320);
  conv9(Xhi, Xlo, off_cl2(4), Yhi, Ylo, 64, 6);
  conv9r(Yhi, Ylo, off_cl2(5), Xhi, Xlo, 64, 6);             // base = X @64

  // ---- i = 2 (dil 10 @64)
  donutA(Xhi, Xlo, off_dil(2), 10, Yhi, Ylo, 64, 6);
  upsC(Yhi, Ylo, off_ups(2), 64, 6, 384);
  avgp(Xhi, Xlo, Yhi, Ylo, 5);                               // base = Y @32
  conv9(Yhi, Ylo, off_cl10(6), Xhi, Xlo, 32, 5);
  conv9r(Xhi, Xlo, off_cl10(7), Yhi, Ylo, 32, 5);            // base = Y @32
  donutA(Yhi, Ylo, off_dilres(3), 9, Xhi, Xlo, 32, 5);
  upsC(Xhi, Xlo, off_ups(3), 32, 5, 448);
  conv9(Yhi, Ylo, off_cl2(6), Xhi, Xlo, 32, 5);
  conv9r(Xhi, Xlo, off_cl2(7), Yhi, Ylo, 32, 5);             // base = Y @32

  // ---- i = 3 (dil 11 @32)
  donutA(Yhi, Ylo, off_dil(3), 11, Xhi, Xlo, 32, 5);
  upsC(Xhi, Xlo, off_ups(3), 32, 5, 512);

  // ---- MFMA head
  head_mfma_kernel<<<dim3(512, 2), 256, 0, stream>>>(concat, w1p, w2p, w3,
                                                     (float*)d_out);
}

// Round 10
// 1090.077 us; speedup vs baseline: 5.8678x; 1.0409x over previous
//
#include <hip/hip_runtime.h>
#include <hip/hip_bf16.h>

// ---------------------------------------------------------------------------
// SHINE forward, full bf16-MFMA version with hi/lo-split activations+weights.
// Workspace (222,445,568 B total, unchanged):
//   concat : bf16 NHWC [2][65536][576]          150,994,944 B
//   Xhi,Xlo,Yhi,Ylo : bf16 NHWC [2][65536][64]  4 x 16,777,216 B
//   packs  : conv B-frags (hi,lo)                 3,604,480 B
//   w1p    : head W1 frags                          663,552 B
//   w2p    : head W2 frags                           73,728 B
// R10: (a) head split into two GEMM kernels (out1_gemm/out2_gemm) with h
//      (bf16) bounced through the dead X/Y/packs region in 2 px-chunks;
//      w1p LDS-staged per kt shared by 4 waves; (b) all conv/ups epilogues
//      write through per-wave LDS transpose tiles -> 128B coalesced stores.
//      Math order identical to R9 (same absmax).
// ---------------------------------------------------------------------------

#define HPX 65536   // 256*256
#define FCH 64
#define CHPX 32768  // head px-chunk

typedef __attribute__((ext_vector_type(8))) short  short8;
typedef __attribute__((ext_vector_type(4))) float  floatx4;

__device__ __forceinline__ float gelu_f(float x) {
  return 0.5f * x * (1.0f + erff(x * 0.70710678118654752440f));
}
__device__ __forceinline__ unsigned short f2bf(float x) {  // RNE
  unsigned u = __float_as_uint(x);
  unsigned r = (u + 0x7FFFu + ((u >> 16) & 1u)) >> 16;
  return (unsigned short)r;
}
__device__ __forceinline__ float bf2f(unsigned short h) {
  return __uint_as_float(((unsigned)h) << 16);
}

// ---------------- conv0: base = concat(gelu(1x1(target)), gelu(3x3(feats)))
__global__ __launch_bounds__(256) void conv0_nhwc_kernel(
    const float* __restrict__ img,   // [2][5][256][256]
    const float* __restrict__ w0a,   // [16][4][3][3]
    const float* __restrict__ w0b,   // [48]
    unsigned short* __restrict__ ohi,  // [2][65536][64]
    unsigned short* __restrict__ olo)
{
  long t = (long)blockIdx.x * 256 + threadIdx.x;   // over 2*65536*64
  int c  = (int)(t & 63);
  int px = (int)((t >> 6) & (HPX - 1));
  int n  = (int)(t >> 22);
  const float* im = img + (long)n * 5 * HPX;
  float r;
  if (c < 48) {
    r = w0b[c] * im[2 * HPX + px];
  } else {
    int co = c - 48;
    int y = px >> 8, x = px & 255;
    r = 0.0f;
    const int map4[4] = {0, 1, 3, 4};
    #pragma unroll
    for (int fi = 0; fi < 4; fi++) {
      const float* imc = im + (long)map4[fi] * HPX;
      #pragma unroll
      for (int ky = 0; ky < 3; ky++) {
        int yy = y + ky - 1;
        #pragma unroll
        for (int kx = 0; kx < 3; kx++) {
          int xx = x + kx - 1;
          bool ok = ((unsigned)yy < 256u) && ((unsigned)xx < 256u);
          float v = ok ? imc[yy * 256 + xx] : 0.0f;
          r = fmaf(w0a[((co * 4 + fi) * 3 + ky) * 3 + kx], v, r);
        }
      }
    }
  }
  float v = gelu_f(r);
  unsigned short hb = f2bf(v);
  ohi[t] = hb;
  olo[t] = f2bf(v - bf2f(hb));
}

// ---------------- batched conv-weight packing into MFMA B-frags (hi,lo)
struct JobArr { int4 j[29]; };   // {src_sel, src_off, ntaps, dst_off}

__global__ __launch_bounds__(256) void pack_conv_kernel(
    const float* __restrict__ cl10, const float* __restrict__ cl2,
    const float* __restrict__ first_p, const float* __restrict__ dilres_p,
    const float* __restrict__ dil_p, const float* __restrict__ ups_w,
    unsigned short* __restrict__ packs, JobArr jobs)
{
  int4 jb = jobs.j[blockIdx.y];
  int ntaps = jb.z;
  int idx = blockIdx.x * 256 + threadIdx.x;
  if (idx >= ntaps * 8192) return;
  int j  = idx & 7;
  int l  = (idx >> 3) & 63;
  int s  = (idx >> 9) & 1;
  int nt = (idx >> 10) & 3;
  int kt = (idx >> 12) & 1;
  int tap = idx >> 13;
  int oc = nt * 16 + (l & 15);
  int ci = kt * 32 + (l >> 4) * 8 + j;
  const float* src;
  switch (jb.x) {
    case 0: src = cl10; break;
    case 1: src = cl2; break;
    case 2: src = first_p; break;
    case 3: src = dilres_p; break;
    case 4: src = dil_p; break;
    default: src = ups_w; break;
  }
  float w = src[jb.y + (oc * 64 + ci) * ntaps + tap];
  unsigned short hi = f2bf(w);
  unsigned short v = (s == 0) ? hi : f2bf(w - bf2f(hi));
  packs[jb.w + idx] = v;
}

// ---------------- head weight packing (hi+lo)
__global__ __launch_bounds__(256) void pack_w1_kernel(
    const float* __restrict__ w1, unsigned short* __restrict__ w1p)
{
  int t = blockIdx.x * 256 + threadIdx.x;      // 18*18*512
  if (t >= 18 * 18 * 512) return;
  int j = t & 7, l = (t >> 3) & 63;
  int mt = (t >> 9) % 18, kt = (t >> 9) / 18;
  int oc = mt * 16 + (l & 15);
  int k  = kt * 32 + (l >> 4) * 8 + j;
  float w = w1[oc * 576 + k];
  unsigned short hi = f2bf(w);
  unsigned short lo = f2bf(w - bf2f(hi));
  long base = ((long)(kt * 18 + mt) * 2) * 512 + l * 8 + j;
  w1p[base] = hi;
  w1p[base + 512] = lo;
}
__global__ __launch_bounds__(256) void pack_w2_kernel(
    const float* __restrict__ w2, unsigned short* __restrict__ w2p)
{
  int t = blockIdx.x * 256 + threadIdx.x;      // 9*4*512
  if (t >= 9 * 4 * 512) return;
  int j = t & 7, l = (t >> 3) & 63;
  int ot = (t >> 9) % 4, kt = (t >> 9) / 4;
  int oc = ot * 16 + (l & 15);
  int k  = kt * 32 + (l >> 4) * 8 + j;
  float w = w2[oc * 288 + k];
  unsigned short hi = f2bf(w);
  unsigned short lo = f2bf(w - bf2f(hi));
  long base = ((long)(kt * 4 + ot) * 2) * 512 + l * 8 + j;
  w2p[base] = hi;
  w2p[base + 512] = lo;
}

// ---------------- software-pipelined MFMA conv (implicit GEMM, 16x16x32 bf16)
// Pipeline per tap as R9. Epilogue now routes through a per-wave LDS tile
// so global stores are contiguous short8 (128B lines) instead of 2B scatter.
template <int NTAPS, int MT, bool RESID, bool TO_CONCAT>
__global__ __launch_bounds__(256) void conv_pipe_kernel(
    const unsigned short* __restrict__ in_hi,   // NHWC [n][npx_in][64]
    const unsigned short* __restrict__ in_lo,
    const unsigned short* __restrict__ wp,      // packed frags
    const unsigned short* __restrict__ res_hi,
    const unsigned short* __restrict__ res_lo,
    unsigned short* __restrict__ out_hi,        // act hi or concat
    unsigned short* __restrict__ out_lo,
    int Hs, int logW, int dil, int ccol)
{
  constexpr int PL = TO_CONCAT ? 1 : 2;
  __shared__ short8 wst[2][1024];               // 2 x 16 KB double buffer
  __shared__ unsigned short tb[4][PL][16][76];  // per-wave transpose tiles
  const int tid  = threadIdx.x;
  const int lane = tid & 63;
  const int wave = tid >> 6;
  const int row  = lane & 15;
  const int g    = lane >> 4;
  const int n    = blockIdx.z;
  const int Ws   = 1 << logW;
  const int npx_in = Hs << logW;
  const int opx0 = blockIdx.x * (64 * MT) + wave * (16 * MT);

  const unsigned short* ihi = in_hi + (long)n * npx_in * 64;
  const unsigned short* ilo = in_lo + (long)n * npx_in * 64;
  const short8* wpv = (const short8*)wp;

  int ry[MT], rx[MT];
  #pragma unroll
  for (int mt = 0; mt < MT; mt++) {
    int p = opx0 + mt * 16 + row;
    ry[mt] = p >> logW;
    rx[mt] = p & (Ws - 1);
  }

  floatx4 acc[MT][4];
  #pragma unroll
  for (int mt = 0; mt < MT; mt++)
    #pragma unroll
    for (int nt = 0; nt < 4; nt++) acc[mt][nt] = (floatx4){0.f, 0.f, 0.f, 0.f};

  const short8 zz = {0, 0, 0, 0, 0, 0, 0, 0};
  short8 sreg[4];
  short8 ahA[MT][2], alA[MT][2], ahB[MT][2], alB[MT][2];

  auto stage_issue = [&](int t) {
    #pragma unroll
    for (int p = 0; p < 4; p++)
      sreg[p] = wpv[(long)t * 1024 + tid + p * 256];
  };
  auto stage_write = [&](int b) {
    #pragma unroll
    for (int p = 0; p < 4; p++)
      wst[b][tid + p * 256] = sreg[p];
  };
  auto a_load = [&](short8 (&ah)[MT][2], short8 (&al)[MT][2], int t) {
    const int kk  = (NTAPS == 9) ? t : (t < 4 ? t : t + 1);
    const int dyd = (kk / 3 - 1) * dil, dxd = (kk % 3 - 1) * dil;
    #pragma unroll
    for (int mt = 0; mt < MT; mt++) {
      int yy = ry[mt] + dyd, xx = rx[mt] + dxd;
      bool ok = ((unsigned)yy < (unsigned)Hs) && ((unsigned)xx < (unsigned)Ws);
      long base = ok ? (long)((yy << logW) + xx) * 64 : 0;
      #pragma unroll
      for (int kt = 0; kt < 2; kt++) {
        long a = base + kt * 32 + g * 8;
        short8 h = *(const short8*)(ihi + a);
        short8 l = *(const short8*)(ilo + a);
        ah[mt][kt] = ok ? h : zz;
        al[mt][kt] = ok ? l : zz;
      }
    }
  };
  auto compute = [&](int b, short8 (&ah)[MT][2], short8 (&al)[MT][2]) {
    #pragma unroll
    for (int kt = 0; kt < 2; kt++)
      #pragma unroll
      for (int nt = 0; nt < 4; nt++) {
        short8 bh = wst[b][(kt * 4 + nt) * 128 + lane];
        short8 bl = wst[b][(kt * 4 + nt) * 128 + 64 + lane];
        #pragma unroll
        for (int mt = 0; mt < MT; mt++) {
          acc[mt][nt] = __builtin_amdgcn_mfma_f32_16x16x32_bf16(ah[mt][kt], bh, acc[mt][nt], 0, 0, 0);
          acc[mt][nt] = __builtin_amdgcn_mfma_f32_16x16x32_bf16(ah[mt][kt], bl, acc[mt][nt], 0, 0, 0);
          acc[mt][nt] = __builtin_amdgcn_mfma_f32_16x16x32_bf16(al[mt][kt], bh, acc[mt][nt], 0, 0, 0);
        }
      }
  };

  // prologue: stage + A for tap 0
  stage_issue(0);
  a_load(ahA, alA, 0);
  stage_write(0);
  __syncthreads();

  #pragma unroll
  for (int tt = 0; tt < NTAPS; tt++) {
    const int b = tt & 1;
    if (tt + 1 < NTAPS) {
      stage_issue(tt + 1);                       // global loads, early
      if ((tt & 1) == 0) a_load(ahB, alB, tt + 1);
      else               a_load(ahA, alA, tt + 1);
    }
    if ((tt & 1) == 0) compute(b, ahA, alA);     // hides the loads above
    else               compute(b, ahB, alB);
    if (tt + 1 < NTAPS) {
      stage_write(b ^ 1);                        // write-late into other buf
      __syncthreads();                           // ONE barrier per tap
    }
  }

  // epilogue: (+resid) -> gelu -> LDS transpose -> coalesced short8 stores
  #pragma unroll
  for (int mt = 0; mt < MT; mt++) {
    __builtin_amdgcn_wave_barrier();
    #pragma unroll
    for (int nt = 0; nt < 4; nt++) {
      #pragma unroll
      for (int r = 0; r < 4; r++) {
        int px = opx0 + mt * 16 + g * 4 + r;
        int oc = nt * 16 + row;
        float v = acc[mt][nt][r];
        if (RESID) {
          long ri = ((long)n * npx_in + px) * 64 + oc;
          v += bf2f(res_hi[ri]) + bf2f(res_lo[ri]);
        }
        v = gelu_f(v);
        unsigned short hb = f2bf(v);
        tb[wave][0][g * 4 + r][oc] = hb;
        if (!TO_CONCAT)
          tb[wave][PL - 1][g * 4 + r][oc] = f2bf(v - bf2f(hb));
      }
    }
    __builtin_amdgcn_wave_barrier();
    const int pxb = opx0 + mt * 16;
    const int pxl = lane >> 2;
    #pragma unroll
    for (int pl = 0; pl < PL; pl++) {
      #pragma unroll
      for (int it = 0; it < 2; it++) {
        int ch = (lane & 3) + it * 4;
        short8 v8 = *(const short8*)&tb[wave][pl][pxl][ch * 8];
        if (TO_CONCAT) {
          *(short8*)&out_hi[((long)n * HPX + pxb + pxl) * 576 + ccol + ch * 8] = v8;
        } else {
          unsigned short* dst = pl ? out_lo : out_hi;
          *(short8*)&dst[((long)n * npx_in + pxb + pxl) * 64 + ch * 8] = v8;
        }
      }
    }
  }
}

// ---------------- bilinear-upsample 1x1 conv -> concat (coalesced epilogue)
template <int MT>
__global__ __launch_bounds__(256) void ups_mfma_kernel(
    const unsigned short* __restrict__ in_hi,   // NHWC [n][npx_in][64]
    const unsigned short* __restrict__ in_lo,
    const unsigned short* __restrict__ wp,      // packed frags (1 tap)
    unsigned short* __restrict__ outc,          // concat
    int Hs, int logW, int ccol)
{
  __shared__ short8 wst[1024];                  // 16 KB: one tap's 16 frags
  __shared__ unsigned short tb[4][16][76];
  const int tid  = threadIdx.x;
  const int lane = threadIdx.x & 63;
  const int wave = threadIdx.x >> 6;
  const int row  = lane & 15;
  const int g    = lane >> 4;
  const int n    = blockIdx.z;
  const int npx_in = Hs << logW;
  const int opx0 = blockIdx.x * (64 * MT) + wave * (16 * MT);

  const unsigned short* ihi = in_hi + (long)n * npx_in * 64;
  const unsigned short* ilo = in_lo + (long)n * npx_in * 64;
  const short8* wpv = (const short8*)wp;

  int b00[MT], b01[MT], b10[MT], b11[MT];
  float bwx[MT], bwy[MT];
  #pragma unroll
  for (int mt = 0; mt < MT; mt++) {
    int p = opx0 + mt * 16 + row;
    int Y = p >> 8, X = p & 255;
    float sc = (float)Hs * (1.0f / 256.0f);
    float fy = ((float)Y + 0.5f) * sc - 0.5f;
    float fx = ((float)X + 0.5f) * sc - 0.5f;
    int y0 = (int)floorf(fy), x0 = (int)floorf(fx);
    bwy[mt] = fy - (float)y0; bwx[mt] = fx - (float)x0;
    int y0c = min(max(y0, 0), Hs - 1), y1c = min(max(y0 + 1, 0), Hs - 1);
    int x0c = min(max(x0, 0), Hs - 1), x1c = min(max(x0 + 1, 0), Hs - 1);
    b00[mt] = (y0c * Hs + x0c) * 64; b01[mt] = (y0c * Hs + x1c) * 64;
    b10[mt] = (y1c * Hs + x0c) * 64; b11[mt] = (y1c * Hs + x1c) * 64;
  }

  floatx4 acc[MT][4];
  #pragma unroll
  for (int mt = 0; mt < MT; mt++)
    #pragma unroll
    for (int nt = 0; nt < 4; nt++) acc[mt][nt] = (floatx4){0.f, 0.f, 0.f, 0.f};

  #pragma unroll
  for (int p = 0; p < 4; p++)
    wst[tid + p * 256] = wpv[tid + p * 256];
  __syncthreads();

  #pragma unroll
  for (int kt = 0; kt < 2; kt++) {
    const int ko = kt * 32 + g * 8;
    short8 ah[MT], al[MT];
    #pragma unroll
    for (int mt = 0; mt < MT; mt++) {
      short8 h00 = *(const short8*)(ihi + b00[mt] + ko);
      short8 l00 = *(const short8*)(ilo + b00[mt] + ko);
      short8 h01 = *(const short8*)(ihi + b01[mt] + ko);
      short8 l01 = *(const short8*)(ilo + b01[mt] + ko);
      short8 h10 = *(const short8*)(ihi + b10[mt] + ko);
      short8 l10 = *(const short8*)(ilo + b10[mt] + ko);
      short8 h11 = *(const short8*)(ihi + b11[mt] + ko);
      short8 l11 = *(const short8*)(ilo + b11[mt] + ko);
      short8 hh, ll;
      #pragma unroll
      for (int j = 0; j < 8; j++) {
        float v00 = bf2f((unsigned short)h00[j]) + bf2f((unsigned short)l00[j]);
        float v01 = bf2f((unsigned short)h01[j]) + bf2f((unsigned short)l01[j]);
        float v10 = bf2f((unsigned short)h10[j]) + bf2f((unsigned short)l10[j]);
        float v11 = bf2f((unsigned short)h11[j]) + bf2f((unsigned short)l11[j]);
        float v0 = v00 + bwx[mt] * (v01 - v00);
        float v1 = v10 + bwx[mt] * (v11 - v10);
        float v  = v0 + bwy[mt] * (v1 - v0);
        unsigned short hb = f2bf(v);
        hh[j] = (short)hb;
        ll[j] = (short)f2bf(v - bf2f(hb));
      }
      ah[mt] = hh; al[mt] = ll;
    }
    #pragma unroll
    for (int nt = 0; nt < 4; nt++) {
      short8 bh = wst[(kt * 4 + nt) * 2 * 64 + lane];
      short8 bl = wst[((kt * 4 + nt) * 2 + 1) * 64 + lane];
      #pragma unroll
      for (int mt = 0; mt < MT; mt++) {
        acc[mt][nt] = __builtin_amdgcn_mfma_f32_16x16x32_bf16(ah[mt], bh, acc[mt][nt], 0, 0, 0);
        acc[mt][nt] = __builtin_amdgcn_mfma_f32_16x16x32_bf16(ah[mt], bl, acc[mt][nt], 0, 0, 0);
        acc[mt][nt] = __builtin_amdgcn_mfma_f32_16x16x32_bf16(al[mt], bh, acc[mt][nt], 0, 0, 0);
      }
    }
  }

  #pragma unroll
  for (int mt = 0; mt < MT; mt++) {
    __builtin_amdgcn_wave_barrier();
    #pragma unroll
    for (int nt = 0; nt < 4; nt++)
      #pragma unroll
      for (int r = 0; r < 4; r++)
        tb[wave][g * 4 + r][nt * 16 + row] = f2bf(gelu_f(acc[mt][nt][r]));
    __builtin_amdgcn_wave_barrier();
    const int pxb = opx0 + mt * 16;
    const int pxl = lane >> 2;
    #pragma unroll
    for (int it = 0; it < 2; it++) {
      int ch = (lane & 3) + it * 4;
      short8 v8 = *(const short8*)&tb[wave][pxl][ch * 8];
      *(short8*)&outc[((long)n * HPX + pxb + pxl) * 576 + ccol + ch * 8] = v8;
    }
  }
}

// ---------------- 2x2 average pool, NHWC hi/lo -> NHWC hi/lo
__global__ __launch_bounds__(256) void avgpool_nhwc_kernel(
    const unsigned short* __restrict__ ihi, const unsigned short* __restrict__ ilo,
    unsigned short* __restrict__ ohi, unsigned short* __restrict__ olo,
    int logWo)
{
  const int lognpo = 2 * logWo;
  long t = (long)blockIdx.x * 256 + threadIdx.x;   // over 2*npo*8
  int cg = (int)(t & 7);
  int p  = (int)((t >> 3) & ((1 << lognpo) - 1));
  int n  = (int)(t >> (3 + lognpo));
  int y = p >> logWo, x = p & ((1 << logWo) - 1);
  int Wi = 2 << logWo;
  long ib = ((long)n * (4 << lognpo) + (long)(2 * y) * Wi + 2 * x) * 64 + cg * 8;
  short8 h00 = *(const short8*)(ihi + ib);
  short8 h01 = *(const short8*)(ihi + ib + 64);
  short8 h10 = *(const short8*)(ihi + ib + (long)Wi * 64);
  short8 h11 = *(const short8*)(ihi + ib + (long)Wi * 64 + 64);
  short8 l00 = *(const short8*)(ilo + ib);
  short8 l01 = *(const short8*)(ilo + ib + 64);
  short8 l10 = *(const short8*)(ilo + ib + (long)Wi * 64);
  short8 l11 = *(const short8*)(ilo + ib + (long)Wi * 64 + 64);
  short8 oh, ol;
  #pragma unroll
  for (int j = 0; j < 8; j++) {
    float v = 0.25f * ((bf2f((unsigned short)h00[j]) + bf2f((unsigned short)l00[j])) +
                       (bf2f((unsigned short)h01[j]) + bf2f((unsigned short)l01[j])) +
                       (bf2f((unsigned short)h10[j]) + bf2f((unsigned short)l10[j])) +
                       (bf2f((unsigned short)h11[j]) + bf2f((unsigned short)l11[j])));
    unsigned short hb = f2bf(v);
    oh[j] = (short)hb;
    ol[j] = (short)f2bf(v - bf2f(hb));
  }
  long ob = (((long)n << lognpo) + p) * 64 + cg * 8;
  *(short8*)(ohi + ob) = oh;
  *(short8*)(olo + ob) = ol;
}

// ---------------- head stage 1 GEMM: h = gelu(W1 @ concat), one px-chunk
// block: 64 px; 4 waves split 18 oc-tiles {5,5,4,4}; w1p staged per kt in LDS
// (shared by all waves); epilogue via LDS transpose -> coalesced h writes.
__global__ __launch_bounds__(256) void out1_gemm_kernel(
    const unsigned short* __restrict__ v,       // concat NHWC [2][65536][576]
    const unsigned short* __restrict__ w1p,
    unsigned short* __restrict__ h,             // [2][CHPX][288] bf16
    int cpx)
{
  __shared__ short8 ws8[2400];                  // 38,400 B (stage 36,864 /
                                                //  transpose 64x300x2=38,400)
  const int tid  = threadIdx.x;
  const int lane = tid & 63;
  const int wave = tid >> 6;
  const int row  = lane & 15;
  const int g    = lane >> 4;
  const int n    = blockIdx.y;
  const int px0  = cpx + blockIdx.x * 64;       // absolute px
  const int mtb  = (wave < 2) ? wave * 5 : 10 + (wave - 2) * 4;
  const int MTN  = (wave < 2) ? 5 : 4;
  const short8* w1v = (const short8*)w1p;

  floatx4 acc[4][5];
  #pragma unroll
  for (int t = 0; t < 4; t++)
    #pragma unroll
    for (int m = 0; m < 5; m++) acc[t][m] = (floatx4){0.f, 0.f, 0.f, 0.f};

  for (int kt = 0; kt < 18; kt++) {
    __syncthreads();                             // prev kt's LDS reads done
    #pragma unroll
    for (int p = 0; p < 9; p++)
      ws8[tid + p * 256] = w1v[kt * 2304 + tid + p * 256];
    __syncthreads();

    short8 a[4];
    #pragma unroll
    for (int t = 0; t < 4; t++)
      a[t] = *(const short8*)(v + ((long)n * HPX + px0 + t * 16 + row) * 576 +
                              kt * 32 + g * 8);
    #pragma unroll
    for (int m = 0; m < 5; m++) {
      if (m < MTN) {
        short8 bh = ws8[((mtb + m) * 2 + 0) * 64 + lane];
        short8 bl = ws8[((mtb + m) * 2 + 1) * 64 + lane];
        #pragma unroll
        for (int t = 0; t < 4; t++) {
          acc[t][m] = __builtin_amdgcn_mfma_f32_16x16x32_bf16(a[t], bh, acc[t][m], 0, 0, 0);
          acc[t][m] = __builtin_amdgcn_mfma_f32_16x16x32_bf16(a[t], bl, acc[t][m], 0, 0, 0);
        }
      }
    }
  }

  // epilogue: gelu -> bf16 -> LDS [64][300] -> coalesced h writes
  __syncthreads();
  unsigned short* hs2 = (unsigned short*)ws8;
  #pragma unroll
  for (int m = 0; m < 5; m++) {
    if (m < MTN) {
      #pragma unroll
      for (int t = 0; t < 4; t++)
        #pragma unroll
        for (int r = 0; r < 4; r++)
          hs2[(t * 16 + g * 4 + r) * 300 + (mtb + m) * 16 + row] =
              f2bf(gelu_f(acc[t][m][r]));
    }
  }
  __syncthreads();
  #pragma unroll
  for (int p = 0; p < 9; p++) {
    int li = tid + p * 256;                      // 2304 chunks of 16B
    int px = li / 36, c16 = li % 36;
    short8 v8 = *(const short8*)&hs2[px * 300 + c16 * 8];
    *(short8*)&h[((long)n * CHPX + (px0 - cpx) + px) * 288 + c16 * 8] = v8;
  }
}

// ---------------- head stage 2: out = w3 . gelu(W2 @ h), one px-chunk
__global__ __launch_bounds__(256) void out2_gemm_kernel(
    const unsigned short* __restrict__ h,       // [2][CHPX][288] bf16
    const unsigned short* __restrict__ w2p,
    const float* __restrict__ w3,               // [64]
    float* __restrict__ out,                    // [2][65536]
    int cpx)
{
  __shared__ short8 w2s[4608];                  // 73,728 B, whole w2p
  const int tid  = threadIdx.x;
  const int lane = tid & 63;
  const int wave = tid >> 6;
  const int row  = lane & 15;
  const int g    = lane >> 4;
  const int n    = blockIdx.y;
  const int pxc  = blockIdx.x * 256 + wave * 64; // px within chunk
  const short8* w2v = (const short8*)w2p;

  #pragma unroll
  for (int p = 0; p < 18; p++)
    w2s[tid + p * 256] = w2v[tid + p * 256];
  __syncthreads();

  floatx4 acc2[4][4];
  #pragma unroll
  for (int t = 0; t < 4; t++)
    #pragma unroll
    for (int ot = 0; ot < 4; ot++) acc2[t][ot] = (floatx4){0.f, 0.f, 0.f, 0.f};

  for (int kt = 0; kt < 9; kt++) {
    short8 a[4];
    #pragma unroll
    for (int t = 0; t < 4; t++)
      a[t] = *(const short8*)&h[((long)n * CHPX + pxc + t * 16 + row) * 288 +
                                kt * 32 + g * 8];
    #pragma unroll
    for (int ot = 0; ot < 4; ot++) {
      short8 bh = w2s[((kt * 4 + ot) * 2 + 0) * 64 + lane];
      short8 bl = w2s[((kt * 4 + ot) * 2 + 1) * 64 + lane];
      #pragma unroll
      for (int t = 0; t < 4; t++) {
        acc2[t][ot] = __builtin_amdgcn_mfma_f32_16x16x32_bf16(a[t], bh, acc2[t][ot], 0, 0, 0);
        acc2[t][ot] = __builtin_amdgcn_mfma_f32_16x16x32_bf16(a[t], bl, acc2[t][ot], 0, 0, 0);
      }
    }
  }

  float w3r[4];
  #pragma unroll
  for (int ot = 0; ot < 4; ot++) w3r[ot] = w3[ot * 16 + row];
  #pragma unroll
  for (int t = 0; t < 4; t++) {
    float r[4] = {0.f, 0.f, 0.f, 0.f};
    #pragma unroll
    for (int ot = 0; ot < 4; ot++)
      #pragma unroll
      for (int rr = 0; rr < 4; rr++)
        r[rr] = fmaf(w3r[ot], gelu_f(acc2[t][ot][rr]), r[rr]);
    #pragma unroll
    for (int rr = 0; rr < 4; rr++) {
      r[rr] += __shfl_xor(r[rr], 1);
      r[rr] += __shfl_xor(r[rr], 2);
      r[rr] += __shfl_xor(r[rr], 4);
      r[rr] += __shfl_xor(r[rr], 8);
    }
    if (row == 0) {
      int px = cpx + pxc + t * 16 + g * 4;
      #pragma unroll
      for (int rr = 0; rr < 4; rr++)
        out[(long)n * HPX + px + rr] = r[rr];
    }
  }
}

// ---------------------------------------------------------------------------
extern "C" void kernel_launch(void* const* d_in, const int* in_sizes, int n_in,
                              void* d_out, int out_size, void* d_ws, size_t ws_size,
                              hipStream_t stream) {
  const float* img      = (const float*)d_in[0];
  const float* w0a      = (const float*)d_in[1];
  const float* w0b      = (const float*)d_in[2];
  const float* first_p  = (const float*)d_in[3];
  const float* cl10     = (const float*)d_in[4];   // [4][2][64][64][9]
  const float* cl2      = (const float*)d_in[5];
  const float* dil_p    = (const float*)d_in[6];   // [4][64][64][8]
  const float* dilres_p = (const float*)d_in[7];
  const float* ups_w    = (const float*)d_in[8];   // [4][64][64]
  const float* w1       = (const float*)d_in[9];   // [288][576]
  const float* w2       = (const float*)d_in[10];  // [64][288]
  const float* w3       = (const float*)d_in[11];  // [64]

  const size_t CONCAT_B = 150994944ul;             // 2*65536*576*2
  const size_t ACT_B    = 16777216ul;              // 2*65536*64*2 per plane
  const size_t PACKS_B  = 3604480ul;               // 1,802,240 elems
  const size_t W1P_B    = 663552ul;
  const size_t W2P_B    = 73728ul;
  const size_t NEED = CONCAT_B + 4 * ACT_B + PACKS_B + W1P_B + W2P_B; // 222,445,568

  if (ws_size < NEED) {
    hipMemsetAsync(d_out, 0, (size_t)out_size * 4, stream);
    return;
  }

  char* wsb = (char*)d_ws;
  unsigned short* concat = (unsigned short*)wsb;
  unsigned short* Xhi = (unsigned short*)(wsb + CONCAT_B);
  unsigned short* Xlo = (unsigned short*)(wsb + CONCAT_B + ACT_B);
  unsigned short* Yhi = (unsigned short*)(wsb + CONCAT_B + 2 * ACT_B);
  unsigned short* Ylo = (unsigned short*)(wsb + CONCAT_B + 3 * ACT_B);
  unsigned short* packs = (unsigned short*)(wsb + CONCAT_B + 4 * ACT_B);
  unsigned short* w1p = (unsigned short*)(wsb + CONCAT_B + 4 * ACT_B + PACKS_B);
  unsigned short* w2p = (unsigned short*)(wsb + CONCAT_B + 4 * ACT_B + PACKS_B + W1P_B);
  // head h buffer: reuses dead X/Y/packs region after last ups
  // (2*CHPX*288*2 = 37,748,736 B <= 4*ACT_B + PACKS_B = 70,713,344 B)
  unsigned short* hbuf = Xhi;

  // pack-destination offsets (elems)
  auto off_cl10   = [](int c) { return (long)c * 73728; };
  auto off_cl2    = [](int c) { return 589824l + (long)c * 73728; };
  const long OFF_FIRST = 1179648;
  auto off_dilres = [](int k) { return 1245184l + (long)k * 65536; };
  auto off_dil    = [](int k) { return 1507328l + (long)k * 65536; };
  auto off_ups    = [](int k) { return 1769472l + (long)k * 8192; };

  // ---- weight packing
  JobArr jobs;
  for (int c = 0; c < 8; c++) jobs.j[c]     = {0, c * 36864, 9, (int)off_cl10(c)};
  for (int c = 0; c < 8; c++) jobs.j[8 + c] = {1, c * 36864, 9, (int)off_cl2(c)};
  jobs.j[16] = {2, 0, 8, (int)OFF_FIRST};
  for (int k = 0; k < 4; k++) jobs.j[17 + k] = {3, k * 32768, 8, (int)off_dilres(k)};
  for (int k = 0; k < 4; k++) jobs.j[21 + k] = {4, k * 32768, 8, (int)off_dil(k)};
  for (int k = 0; k < 4; k++) jobs.j[25 + k] = {5, k * 4096, 1, (int)off_ups(k)};
  pack_conv_kernel<<<dim3(288, 29), 256, 0, stream>>>(
      cl10, cl2, first_p, dilres_p, dil_p, ups_w, packs, jobs);
  pack_w1_kernel<<<(18 * 18 * 512 + 255) / 256, 256, 0, stream>>>(w1, w1p);
  pack_w2_kernel<<<(9 * 4 * 512 + 255) / 256, 256, 0, stream>>>(w2, w2p);

  // ---- conv0 -> X @256
  conv0_nhwc_kernel<<<(2 * HPX * 64) / 256, 256, 0, stream>>>(img, w0a, w0b, Xhi, Xlo);

  // ---- launch helpers (pipelined convs; MT=2 @256, MT=1 below)
  auto conv9 = [&](const unsigned short* ih, const unsigned short* il, long wo,
                   unsigned short* oh, unsigned short* ol, int Hs, int logW) {
    int npx = Hs << logW;
    if (npx == HPX)
      conv_pipe_kernel<9, 2, false, false><<<dim3(npx / 128, 1, 2), 256, 0, stream>>>(
          ih, il, packs + wo, nullptr, nullptr, oh, ol, Hs, logW, 1, 0);
    else
      conv_pipe_kernel<9, 1, false, false><<<dim3(npx / 64, 1, 2), 256, 0, stream>>>(
          ih, il, packs + wo, nullptr, nullptr, oh, ol, Hs, logW, 1, 0);
  };
  auto conv9r = [&](const unsigned short* ih, const unsigned short* il, long wo,
                    unsigned short* rh, unsigned short* rl, int Hs, int logW) {
    int npx = Hs << logW;
    if (npx == HPX)
      conv_pipe_kernel<9, 2, true, false><<<dim3(npx / 128, 1, 2), 256, 0, stream>>>(
          ih, il, packs + wo, rh, rl, rh, rl, Hs, logW, 1, 0);
    else
      conv_pipe_kernel<9, 1, true, false><<<dim3(npx / 64, 1, 2), 256, 0, stream>>>(
          ih, il, packs + wo, rh, rl, rh, rl, Hs, logW, 1, 0);
  };
  auto donutC = [&](const unsigned short* ih, const unsigned short* il, long wo,
                    int dil, int ccol) {  // @256 -> concat
    conv_pipe_kernel<8, 2, false, true><<<dim3(512, 1, 2), 256, 0, stream>>>(
        ih, il, packs + wo, nullptr, nullptr, concat, nullptr, 256, 8, dil, ccol);
  };
  auto donutA = [&](const unsigned short* ih, const unsigned short* il, long wo,
                    int dil, unsigned short* oh, unsigned short* ol, int Hs, int logW) {
    int npx = Hs << logW;
    if (npx == HPX)
      conv_pipe_kernel<8, 2, false, false><<<dim3(npx / 128, 1, 2), 256, 0, stream>>>(
          ih, il, packs + wo, nullptr, nullptr, oh, ol, Hs, logW, dil, 0);
    else
      conv_pipe_kernel<8, 1, false, false><<<dim3(npx / 64, 1, 2), 256, 0, stream>>>(
          ih, il, packs + wo, nullptr, nullptr, oh, ol, Hs, logW, dil, 0);
  };
  auto upsC = [&](const unsigned short* ih, const unsigned short* il, long wo,
                  int Hs, int logW, int ccol) {
    ups_mfma_kernel<4><<<dim3(256, 1, 2), 256, 0, stream>>>(
        ih, il, packs + wo, concat, Hs, logW, ccol);
  };
  auto avgp = [&](const unsigned short* ih, const unsigned short* il,
                  unsigned short* oh, unsigned short* ol, int logWo) {
    long total = 2l * (1l << (2 * logWo)) * 8;
    avgpool_nhwc_kernel<<<(int)(total / 256), 256, 0, stream>>>(ih, il, oh, ol, logWo);
  };

  // ---- @256: outs[0], resblock cl10[0], outs[1], resblock cl2[0]
  donutC(Xhi, Xlo, OFF_FIRST, 1, 0);
  conv9(Xhi, Xlo, off_cl10(0), Yhi, Ylo, 256, 8);
  conv9r(Yhi, Ylo, off_cl10(1), Xhi, Xlo, 256, 8);           // base = X @256
  donutC(Xhi, Xlo, off_dilres(0), 3, 64);
  conv9(Xhi, Xlo, off_cl2(0), Yhi, Ylo, 256, 8);
  conv9r(Yhi, Ylo, off_cl2(1), Xhi, Xlo, 256, 8);            // base = X @256

  // ---- i = 0 (dil 5 @256)
  donutA(Xhi, Xlo, off_dil(0), 5, Yhi, Ylo, 256, 8);
  upsC(Yhi, Ylo, off_ups(0), 256, 8, 128);
  avgp(Xhi, Xlo, Yhi, Ylo, 7);                               // base = Y @128
  conv9(Yhi, Ylo, off_cl10(2), Xhi, Xlo, 128, 7);
  conv9r(Xhi, Xlo, off_cl10(3), Yhi, Ylo, 128, 7);           // base = Y @128
  donutA(Yhi, Ylo, off_dilres(1), 6, Xhi, Xlo, 128, 7);
  upsC(Xhi, Xlo, off_ups(1), 128, 7, 192);
  conv9(Yhi, Ylo, off_cl2(2), Xhi, Xlo, 128, 7);
  conv9r(Xhi, Xlo, off_cl2(3), Yhi, Ylo, 128, 7);            // base = Y @128

  // ---- i = 1 (dil 8 @128)
  donutA(Yhi, Ylo, off_dil(1), 8, Xhi, Xlo, 128, 7);
  upsC(Xhi, Xlo, off_ups(1), 128, 7, 256);
  avgp(Yhi, Ylo, Xhi, Xlo, 6);                               // base = X @64
  conv9(Xhi, Xlo, off_cl10(4), Yhi, Ylo, 64, 6);
  conv9r(Yhi, Ylo, off_cl10(5), Xhi, Xlo, 64, 6);            // base = X @64
  donutA(Xhi, Xlo, off_dilres(2), 8, Yhi, Ylo, 64, 6);
  upsC(Yhi, Ylo, off_ups(2), 64, 6, 320);
  conv9(Xhi, Xlo, off_cl2(4), Yhi, Ylo, 64, 6);
  conv9r(Yhi, Ylo, off_cl2(5), Xhi, Xlo, 64, 6);             // base = X @64

  // ---- i = 2 (dil 10 @64)
  donutA(Xhi, Xlo, off_dil(2), 10, Yhi, Ylo, 64, 6);
  upsC(Yhi, Ylo, off_ups(2), 64, 6, 384);
  avgp(Xhi, Xlo, Yhi, Ylo, 5);                               // base = Y @32
  conv9(Yhi, Ylo, off_cl10(6), Xhi, Xlo, 32, 5);
  conv9r(Xhi, Xlo, off_cl10(7), Yhi, Ylo, 32, 5);            // base = Y @32
  donutA(Yhi, Ylo, off_dilres(3), 9, Xhi, Xlo, 32, 5);
  upsC(Xhi, Xlo, off_ups(3), 32, 5, 448);
  conv9(Yhi, Ylo, off_cl2(6), Xhi, Xlo, 32, 5);
  conv9r(Xhi, Xlo, off_cl2(7), Yhi, Ylo, 32, 5);             // base = Y @32

  // ---- i = 3 (dil 11 @32)
  donutA(Yhi, Ylo, off_dil(3), 11, Xhi, Xlo, 32, 5);
  upsC(Xhi, Xlo, off_ups(3), 32, 5, 512);

  // ---- head: 2 px-chunks, h bounced through dead act region
  for (int c = 0; c < 2; c++) {
    out1_gemm_kernel<<<dim3(CHPX / 64, 2), 256, 0, stream>>>(
        concat, w1p, hbuf, c * CHPX);
    out2_gemm_kernel<<<dim3(CHPX / 256, 2), 256, 0, stream>>>(
        hbuf, w2p, w3, (float*)d_out, c * CHPX);
  }
}

// Round 11
// 972.304 us; speedup vs baseline: 6.5786x; 1.1211x over previous
//
#include <hip/hip_runtime.h>
#include <hip/hip_bf16.h>

// ---------------------------------------------------------------------------
// SHINE forward, full bf16-MFMA version with hi/lo-split activations+weights.
// Workspace (222,445,568 B total, unchanged layout):
//   concat : bf16 NHWC [2][65536][576]          150,994,944 B
//   Xhi,Xlo,Yhi,Ylo : bf16 NHWC [2][65536][64]  4 x 16,777,216 B
//   packs  : conv B-frags (hi,lo)                 3,604,480 B
//   w1p    : head W1 frags                          663,552 B
//   w2p    : head W2 frags                           73,728 B
// R11: (a) conv0 split into elementwise + small-conv kernels with coalesced
//      short8 stores (was 1-px-per-wave, divergent, 2B scatter; 131 us);
//      (b) conv_pipe epilogue via f32 LDS transpose: coalesced resid loads
//      (short8) replace 32 scalar 2B loads/thread in conv9r.
//      Math order identical to R10 (same absmax).
// ---------------------------------------------------------------------------

#define HPX 65536   // 256*256
#define FCH 64
#define CHPX 32768  // head px-chunk

typedef __attribute__((ext_vector_type(8))) short  short8;
typedef __attribute__((ext_vector_type(4))) float  floatx4;

__device__ __forceinline__ float gelu_f(float x) {
  return 0.5f * x * (1.0f + erff(x * 0.70710678118654752440f));
}
__device__ __forceinline__ unsigned short f2bf(float x) {  // RNE
  unsigned u = __float_as_uint(x);
  unsigned r = (u + 0x7FFFu + ((u >> 16) & 1u)) >> 16;
  return (unsigned short)r;
}
__device__ __forceinline__ float bf2f(unsigned short h) {
  return __uint_as_float(((unsigned)h) << 16);
}

// ---------------- conv0 part A: channels 0..47 = gelu(w0b[c] * target)
__global__ __launch_bounds__(256) void conv0_elem_kernel(
    const float* __restrict__ img,   // [2][5][256][256]
    const float* __restrict__ w0b,   // [48]
    unsigned short* __restrict__ ohi,  // [2][65536][64]
    unsigned short* __restrict__ olo)
{
  int t = blockIdx.x * 256 + threadIdx.x;     // over 2*HPX*6 = 786432
  int cg = t % 6;
  int pn = t / 6;                              // n*HPX + px
  int px = pn & (HPX - 1);
  int n  = pn >> 16;
  float x = img[(long)n * 5 * HPX + 2 * HPX + px];
  short8 oh, ol;
  #pragma unroll
  for (int j = 0; j < 8; j++) {
    int c = cg * 8 + j;
    float v = gelu_f(w0b[c] * x);
    unsigned short hb = f2bf(v);
    oh[j] = (short)hb;
    ol[j] = (short)f2bf(v - bf2f(hb));
  }
  long o = ((long)pn) * 64 + cg * 8;
  *(short8*)&ohi[o] = oh;
  *(short8*)&olo[o] = ol;
}

// ---------------- conv0 part B: channels 48..63 = gelu(3x3 conv over 4 feats)
__global__ __launch_bounds__(256) void conv0_conv_kernel(
    const float* __restrict__ img,   // [2][5][256][256]
    const float* __restrict__ w0a,   // [16][4][3][3]
    unsigned short* __restrict__ ohi,
    unsigned short* __restrict__ olo)
{
  int t = blockIdx.x * 256 + threadIdx.x;     // over 2*HPX*2 = 262144
  int cg = t & 1;
  int pn = t >> 1;
  int px = pn & (HPX - 1);
  int n  = pn >> 16;
  int y = px >> 8, x = px & 255;
  const float* im = img + (long)n * 5 * HPX;
  const int map4[4] = {0, 1, 3, 4};
  float vreg[36];
  #pragma unroll
  for (int fi = 0; fi < 4; fi++)
    #pragma unroll
    for (int ky = 0; ky < 3; ky++)
      #pragma unroll
      for (int kx = 0; kx < 3; kx++) {
        int yy = y + ky - 1, xx = x + kx - 1;
        bool ok = ((unsigned)yy < 256u) && ((unsigned)xx < 256u);
        vreg[(fi * 3 + ky) * 3 + kx] =
            ok ? im[(long)map4[fi] * HPX + yy * 256 + xx] : 0.0f;
      }
  short8 oh, ol;
  #pragma unroll
  for (int j = 0; j < 8; j++) {
    int co = cg * 8 + j;                       // 0..15 -> output ch 48+co
    const float* wr = w0a + co * 36;
    float r = 0.0f;
    #pragma unroll
    for (int q = 0; q < 36; q++) r = fmaf(wr[q], vreg[q], r);
    float v = gelu_f(r);
    unsigned short hb = f2bf(v);
    oh[j] = (short)hb;
    ol[j] = (short)f2bf(v - bf2f(hb));
  }
  long o = ((long)pn) * 64 + 48 + cg * 8;
  *(short8*)&ohi[o] = oh;
  *(short8*)&olo[o] = ol;
}

// ---------------- batched conv-weight packing into MFMA B-frags (hi,lo)
struct JobArr { int4 j[29]; };   // {src_sel, src_off, ntaps, dst_off}

__global__ __launch_bounds__(256) void pack_conv_kernel(
    const float* __restrict__ cl10, const float* __restrict__ cl2,
    const float* __restrict__ first_p, const float* __restrict__ dilres_p,
    const float* __restrict__ dil_p, const float* __restrict__ ups_w,
    unsigned short* __restrict__ packs, JobArr jobs)
{
  int4 jb = jobs.j[blockIdx.y];
  int ntaps = jb.z;
  int idx = blockIdx.x * 256 + threadIdx.x;
  if (idx >= ntaps * 8192) return;
  int j  = idx & 7;
  int l  = (idx >> 3) & 63;
  int s  = (idx >> 9) & 1;
  int nt = (idx >> 10) & 3;
  int kt = (idx >> 12) & 1;
  int tap = idx >> 13;
  int oc = nt * 16 + (l & 15);
  int ci = kt * 32 + (l >> 4) * 8 + j;
  const float* src;
  switch (jb.x) {
    case 0: src = cl10; break;
    case 1: src = cl2; break;
    case 2: src = first_p; break;
    case 3: src = dilres_p; break;
    case 4: src = dil_p; break;
    default: src = ups_w; break;
  }
  float w = src[jb.y + (oc * 64 + ci) * ntaps + tap];
  unsigned short hi = f2bf(w);
  unsigned short v = (s == 0) ? hi : f2bf(w - bf2f(hi));
  packs[jb.w + idx] = v;
}

// ---------------- head weight packing (hi+lo)
__global__ __launch_bounds__(256) void pack_w1_kernel(
    const float* __restrict__ w1, unsigned short* __restrict__ w1p)
{
  int t = blockIdx.x * 256 + threadIdx.x;      // 18*18*512
  if (t >= 18 * 18 * 512) return;
  int j = t & 7, l = (t >> 3) & 63;
  int mt = (t >> 9) % 18, kt = (t >> 9) / 18;
  int oc = mt * 16 + (l & 15);
  int k  = kt * 32 + (l >> 4) * 8 + j;
  float w = w1[oc * 576 + k];
  unsigned short hi = f2bf(w);
  unsigned short lo = f2bf(w - bf2f(hi));
  long base = ((long)(kt * 18 + mt) * 2) * 512 + l * 8 + j;
  w1p[base] = hi;
  w1p[base + 512] = lo;
}
__global__ __launch_bounds__(256) void pack_w2_kernel(
    const float* __restrict__ w2, unsigned short* __restrict__ w2p)
{
  int t = blockIdx.x * 256 + threadIdx.x;      // 9*4*512
  if (t >= 9 * 4 * 512) return;
  int j = t & 7, l = (t >> 3) & 63;
  int ot = (t >> 9) % 4, kt = (t >> 9) / 4;
  int oc = ot * 16 + (l & 15);
  int k  = kt * 32 + (l >> 4) * 8 + j;
  float w = w2[oc * 288 + k];
  unsigned short hi = f2bf(w);
  unsigned short lo = f2bf(w - bf2f(hi));
  long base = ((long)(kt * 4 + ot) * 2) * 512 + l * 8 + j;
  w2p[base] = hi;
  w2p[base + 512] = lo;
}

// ---------------- software-pipelined MFMA conv (implicit GEMM, 16x16x32 bf16)
// Pipeline per tap as R9. Epilogue: acc -> f32 LDS transpose tile -> coalesced
// resid loads (short8) -> gelu -> coalesced short8 stores.
template <int NTAPS, int MT, bool RESID, bool TO_CONCAT>
__global__ __launch_bounds__(256) void conv_pipe_kernel(
    const unsigned short* __restrict__ in_hi,   // NHWC [n][npx_in][64]
    const unsigned short* __restrict__ in_lo,
    const unsigned short* __restrict__ wp,      // packed frags
    const unsigned short* __restrict__ res_hi,
    const unsigned short* __restrict__ res_lo,
    unsigned short* __restrict__ out_hi,        // act hi or concat
    unsigned short* __restrict__ out_lo,
    int Hs, int logW, int dil, int ccol)
{
  __shared__ short8 wst[2][1024];               // 2 x 16 KB double buffer
  __shared__ float  ftb[4][16][65];             // per-wave f32 transpose tiles
  const int tid  = threadIdx.x;
  const int lane = tid & 63;
  const int wave = tid >> 6;
  const int row  = lane & 15;
  const int g    = lane >> 4;
  const int n    = blockIdx.z;
  const int Ws   = 1 << logW;
  const int npx_in = Hs << logW;
  const int opx0 = blockIdx.x * (64 * MT) + wave * (16 * MT);

  const unsigned short* ihi = in_hi + (long)n * npx_in * 64;
  const unsigned short* ilo = in_lo + (long)n * npx_in * 64;
  const short8* wpv = (const short8*)wp;

  int ry[MT], rx[MT];
  #pragma unroll
  for (int mt = 0; mt < MT; mt++) {
    int p = opx0 + mt * 16 + row;
    ry[mt] = p >> logW;
    rx[mt] = p & (Ws - 1);
  }

  floatx4 acc[MT][4];
  #pragma unroll
  for (int mt = 0; mt < MT; mt++)
    #pragma unroll
    for (int nt = 0; nt < 4; nt++) acc[mt][nt] = (floatx4){0.f, 0.f, 0.f, 0.f};

  const short8 zz = {0, 0, 0, 0, 0, 0, 0, 0};
  short8 sreg[4];
  short8 ahA[MT][2], alA[MT][2], ahB[MT][2], alB[MT][2];

  auto stage_issue = [&](int t) {
    #pragma unroll
    for (int p = 0; p < 4; p++)
      sreg[p] = wpv[(long)t * 1024 + tid + p * 256];
  };
  auto stage_write = [&](int b) {
    #pragma unroll
    for (int p = 0; p < 4; p++)
      wst[b][tid + p * 256] = sreg[p];
  };
  auto a_load = [&](short8 (&ah)[MT][2], short8 (&al)[MT][2], int t) {
    const int kk  = (NTAPS == 9) ? t : (t < 4 ? t : t + 1);
    const int dyd = (kk / 3 - 1) * dil, dxd = (kk % 3 - 1) * dil;
    #pragma unroll
    for (int mt = 0; mt < MT; mt++) {
      int yy = ry[mt] + dyd, xx = rx[mt] + dxd;
      bool ok = ((unsigned)yy < (unsigned)Hs) && ((unsigned)xx < (unsigned)Ws);
      long base = ok ? (long)((yy << logW) + xx) * 64 : 0;
      #pragma unroll
      for (int kt = 0; kt < 2; kt++) {
        long a = base + kt * 32 + g * 8;
        short8 h = *(const short8*)(ihi + a);
        short8 l = *(const short8*)(ilo + a);
        ah[mt][kt] = ok ? h : zz;
        al[mt][kt] = ok ? l : zz;
      }
    }
  };
  auto compute = [&](int b, short8 (&ah)[MT][2], short8 (&al)[MT][2]) {
    #pragma unroll
    for (int kt = 0; kt < 2; kt++)
      #pragma unroll
      for (int nt = 0; nt < 4; nt++) {
        short8 bh = wst[b][(kt * 4 + nt) * 128 + lane];
        short8 bl = wst[b][(kt * 4 + nt) * 128 + 64 + lane];
        #pragma unroll
        for (int mt = 0; mt < MT; mt++) {
          acc[mt][nt] = __builtin_amdgcn_mfma_f32_16x16x32_bf16(ah[mt][kt], bh, acc[mt][nt], 0, 0, 0);
          acc[mt][nt] = __builtin_amdgcn_mfma_f32_16x16x32_bf16(ah[mt][kt], bl, acc[mt][nt], 0, 0, 0);
          acc[mt][nt] = __builtin_amdgcn_mfma_f32_16x16x32_bf16(al[mt][kt], bh, acc[mt][nt], 0, 0, 0);
        }
      }
  };

  // prologue: stage + A for tap 0
  stage_issue(0);
  a_load(ahA, alA, 0);
  stage_write(0);
  __syncthreads();

  #pragma unroll
  for (int tt = 0; tt < NTAPS; tt++) {
    const int b = tt & 1;
    if (tt + 1 < NTAPS) {
      stage_issue(tt + 1);                       // global loads, early
      if ((tt & 1) == 0) a_load(ahB, alB, tt + 1);
      else               a_load(ahA, alA, tt + 1);
    }
    if ((tt & 1) == 0) compute(b, ahA, alA);     // hides the loads above
    else               compute(b, ahB, alB);
    if (tt + 1 < NTAPS) {
      stage_write(b ^ 1);                        // write-late into other buf
      __syncthreads();                           // ONE barrier per tap
    }
  }

  // epilogue: acc -> f32 LDS tile -> (+coalesced resid) -> gelu -> short8 out
  #pragma unroll
  for (int mt = 0; mt < MT; mt++) {
    __builtin_amdgcn_wave_barrier();
    #pragma unroll
    for (int nt = 0; nt < 4; nt++)
      #pragma unroll
      for (int r = 0; r < 4; r++)
        ftb[wave][g * 4 + r][nt * 16 + row] = acc[mt][nt][r];
    __builtin_amdgcn_wave_barrier();
    const int pxb = opx0 + mt * 16;
    const int pxl = lane >> 2;
    #pragma unroll
    for (int it = 0; it < 2; it++) {
      const int ch = (lane & 3) + it * 4;
      float vv[8];
      #pragma unroll
      for (int j = 0; j < 8; j++) vv[j] = ftb[wave][pxl][ch * 8 + j];
      if (RESID) {
        long rb = ((long)n * npx_in + pxb + pxl) * 64 + ch * 8;
        short8 rh = *(const short8*)(res_hi + rb);
        short8 rl = *(const short8*)(res_lo + rb);
        #pragma unroll
        for (int j = 0; j < 8; j++)
          vv[j] += bf2f((unsigned short)rh[j]) + bf2f((unsigned short)rl[j]);
      }
      short8 oh8, ol8;
      #pragma unroll
      for (int j = 0; j < 8; j++) {
        float v = gelu_f(vv[j]);
        unsigned short hb = f2bf(v);
        oh8[j] = (short)hb;
        ol8[j] = (short)f2bf(v - bf2f(hb));
      }
      if (TO_CONCAT) {
        *(short8*)&out_hi[((long)n * HPX + pxb + pxl) * 576 + ccol + ch * 8] = oh8;
      } else {
        *(short8*)&out_hi[((long)n * npx_in + pxb + pxl) * 64 + ch * 8] = oh8;
        *(short8*)&out_lo[((long)n * npx_in + pxb + pxl) * 64 + ch * 8] = ol8;
      }
    }
  }
}

// ---------------- bilinear-upsample 1x1 conv -> concat (coalesced epilogue)
template <int MT>
__global__ __launch_bounds__(256) void ups_mfma_kernel(
    const unsigned short* __restrict__ in_hi,   // NHWC [n][npx_in][64]
    const unsigned short* __restrict__ in_lo,
    const unsigned short* __restrict__ wp,      // packed frags (1 tap)
    unsigned short* __restrict__ outc,          // concat
    int Hs, int logW, int ccol)
{
  __shared__ short8 wst[1024];                  // 16 KB: one tap's 16 frags
  __shared__ unsigned short tb[4][16][76];
  const int tid  = threadIdx.x;
  const int lane = threadIdx.x & 63;
  const int wave = threadIdx.x >> 6;
  const int row  = lane & 15;
  const int g    = lane >> 4;
  const int n    = blockIdx.z;
  const int npx_in = Hs << logW;
  const int opx0 = blockIdx.x * (64 * MT) + wave * (16 * MT);

  const unsigned short* ihi = in_hi + (long)n * npx_in * 64;
  const unsigned short* ilo = in_lo + (long)n * npx_in * 64;
  const short8* wpv = (const short8*)wp;

  int b00[MT], b01[MT], b10[MT], b11[MT];
  float bwx[MT], bwy[MT];
  #pragma unroll
  for (int mt = 0; mt < MT; mt++) {
    int p = opx0 + mt * 16 + row;
    int Y = p >> 8, X = p & 255;
    float sc = (float)Hs * (1.0f / 256.0f);
    float fy = ((float)Y + 0.5f) * sc - 0.5f;
    float fx = ((float)X + 0.5f) * sc - 0.5f;
    int y0 = (int)floorf(fy), x0 = (int)floorf(fx);
    bwy[mt] = fy - (float)y0; bwx[mt] = fx - (float)x0;
    int y0c = min(max(y0, 0), Hs - 1), y1c = min(max(y0 + 1, 0), Hs - 1);
    int x0c = min(max(x0, 0), Hs - 1), x1c = min(max(x0 + 1, 0), Hs - 1);
    b00[mt] = (y0c * Hs + x0c) * 64; b01[mt] = (y0c * Hs + x1c) * 64;
    b10[mt] = (y1c * Hs + x0c) * 64; b11[mt] = (y1c * Hs + x1c) * 64;
  }

  floatx4 acc[MT][4];
  #pragma unroll
  for (int mt = 0; mt < MT; mt++)
    #pragma unroll
    for (int nt = 0; nt < 4; nt++) acc[mt][nt] = (floatx4){0.f, 0.f, 0.f, 0.f};

  #pragma unroll
  for (int p = 0; p < 4; p++)
    wst[tid + p * 256] = wpv[tid + p * 256];
  __syncthreads();

  #pragma unroll
  for (int kt = 0; kt < 2; kt++) {
    const int ko = kt * 32 + g * 8;
    short8 ah[MT], al[MT];
    #pragma unroll
    for (int mt = 0; mt < MT; mt++) {
      short8 h00 = *(const short8*)(ihi + b00[mt] + ko);
      short8 l00 = *(const short8*)(ilo + b00[mt] + ko);
      short8 h01 = *(const short8*)(ihi + b01[mt] + ko);
      short8 l01 = *(const short8*)(ilo + b01[mt] + ko);
      short8 h10 = *(const short8*)(ihi + b10[mt] + ko);
      short8 l10 = *(const short8*)(ilo + b10[mt] + ko);
      short8 h11 = *(const short8*)(ihi + b11[mt] + ko);
      short8 l11 = *(const short8*)(ilo + b11[mt] + ko);
      short8 hh, ll;
      #pragma unroll
      for (int j = 0; j < 8; j++) {
        float v00 = bf2f((unsigned short)h00[j]) + bf2f((unsigned short)l00[j]);
        float v01 = bf2f((unsigned short)h01[j]) + bf2f((unsigned short)l01[j]);
        float v10 = bf2f((unsigned short)h10[j]) + bf2f((unsigned short)l10[j]);
        float v11 = bf2f((unsigned short)h11[j]) + bf2f((unsigned short)l11[j]);
        float v0 = v00 + bwx[mt] * (v01 - v00);
        float v1 = v10 + bwx[mt] * (v11 - v10);
        float v  = v0 + bwy[mt] * (v1 - v0);
        unsigned short hb = f2bf(v);
        hh[j] = (short)hb;
        ll[j] = (short)f2bf(v - bf2f(hb));
      }
      ah[mt] = hh; al[mt] = ll;
    }
    #pragma unroll
    for (int nt = 0; nt < 4; nt++) {
      short8 bh = wst[(kt * 4 + nt) * 2 * 64 + lane];
      short8 bl = wst[((kt * 4 + nt) * 2 + 1) * 64 + lane];
      #pragma unroll
      for (int mt = 0; mt < MT; mt++) {
        acc[mt][nt] = __builtin_amdgcn_mfma_f32_16x16x32_bf16(ah[mt], bh, acc[mt][nt], 0, 0, 0);
        acc[mt][nt] = __builtin_amdgcn_mfma_f32_16x16x32_bf16(ah[mt], bl, acc[mt][nt], 0, 0, 0);
        acc[mt][nt] = __builtin_amdgcn_mfma_f32_16x16x32_bf16(al[mt], bh, acc[mt][nt], 0, 0, 0);
      }
    }
  }

  #pragma unroll
  for (int mt = 0; mt < MT; mt++) {
    __builtin_amdgcn_wave_barrier();
    #pragma unroll
    for (int nt = 0; nt < 4; nt++)
      #pragma unroll
      for (int r = 0; r < 4; r++)
        tb[wave][g * 4 + r][nt * 16 + row] = f2bf(gelu_f(acc[mt][nt][r]));
    __builtin_amdgcn_wave_barrier();
    const int pxb = opx0 + mt * 16;
    const int pxl = lane >> 2;
    #pragma unroll
    for (int it = 0; it < 2; it++) {
      int ch = (lane & 3) + it * 4;
      short8 v8 = *(const short8*)&tb[wave][pxl][ch * 8];
      *(short8*)&outc[((long)n * HPX + pxb + pxl) * 576 + ccol + ch * 8] = v8;
    }
  }
}

// ---------------- 2x2 average pool, NHWC hi/lo -> NHWC hi/lo
__global__ __launch_bounds__(256) void avgpool_nhwc_kernel(
    const unsigned short* __restrict__ ihi, const unsigned short* __restrict__ ilo,
    unsigned short* __restrict__ ohi, unsigned short* __restrict__ olo,
    int logWo)
{
  const int lognpo = 2 * logWo;
  long t = (long)blockIdx.x * 256 + threadIdx.x;   // over 2*npo*8
  int cg = (int)(t & 7);
  int p  = (int)((t >> 3) & ((1 << lognpo) - 1));
  int n  = (int)(t >> (3 + lognpo));
  int y = p >> logWo, x = p & ((1 << logWo) - 1);
  int Wi = 2 << logWo;
  long ib = ((long)n * (4 << lognpo) + (long)(2 * y) * Wi + 2 * x) * 64 + cg * 8;
  short8 h00 = *(const short8*)(ihi + ib);
  short8 h01 = *(const short8*)(ihi + ib + 64);
  short8 h10 = *(const short8*)(ihi + ib + (long)Wi * 64);
  short8 h11 = *(const short8*)(ihi + ib + (long)Wi * 64 + 64);
  short8 l00 = *(const short8*)(ilo + ib);
  short8 l01 = *(const short8*)(ilo + ib + 64);
  short8 l10 = *(const short8*)(ilo + ib + (long)Wi * 64);
  short8 l11 = *(const short8*)(ilo + ib + (long)Wi * 64 + 64);
  short8 oh, ol;
  #pragma unroll
  for (int j = 0; j < 8; j++) {
    float v = 0.25f * ((bf2f((unsigned short)h00[j]) + bf2f((unsigned short)l00[j])) +
                       (bf2f((unsigned short)h01[j]) + bf2f((unsigned short)l01[j])) +
                       (bf2f((unsigned short)h10[j]) + bf2f((unsigned short)l10[j])) +
                       (bf2f((unsigned short)h11[j]) + bf2f((unsigned short)l11[j])));
    unsigned short hb = f2bf(v);
    oh[j] = (short)hb;
    ol[j] = (short)f2bf(v - bf2f(hb));
  }
  long ob = (((long)n << lognpo) + p) * 64 + cg * 8;
  *(short8*)(ohi + ob) = oh;
  *(short8*)(olo + ob) = ol;
}

// ---------------- head stage 1 GEMM: h = gelu(W1 @ concat), one px-chunk
__global__ __launch_bounds__(256) void out1_gemm_kernel(
    const unsigned short* __restrict__ v,       // concat NHWC [2][65536][576]
    const unsigned short* __restrict__ w1p,
    unsigned short* __restrict__ h,             // [2][CHPX][288] bf16
    int cpx)
{
  __shared__ short8 ws8[2400];                  // 38,400 B (stage / transpose)
  const int tid  = threadIdx.x;
  const int lane = tid & 63;
  const int wave = tid >> 6;
  const int row  = lane & 15;
  const int g    = lane >> 4;
  const int n    = blockIdx.y;
  const int px0  = cpx + blockIdx.x * 64;       // absolute px
  const int mtb  = (wave < 2) ? wave * 5 : 10 + (wave - 2) * 4;
  const int MTN  = (wave < 2) ? 5 : 4;
  const short8* w1v = (const short8*)w1p;

  floatx4 acc[4][5];
  #pragma unroll
  for (int t = 0; t < 4; t++)
    #pragma unroll
    for (int m = 0; m < 5; m++) acc[t][m] = (floatx4){0.f, 0.f, 0.f, 0.f};

  for (int kt = 0; kt < 18; kt++) {
    __syncthreads();                             // prev kt's LDS reads done
    #pragma unroll
    for (int p = 0; p < 9; p++)
      ws8[tid + p * 256] = w1v[kt * 2304 + tid + p * 256];
    __syncthreads();

    short8 a[4];
    #pragma unroll
    for (int t = 0; t < 4; t++)
      a[t] = *(const short8*)(v + ((long)n * HPX + px0 + t * 16 + row) * 576 +
                              kt * 32 + g * 8);
    #pragma unroll
    for (int m = 0; m < 5; m++) {
      if (m < MTN) {
        short8 bh = ws8[((mtb + m) * 2 + 0) * 64 + lane];
        short8 bl = ws8[((mtb + m) * 2 + 1) * 64 + lane];
        #pragma unroll
        for (int t = 0; t < 4; t++) {
          acc[t][m] = __builtin_amdgcn_mfma_f32_16x16x32_bf16(a[t], bh, acc[t][m], 0, 0, 0);
          acc[t][m] = __builtin_amdgcn_mfma_f32_16x16x32_bf16(a[t], bl, acc[t][m], 0, 0, 0);
        }
      }
    }
  }

  // epilogue: gelu -> bf16 -> LDS [64][300] -> coalesced h writes
  __syncthreads();
  unsigned short* hs2 = (unsigned short*)ws8;
  #pragma unroll
  for (int m = 0; m < 5; m++) {
    if (m < MTN) {
      #pragma unroll
      for (int t = 0; t < 4; t++)
        #pragma unroll
        for (int r = 0; r < 4; r++)
          hs2[(t * 16 + g * 4 + r) * 300 + (mtb + m) * 16 + row] =
              f2bf(gelu_f(acc[t][m][r]));
    }
  }
  __syncthreads();
  #pragma unroll
  for (int p = 0; p < 9; p++) {
    int li = tid + p * 256;                      // 2304 chunks of 16B
    int px = li / 36, c16 = li % 36;
    short8 v8 = *(const short8*)&hs2[px * 300 + c16 * 8];
    *(short8*)&h[((long)n * CHPX + (px0 - cpx) + px) * 288 + c16 * 8] = v8;
  }
}

// ---------------- head stage 2: out = w3 . gelu(W2 @ h), one px-chunk
__global__ __launch_bounds__(256) void out2_gemm_kernel(
    const unsigned short* __restrict__ h,       // [2][CHPX][288] bf16
    const unsigned short* __restrict__ w2p,
    const float* __restrict__ w3,               // [64]
    float* __restrict__ out,                    // [2][65536]
    int cpx)
{
  __shared__ short8 w2s[4608];                  // 73,728 B, whole w2p
  const int tid  = threadIdx.x;
  const int lane = tid & 63;
  const int wave = tid >> 6;
  const int row  = lane & 15;
  const int g    = lane >> 4;
  const int n    = blockIdx.y;
  const int pxc  = blockIdx.x * 256 + wave * 64; // px within chunk
  const short8* w2v = (const short8*)w2p;

  #pragma unroll
  for (int p = 0; p < 18; p++)
    w2s[tid + p * 256] = w2v[tid + p * 256];
  __syncthreads();

  floatx4 acc2[4][4];
  #pragma unroll
  for (int t = 0; t < 4; t++)
    #pragma unroll
    for (int ot = 0; ot < 4; ot++) acc2[t][ot] = (floatx4){0.f, 0.f, 0.f, 0.f};

  for (int kt = 0; kt < 9; kt++) {
    short8 a[4];
    #pragma unroll
    for (int t = 0; t < 4; t++)
      a[t] = *(const short8*)&h[((long)n * CHPX + pxc + t * 16 + row) * 288 +
                                kt * 32 + g * 8];
    #pragma unroll
    for (int ot = 0; ot < 4; ot++) {
      short8 bh = w2s[((kt * 4 + ot) * 2 + 0) * 64 + lane];
      short8 bl = w2s[((kt * 4 + ot) * 2 + 1) * 64 + lane];
      #pragma unroll
      for (int t = 0; t < 4; t++) {
        acc2[t][ot] = __builtin_amdgcn_mfma_f32_16x16x32_bf16(a[t], bh, acc2[t][ot], 0, 0, 0);
        acc2[t][ot] = __builtin_amdgcn_mfma_f32_16x16x32_bf16(a[t], bl, acc2[t][ot], 0, 0, 0);
      }
    }
  }

  float w3r[4];
  #pragma unroll
  for (int ot = 0; ot < 4; ot++) w3r[ot] = w3[ot * 16 + row];
  #pragma unroll
  for (int t = 0; t < 4; t++) {
    float r[4] = {0.f, 0.f, 0.f, 0.f};
    #pragma unroll
    for (int ot = 0; ot < 4; ot++)
      #pragma unroll
      for (int rr = 0; rr < 4; rr++)
        r[rr] = fmaf(w3r[ot], gelu_f(acc2[t][ot][rr]), r[rr]);
    #pragma unroll
    for (int rr = 0; rr < 4; rr++) {
      r[rr] += __shfl_xor(r[rr], 1);
      r[rr] += __shfl_xor(r[rr], 2);
      r[rr] += __shfl_xor(r[rr], 4);
      r[rr] += __shfl_xor(r[rr], 8);
    }
    if (row == 0) {
      int px = cpx + pxc + t * 16 + g * 4;
      #pragma unroll
      for (int rr = 0; rr < 4; rr++)
        out[(long)n * HPX + px + rr] = r[rr];
    }
  }
}

// ---------------------------------------------------------------------------
extern "C" void kernel_launch(void* const* d_in, const int* in_sizes, int n_in,
                              void* d_out, int out_size, void* d_ws, size_t ws_size,
                              hipStream_t stream) {
  const float* img      = (const float*)d_in[0];
  const float* w0a      = (const float*)d_in[1];
  const float* w0b      = (const float*)d_in[2];
  const float* first_p  = (const float*)d_in[3];
  const float* cl10     = (const float*)d_in[4];   // [4][2][64][64][9]
  const float* cl2      = (const float*)d_in[5];
  const float* dil_p    = (const float*)d_in[6];   // [4][64][64][8]
  const float* dilres_p = (const float*)d_in[7];
  const float* ups_w    = (const float*)d_in[8];   // [4][64][64]
  const float* w1       = (const float*)d_in[9];   // [288][576]
  const float* w2       = (const float*)d_in[10];  // [64][288]
  const float* w3       = (const float*)d_in[11];  // [64]

  const size_t CONCAT_B = 150994944ul;             // 2*65536*576*2
  const size_t ACT_B    = 16777216ul;              // 2*65536*64*2 per plane
  const size_t PACKS_B  = 3604480ul;               // 1,802,240 elems
  const size_t W1P_B    = 663552ul;
  const size_t W2P_B    = 73728ul;
  const size_t NEED = CONCAT_B + 4 * ACT_B + PACKS_B + W1P_B + W2P_B; // 222,445,568

  if (ws_size < NEED) {
    hipMemsetAsync(d_out, 0, (size_t)out_size * 4, stream);
    return;
  }

  char* wsb = (char*)d_ws;
  unsigned short* concat = (unsigned short*)wsb;
  unsigned short* Xhi = (unsigned short*)(wsb + CONCAT_B);
  unsigned short* Xlo = (unsigned short*)(wsb + CONCAT_B + ACT_B);
  unsigned short* Yhi = (unsigned short*)(wsb + CONCAT_B + 2 * ACT_B);
  unsigned short* Ylo = (unsigned short*)(wsb + CONCAT_B + 3 * ACT_B);
  unsigned short* packs = (unsigned short*)(wsb + CONCAT_B + 4 * ACT_B);
  unsigned short* w1p = (unsigned short*)(wsb + CONCAT_B + 4 * ACT_B + PACKS_B);
  unsigned short* w2p = (unsigned short*)(wsb + CONCAT_B + 4 * ACT_B + PACKS_B + W1P_B);
  unsigned short* hbuf = Xhi;   // head h buffer reuses dead act region

  // pack-destination offsets (elems)
  auto off_cl10   = [](int c) { return (long)c * 73728; };
  auto off_cl2    = [](int c) { return 589824l + (long)c * 73728; };
  const long OFF_FIRST = 1179648;
  auto off_dilres = [](int k) { return 1245184l + (long)k * 65536; };
  auto off_dil    = [](int k) { return 1507328l + (long)k * 65536; };
  auto off_ups    = [](int k) { return 1769472l + (long)k * 8192; };

  // ---- weight packing
  JobArr jobs;
  for (int c = 0; c < 8; c++) jobs.j[c]     = {0, c * 36864, 9, (int)off_cl10(c)};
  for (int c = 0; c < 8; c++) jobs.j[8 + c] = {1, c * 36864, 9, (int)off_cl2(c)};
  jobs.j[16] = {2, 0, 8, (int)OFF_FIRST};
  for (int k = 0; k < 4; k++) jobs.j[17 + k] = {3, k * 32768, 8, (int)off_dilres(k)};
  for (int k = 0; k < 4; k++) jobs.j[21 + k] = {4, k * 32768, 8, (int)off_dil(k)};
  for (int k = 0; k < 4; k++) jobs.j[25 + k] = {5, k * 4096, 1, (int)off_ups(k)};
  pack_conv_kernel<<<dim3(288, 29), 256, 0, stream>>>(
      cl10, cl2, first_p, dilres_p, dil_p, ups_w, packs, jobs);
  pack_w1_kernel<<<(18 * 18 * 512 + 255) / 256, 256, 0, stream>>>(w1, w1p);
  pack_w2_kernel<<<(9 * 4 * 512 + 255) / 256, 256, 0, stream>>>(w2, w2p);

  // ---- conv0 -> X @256 (elementwise part + 3x3 part)
  conv0_elem_kernel<<<(2 * HPX * 6) / 256, 256, 0, stream>>>(img, w0b, Xhi, Xlo);
  conv0_conv_kernel<<<(2 * HPX * 2) / 256, 256, 0, stream>>>(img, w0a, Xhi, Xlo);

  // ---- launch helpers (pipelined convs; MT=2 @256, MT=1 below)
  auto conv9 = [&](const unsigned short* ih, const unsigned short* il, long wo,
                   unsigned short* oh, unsigned short* ol, int Hs, int logW) {
    int npx = Hs << logW;
    if (npx == HPX)
      conv_pipe_kernel<9, 2, false, false><<<dim3(npx / 128, 1, 2), 256, 0, stream>>>(
          ih, il, packs + wo, nullptr, nullptr, oh, ol, Hs, logW, 1, 0);
    else
      conv_pipe_kernel<9, 1, false, false><<<dim3(npx / 64, 1, 2), 256, 0, stream>>>(
          ih, il, packs + wo, nullptr, nullptr, oh, ol, Hs, logW, 1, 0);
  };
  auto conv9r = [&](const unsigned short* ih, const unsigned short* il, long wo,
                    unsigned short* rh, unsigned short* rl, int Hs, int logW) {
    int npx = Hs << logW;
    if (npx == HPX)
      conv_pipe_kernel<9, 2, true, false><<<dim3(npx / 128, 1, 2), 256, 0, stream>>>(
          ih, il, packs + wo, rh, rl, rh, rl, Hs, logW, 1, 0);
    else
      conv_pipe_kernel<9, 1, true, false><<<dim3(npx / 64, 1, 2), 256, 0, stream>>>(
          ih, il, packs + wo, rh, rl, rh, rl, Hs, logW, 1, 0);
  };
  auto donutC = [&](const unsigned short* ih, const unsigned short* il, long wo,
                    int dil, int ccol) {  // @256 -> concat
    conv_pipe_kernel<8, 2, false, true><<<dim3(512, 1, 2), 256, 0, stream>>>(
        ih, il, packs + wo, nullptr, nullptr, concat, nullptr, 256, 8, dil, ccol);
  };
  auto donutA = [&](const unsigned short* ih, const unsigned short* il, long wo,
                    int dil, unsigned short* oh, unsigned short* ol, int Hs, int logW) {
    int npx = Hs << logW;
    if (npx == HPX)
      conv_pipe_kernel<8, 2, false, false><<<dim3(npx / 128, 1, 2), 256, 0, stream>>>(
          ih, il, packs + wo, nullptr, nullptr, oh, ol, Hs, logW, dil, 0);
    else
      conv_pipe_kernel<8, 1, false, false><<<dim3(npx / 64, 1, 2), 256, 0, stream>>>(
          ih, il, packs + wo, nullptr, nullptr, oh, ol, Hs, logW, dil, 0);
  };
  auto upsC = [&](const unsigned short* ih, const unsigned short* il, long wo,
                  int Hs, int logW, int ccol) {
    ups_mfma_kernel<4><<<dim3(256, 1, 2), 256, 0, stream>>>(
        ih, il, packs + wo, concat, Hs, logW, ccol);
  };
  auto avgp = [&](const unsigned short* ih, const unsigned short* il,
                  unsigned short* oh, unsigned short* ol, int logWo) {
    long total = 2l * (1l << (2 * logWo)) * 8;
    avgpool_nhwc_kernel<<<(int)(total / 256), 256, 0, stream>>>(ih, il, oh, ol, logWo);
  };

  // ---- @256: outs[0], resblock cl10[0], outs[1], resblock cl2[0]
  donutC(Xhi, Xlo, OFF_FIRST, 1, 0);
  conv9(Xhi, Xlo, off_cl10(0), Yhi, Ylo, 256, 8);
  conv9r(Yhi, Ylo, off_cl10(1), Xhi, Xlo, 256, 8);           // base = X @256
  donutC(Xhi, Xlo, off_dilres(0), 3, 64);
  conv9(Xhi, Xlo, off_cl2(0), Yhi, Ylo, 256, 8);
  conv9r(Yhi, Ylo, off_cl2(1), Xhi, Xlo, 256, 8);            // base = X @256

  // ---- i = 0 (dil 5 @256)
  donutA(Xhi, Xlo, off_dil(0), 5, Yhi, Ylo, 256, 8);
  upsC(Yhi, Ylo, off_ups(0), 256, 8, 128);
  avgp(Xhi, Xlo, Yhi, Ylo, 7);                               // base = Y @128
  conv9(Yhi, Ylo, off_cl10(2), Xhi, Xlo, 128, 7);
  conv9r(Xhi, Xlo, off_cl10(3), Yhi, Ylo, 128, 7);           // base = Y @128
  donutA(Yhi, Ylo, off_dilres(1), 6, Xhi, Xlo, 128, 7);
  upsC(Xhi, Xlo, off_ups(1), 128, 7, 192);
  conv9(Yhi, Ylo, off_cl2(2), Xhi, Xlo, 128, 7);
  conv9r(Xhi, Xlo, off_cl2(3), Yhi, Ylo, 128, 7);            // base = Y @128

  // ---- i = 1 (dil 8 @128)
  donutA(Yhi, Ylo, off_dil(1), 8, Xhi, Xlo, 128, 7);
  upsC(Xhi, Xlo, off_ups(1), 128, 7, 256);
  avgp(Yhi, Ylo, Xhi, Xlo, 6);                               // base = X @64
  conv9(Xhi, Xlo, off_cl10(4), Yhi, Ylo, 64, 6);
  conv9r(Yhi, Ylo, off_cl10(5), Xhi, Xlo, 64, 6);            // base = X @64
  donutA(Xhi, Xlo, off_dilres(2), 8, Yhi, Ylo, 64, 6);
  upsC(Yhi, Ylo, off_ups(2), 64, 6, 320);
  conv9(Xhi, Xlo, off_cl2(4), Yhi, Ylo, 64, 6);
  conv9r(Yhi, Ylo, off_cl2(5), Xhi, Xlo, 64, 6);             // base = X @64

  // ---- i = 2 (dil 10 @64)
  donutA(Xhi, Xlo, off_dil(2), 10, Yhi, Ylo, 64, 6);
  upsC(Yhi, Ylo, off_ups(2), 64, 6, 384);
  avgp(Xhi, Xlo, Yhi, Ylo, 5);                               // base = Y @32
  conv9(Yhi, Ylo, off_cl10(6), Xhi, Xlo, 32, 5);
  conv9r(Xhi, Xlo, off_cl10(7), Yhi, Ylo, 32, 5);            // base = Y @32
  donutA(Yhi, Ylo, off_dilres(3), 9, Xhi, Xlo, 32, 5);
  upsC(Xhi, Xlo, off_ups(3), 32, 5, 448);
  conv9(Yhi, Ylo, off_cl2(6), Xhi, Xlo, 32, 5);
  conv9r(Xhi, Xlo, off_cl2(7), Yhi, Ylo, 32, 5);             // base = Y @32

  // ---- i = 3 (dil 11 @32)
  donutA(Yhi, Ylo, off_dil(3), 11, Xhi, Xlo, 32, 5);
  upsC(Xhi, Xlo, off_ups(3), 32, 5, 512);

  // ---- head: 2 px-chunks, h bounced through dead act region
  for (int c = 0; c < 2; c++) {
    out1_gemm_kernel<<<dim3(CHPX / 64, 2), 256, 0, stream>>>(
        concat, w1p, hbuf, c * CHPX);
    out2_gemm_kernel<<<dim3(CHPX / 256, 2), 256, 0, stream>>>(
        hbuf, w2p, w3, (float*)d_out, c * CHPX);
  }
}

// Round 12
// 970.760 us; speedup vs baseline: 6.5891x; 1.0016x over previous
//
#include <hip/hip_runtime.h>
#include <hip/hip_bf16.h>

// ---------------------------------------------------------------------------
// SHINE forward, full bf16-MFMA version with hi/lo-split activations+weights.
// Workspace (222,445,568 B total, unchanged layout):
//   concat : bf16 NHWC [2][65536][576]          150,994,944 B
//   Xhi,Xlo,Yhi,Ylo : bf16 NHWC [2][65536][64]  4 x 16,777,216 B
//   packs  : conv B-frags (hi,lo)                 3,604,480 B
//   w1p    : head W1 frags                          663,552 B
//   w2p    : head W2 frags                           73,728 B
// R11: (a) conv0 split into elementwise + small-conv kernels with coalesced
//      short8 stores (was 1-px-per-wave, divergent, 2B scatter; 131 us);
//      (b) conv_pipe epilogue via f32 LDS transpose: coalesced resid loads
//      (short8) replace 32 scalar 2B loads/thread in conv9r.
//      Math order identical to R10 (same absmax).
// ---------------------------------------------------------------------------

#define HPX 65536   // 256*256
#define FCH 64
#define CHPX 32768  // head px-chunk

typedef __attribute__((ext_vector_type(8))) short  short8;
typedef __attribute__((ext_vector_type(4))) float  floatx4;

__device__ __forceinline__ float gelu_f(float x) {
  return 0.5f * x * (1.0f + erff(x * 0.70710678118654752440f));
}
__device__ __forceinline__ unsigned short f2bf(float x) {  // RNE
  unsigned u = __float_as_uint(x);
  unsigned r = (u + 0x7FFFu + ((u >> 16) & 1u)) >> 16;
  return (unsigned short)r;
}
__device__ __forceinline__ float bf2f(unsigned short h) {
  return __uint_as_float(((unsigned)h) << 16);
}

// ---------------- conv0 part A: channels 0..47 = gelu(w0b[c] * target)
__global__ __launch_bounds__(256) void conv0_elem_kernel(
    const float* __restrict__ img,   // [2][5][256][256]
    const float* __restrict__ w0b,   // [48]
    unsigned short* __restrict__ ohi,  // [2][65536][64]
    unsigned short* __restrict__ olo)
{
  int t = blockIdx.x * 256 + threadIdx.x;     // over 2*HPX*6 = 786432
  int cg = t % 6;
  int pn = t / 6;                              // n*HPX + px
  int px = pn & (HPX - 1);
  int n  = pn >> 16;
  float x = img[(long)n * 5 * HPX + 2 * HPX + px];
  short8 oh, ol;
  #pragma unroll
  for (int j = 0; j < 8; j++) {
    int c = cg * 8 + j;
    float v = gelu_f(w0b[c] * x);
    unsigned short hb = f2bf(v);
    oh[j] = (short)hb;
    ol[j] = (short)f2bf(v - bf2f(hb));
  }
  long o = ((long)pn) * 64 + cg * 8;
  *(short8*)&ohi[o] = oh;
  *(short8*)&olo[o] = ol;
}

// ---------------- conv0 part B: channels 48..63 = gelu(3x3 conv over 4 feats)
__global__ __launch_bounds__(256) void conv0_conv_kernel(
    const float* __restrict__ img,   // [2][5][256][256]
    const float* __restrict__ w0a,   // [16][4][3][3]
    unsigned short* __restrict__ ohi,
    unsigned short* __restrict__ olo)
{
  int t = blockIdx.x * 256 + threadIdx.x;     // over 2*HPX*2 = 262144
  int cg = t & 1;
  int pn = t >> 1;
  int px = pn & (HPX - 1);
  int n  = pn >> 16;
  int y = px >> 8, x = px & 255;
  const float* im = img + (long)n * 5 * HPX;
  const int map4[4] = {0, 1, 3, 4};
  float vreg[36];
  #pragma unroll
  for (int fi = 0; fi < 4; fi++)
    #pragma unroll
    for (int ky = 0; ky < 3; ky++)
      #pragma unroll
      for (int kx = 0; kx < 3; kx++) {
        int yy = y + ky - 1, xx = x + kx - 1;
        bool ok = ((unsigned)yy < 256u) && ((unsigned)xx < 256u);
        vreg[(fi * 3 + ky) * 3 + kx] =
            ok ? im[(long)map4[fi] * HPX + yy * 256 + xx] : 0.0f;
      }
  short8 oh, ol;
  #pragma unroll
  for (int j = 0; j < 8; j++) {
    int co = cg * 8 + j;                       // 0..15 -> output ch 48+co
    const float* wr = w0a + co * 36;
    float r = 0.0f;
    #pragma unroll
    for (int q = 0; q < 36; q++) r = fmaf(wr[q], vreg[q], r);
    float v = gelu_f(r);
    unsigned short hb = f2bf(v);
    oh[j] = (short)hb;
    ol[j] = (short)f2bf(v - bf2f(hb));
  }
  long o = ((long)pn) * 64 + 48 + cg * 8;
  *(short8*)&ohi[o] = oh;
  *(short8*)&olo[o] = ol;
}

// ---------------- batched conv-weight packing into MFMA B-frags (hi,lo)
struct JobArr { int4 j[29]; };   // {src_sel, src_off, ntaps, dst_off}

__global__ __launch_bounds__(256) void pack_conv_kernel(
    const float* __restrict__ cl10, const float* __restrict__ cl2,
    const float* __restrict__ first_p, const float* __restrict__ dilres_p,
    const float* __restrict__ dil_p, const float* __restrict__ ups_w,
    unsigned short* __restrict__ packs, JobArr jobs)
{
  int4 jb = jobs.j[blockIdx.y];
  int ntaps = jb.z;
  int idx = blockIdx.x * 256 + threadIdx.x;
  if (idx >= ntaps * 8192) return;
  int j  = idx & 7;
  int l  = (idx >> 3) & 63;
  int s  = (idx >> 9) & 1;
  int nt = (idx >> 10) & 3;
  int kt = (idx >> 12) & 1;
  int tap = idx >> 13;
  int oc = nt * 16 + (l & 15);
  int ci = kt * 32 + (l >> 4) * 8 + j;
  const float* src;
  switch (jb.x) {
    case 0: src = cl10; break;
    case 1: src = cl2; break;
    case 2: src = first_p; break;
    case 3: src = dilres_p; break;
    case 4: src = dil_p; break;
    default: src = ups_w; break;
  }
  float w = src[jb.y + (oc * 64 + ci) * ntaps + tap];
  unsigned short hi = f2bf(w);
  unsigned short v = (s == 0) ? hi : f2bf(w - bf2f(hi));
  packs[jb.w + idx] = v;
}

// ---------------- head weight packing (hi+lo)
__global__ __launch_bounds__(256) void pack_w1_kernel(
    const float* __restrict__ w1, unsigned short* __restrict__ w1p)
{
  int t = blockIdx.x * 256 + threadIdx.x;      // 18*18*512
  if (t >= 18 * 18 * 512) return;
  int j = t & 7, l = (t >> 3) & 63;
  int mt = (t >> 9) % 18, kt = (t >> 9) / 18;
  int oc = mt * 16 + (l & 15);
  int k  = kt * 32 + (l >> 4) * 8 + j;
  float w = w1[oc * 576 + k];
  unsigned short hi = f2bf(w);
  unsigned short lo = f2bf(w - bf2f(hi));
  long base = ((long)(kt * 18 + mt) * 2) * 512 + l * 8 + j;
  w1p[base] = hi;
  w1p[base + 512] = lo;
}
__global__ __launch_bounds__(256) void pack_w2_kernel(
    const float* __restrict__ w2, unsigned short* __restrict__ w2p)
{
  int t = blockIdx.x * 256 + threadIdx.x;      // 9*4*512
  if (t >= 9 * 4 * 512) return;
  int j = t & 7, l = (t >> 3) & 63;
  int ot = (t >> 9) % 4, kt = (t >> 9) / 4;
  int oc = ot * 16 + (l & 15);
  int k  = kt * 32 + (l >> 4) * 8 + j;
  float w = w2[oc * 288 + k];
  unsigned short hi = f2bf(w);
  unsigned short lo = f2bf(w - bf2f(hi));
  long base = ((long)(kt * 4 + ot) * 2) * 512 + l * 8 + j;
  w2p[base] = hi;
  w2p[base + 512] = lo;
}

// ---------------- software-pipelined MFMA conv (implicit GEMM, 16x16x32 bf16)
// Pipeline per tap as R9. Epilogue: acc -> f32 LDS transpose tile -> coalesced
// resid loads (short8) -> gelu -> coalesced short8 stores.
template <int NTAPS, int MT, bool RESID, bool TO_CONCAT>
__global__ __launch_bounds__(256) void conv_pipe_kernel(
    const unsigned short* __restrict__ in_hi,   // NHWC [n][npx_in][64]
    const unsigned short* __restrict__ in_lo,
    const unsigned short* __restrict__ wp,      // packed frags
    const unsigned short* __restrict__ res_hi,
    const unsigned short* __restrict__ res_lo,
    unsigned short* __restrict__ out_hi,        // act hi or concat
    unsigned short* __restrict__ out_lo,
    int Hs, int logW, int dil, int ccol)
{
  __shared__ short8 wst[2][1024];               // 2 x 16 KB double buffer
  __shared__ float  ftb[4][16][65];             // per-wave f32 transpose tiles
  const int tid  = threadIdx.x;
  const int lane = tid & 63;
  const int wave = tid >> 6;
  const int row  = lane & 15;
  const int g    = lane >> 4;
  const int n    = blockIdx.z;
  const int Ws   = 1 << logW;
  const int npx_in = Hs << logW;
  const int opx0 = blockIdx.x * (64 * MT) + wave * (16 * MT);

  const unsigned short* ihi = in_hi + (long)n * npx_in * 64;
  const unsigned short* ilo = in_lo + (long)n * npx_in * 64;
  const short8* wpv = (const short8*)wp;

  int ry[MT], rx[MT];
  #pragma unroll
  for (int mt = 0; mt < MT; mt++) {
    int p = opx0 + mt * 16 + row;
    ry[mt] = p >> logW;
    rx[mt] = p & (Ws - 1);
  }

  floatx4 acc[MT][4];
  #pragma unroll
  for (int mt = 0; mt < MT; mt++)
    #pragma unroll
    for (int nt = 0; nt < 4; nt++) acc[mt][nt] = (floatx4){0.f, 0.f, 0.f, 0.f};

  const short8 zz = {0, 0, 0, 0, 0, 0, 0, 0};
  short8 sreg[4];
  short8 ahA[MT][2], alA[MT][2], ahB[MT][2], alB[MT][2];

  auto stage_issue = [&](int t) {
    #pragma unroll
    for (int p = 0; p < 4; p++)
      sreg[p] = wpv[(long)t * 1024 + tid + p * 256];
  };
  auto stage_write = [&](int b) {
    #pragma unroll
    for (int p = 0; p < 4; p++)
      wst[b][tid + p * 256] = sreg[p];
  };
  auto a_load = [&](short8 (&ah)[MT][2], short8 (&al)[MT][2], int t) {
    const int kk  = (NTAPS == 9) ? t : (t < 4 ? t : t + 1);
    const int dyd = (kk / 3 - 1) * dil, dxd = (kk % 3 - 1) * dil;
    #pragma unroll
    for (int mt = 0; mt < MT; mt++) {
      int yy = ry[mt] + dyd, xx = rx[mt] + dxd;
      bool ok = ((unsigned)yy < (unsigned)Hs) && ((unsigned)xx < (unsigned)Ws);
      long base = ok ? (long)((yy << logW) + xx) * 64 : 0;
      #pragma unroll
      for (int kt = 0; kt < 2; kt++) {
        long a = base + kt * 32 + g * 8;
        short8 h = *(const short8*)(ihi + a);
        short8 l = *(const short8*)(ilo + a);
        ah[mt][kt] = ok ? h : zz;
        al[mt][kt] = ok ? l : zz;
      }
    }
  };
  auto compute = [&](int b, short8 (&ah)[MT][2], short8 (&al)[MT][2]) {
    #pragma unroll
    for (int kt = 0; kt < 2; kt++)
      #pragma unroll
      for (int nt = 0; nt < 4; nt++) {
        short8 bh = wst[b][(kt * 4 + nt) * 128 + lane];
        short8 bl = wst[b][(kt * 4 + nt) * 128 + 64 + lane];
        #pragma unroll
        for (int mt = 0; mt < MT; mt++) {
          acc[mt][nt] = __builtin_amdgcn_mfma_f32_16x16x32_bf16(ah[mt][kt], bh, acc[mt][nt], 0, 0, 0);
          acc[mt][nt] = __builtin_amdgcn_mfma_f32_16x16x32_bf16(ah[mt][kt], bl, acc[mt][nt], 0, 0, 0);
          acc[mt][nt] = __builtin_amdgcn_mfma_f32_16x16x32_bf16(al[mt][kt], bh, acc[mt][nt], 0, 0, 0);
        }
      }
  };

  // prologue: stage + A for tap 0
  stage_issue(0);
  a_load(ahA, alA, 0);
  stage_write(0);
  __syncthreads();

  #pragma unroll
  for (int tt = 0; tt < NTAPS; tt++) {
    const int b = tt & 1;
    if (tt + 1 < NTAPS) {
      stage_issue(tt + 1);                       // global loads, early
      if ((tt & 1) == 0) a_load(ahB, alB, tt + 1);
      else               a_load(ahA, alA, tt + 1);
    }
    if ((tt & 1) == 0) compute(b, ahA, alA);     // hides the loads above
    else               compute(b, ahB, alB);
    if (tt + 1 < NTAPS) {
      stage_write(b ^ 1);                        // write-late into other buf
      __syncthreads();                           // ONE barrier per tap
    }
  }

  // epilogue: acc -> f32 LDS tile -> (+coalesced resid) -> gelu -> short8 out
  #pragma unroll
  for (int mt = 0; mt < MT; mt++) {
    __builtin_amdgcn_wave_barrier();
    #pragma unroll
    for (int nt = 0; nt < 4; nt++)
      #pragma unroll
      for (int r = 0; r < 4; r++)
        ftb[wave][g * 4 + r][nt * 16 + row] = acc[mt][nt][r];
    __builtin_amdgcn_wave_barrier();
    const int pxb = opx0 + mt * 16;
    const int pxl = lane >> 2;
    #pragma unroll
    for (int it = 0; it < 2; it++) {
      const int ch = (lane & 3) + it * 4;
      float vv[8];
      #pragma unroll
      for (int j = 0; j < 8; j++) vv[j] = ftb[wave][pxl][ch * 8 + j];
      if (RESID) {
        long rb = ((long)n * npx_in + pxb + pxl) * 64 + ch * 8;
        short8 rh = *(const short8*)(res_hi + rb);
        short8 rl = *(const short8*)(res_lo + rb);
        #pragma unroll
        for (int j = 0; j < 8; j++)
          vv[j] += bf2f((unsigned short)rh[j]) + bf2f((unsigned short)rl[j]);
      }
      short8 oh8, ol8;
      #pragma unroll
      for (int j = 0; j < 8; j++) {
        float v = gelu_f(vv[j]);
        unsigned short hb = f2bf(v);
        oh8[j] = (short)hb;
        ol8[j] = (short)f2bf(v - bf2f(hb));
      }
      if (TO_CONCAT) {
        *(short8*)&out_hi[((long)n * HPX + pxb + pxl) * 576 + ccol + ch * 8] = oh8;
      } else {
        *(short8*)&out_hi[((long)n * npx_in + pxb + pxl) * 64 + ch * 8] = oh8;
        *(short8*)&out_lo[((long)n * npx_in + pxb + pxl) * 64 + ch * 8] = ol8;
      }
    }
  }
}

// ---------------- bilinear-upsample 1x1 conv -> concat (coalesced epilogue)
template <int MT>
__global__ __launch_bounds__(256) void ups_mfma_kernel(
    const unsigned short* __restrict__ in_hi,   // NHWC [n][npx_in][64]
    const unsigned short* __restrict__ in_lo,
    const unsigned short* __restrict__ wp,      // packed frags (1 tap)
    unsigned short* __restrict__ outc,          // concat
    int Hs, int logW, int ccol)
{
  __shared__ short8 wst[1024];                  // 16 KB: one tap's 16 frags
  __shared__ unsigned short tb[4][16][76];
  const int tid  = threadIdx.x;
  const int lane = threadIdx.x & 63;
  const int wave = threadIdx.x >> 6;
  const int row  = lane & 15;
  const int g    = lane >> 4;
  const int n    = blockIdx.z;
  const int npx_in = Hs << logW;
  const int opx0 = blockIdx.x * (64 * MT) + wave * (16 * MT);

  const unsigned short* ihi = in_hi + (long)n * npx_in * 64;
  const unsigned short* ilo = in_lo + (long)n * npx_in * 64;
  const short8* wpv = (const short8*)wp;

  int b00[MT], b01[MT], b10[MT], b11[MT];
  float bwx[MT], bwy[MT];
  #pragma unroll
  for (int mt = 0; mt < MT; mt++) {
    int p = opx0 + mt * 16 + row;
    int Y = p >> 8, X = p & 255;
    float sc = (float)Hs * (1.0f / 256.0f);
    float fy = ((float)Y + 0.5f) * sc - 0.5f;
    float fx = ((float)X + 0.5f) * sc - 0.5f;
    int y0 = (int)floorf(fy), x0 = (int)floorf(fx);
    bwy[mt] = fy - (float)y0; bwx[mt] = fx - (float)x0;
    int y0c = min(max(y0, 0), Hs - 1), y1c = min(max(y0 + 1, 0), Hs - 1);
    int x0c = min(max(x0, 0), Hs - 1), x1c = min(max(x0 + 1, 0), Hs - 1);
    b00[mt] = (y0c * Hs + x0c) * 64; b01[mt] = (y0c * Hs + x1c) * 64;
    b10[mt] = (y1c * Hs + x0c) * 64; b11[mt] = (y1c * Hs + x1c) * 64;
  }

  floatx4 acc[MT][4];
  #pragma unroll
  for (int mt = 0; mt < MT; mt++)
    #pragma unroll
    for (int nt = 0; nt < 4; nt++) acc[mt][nt] = (floatx4){0.f, 0.f, 0.f, 0.f};

  #pragma unroll
  for (int p = 0; p < 4; p++)
    wst[tid + p * 256] = wpv[tid + p * 256];
  __syncthreads();

  #pragma unroll
  for (int kt = 0; kt < 2; kt++) {
    const int ko = kt * 32 + g * 8;
    short8 ah[MT], al[MT];
    #pragma unroll
    for (int mt = 0; mt < MT; mt++) {
      short8 h00 = *(const short8*)(ihi + b00[mt] + ko);
      short8 l00 = *(const short8*)(ilo + b00[mt] + ko);
      short8 h01 = *(const short8*)(ihi + b01[mt] + ko);
      short8 l01 = *(const short8*)(ilo + b01[mt] + ko);
      short8 h10 = *(const short8*)(ihi + b10[mt] + ko);
      short8 l10 = *(const short8*)(ilo + b10[mt] + ko);
      short8 h11 = *(const short8*)(ihi + b11[mt] + ko);
      short8 l11 = *(const short8*)(ilo + b11[mt] + ko);
      short8 hh, ll;
      #pragma unroll
      for (int j = 0; j < 8; j++) {
        float v00 = bf2f((unsigned short)h00[j]) + bf2f((unsigned short)l00[j]);
        float v01 = bf2f((unsigned short)h01[j]) + bf2f((unsigned short)l01[j]);
        float v10 = bf2f((unsigned short)h10[j]) + bf2f((unsigned short)l10[j]);
        float v11 = bf2f((unsigned short)h11[j]) + bf2f((unsigned short)l11[j]);
        float v0 = v00 + bwx[mt] * (v01 - v00);
        float v1 = v10 + bwx[mt] * (v11 - v10);
        float v  = v0 + bwy[mt] * (v1 - v0);
        unsigned short hb = f2bf(v);
        hh[j] = (short)hb;
        ll[j] = (short)f2bf(v - bf2f(hb));
      }
      ah[mt] = hh; al[mt] = ll;
    }
    #pragma unroll
    for (int nt = 0; nt < 4; nt++) {
      short8 bh = wst[(kt * 4 + nt) * 2 * 64 + lane];
      short8 bl = wst[((kt * 4 + nt) * 2 + 1) * 64 + lane];
      #pragma unroll
      for (int mt = 0; mt < MT; mt++) {
        acc[mt][nt] = __builtin_amdgcn_mfma_f32_16x16x32_bf16(ah[mt], bh, acc[mt][nt], 0, 0, 0);
        acc[mt][nt] = __builtin_amdgcn_mfma_f32_16x16x32_bf16(ah[mt], bl, acc[mt][nt], 0, 0, 0);
        acc[mt][nt] = __builtin_amdgcn_mfma_f32_16x16x32_bf16(al[mt], bh, acc[mt][nt], 0, 0, 0);
      }
    }
  }

  #pragma unroll
  for (int mt = 0; mt < MT; mt++) {
    __builtin_amdgcn_wave_barrier();
    #pragma unroll
    for (int nt = 0; nt < 4; nt++)
      #pragma unroll
      for (int r = 0; r < 4; r++)
        tb[wave][g * 4 + r][nt * 16 + row] = f2bf(gelu_f(acc[mt][nt][r]));
    __builtin_amdgcn_wave_barrier();
    const int pxb = opx0 + mt * 16;
    const int pxl = lane >> 2;
    #pragma unroll
    for (int it = 0; it < 2; it++) {
      int ch = (lane & 3) + it * 4;
      short8 v8 = *(const short8*)&tb[wave][pxl][ch * 8];
      *(short8*)&outc[((long)n * HPX + pxb + pxl) * 576 + ccol + ch * 8] = v8;
    }
  }
}

// ---------------- 2x2 average pool, NHWC hi/lo -> NHWC hi/lo
__global__ __launch_bounds__(256) void avgpool_nhwc_kernel(
    const unsigned short* __restrict__ ihi, const unsigned short* __restrict__ ilo,
    unsigned short* __restrict__ ohi, unsigned short* __restrict__ olo,
    int logWo)
{
  const int lognpo = 2 * logWo;
  long t = (long)blockIdx.x * 256 + threadIdx.x;   // over 2*npo*8
  int cg = (int)(t & 7);
  int p  = (int)((t >> 3) & ((1 << lognpo) - 1));
  int n  = (int)(t >> (3 + lognpo));
  int y = p >> logWo, x = p & ((1 << logWo) - 1);
  int Wi = 2 << logWo;
  long ib = ((long)n * (4 << lognpo) + (long)(2 * y) * Wi + 2 * x) * 64 + cg * 8;
  short8 h00 = *(const short8*)(ihi + ib);
  short8 h01 = *(const short8*)(ihi + ib + 64);
  short8 h10 = *(const short8*)(ihi + ib + (long)Wi * 64);
  short8 h11 = *(const short8*)(ihi + ib + (long)Wi * 64 + 64);
  short8 l00 = *(const short8*)(ilo + ib);
  short8 l01 = *(const short8*)(ilo + ib + 64);
  short8 l10 = *(const short8*)(ilo + ib + (long)Wi * 64);
  short8 l11 = *(const short8*)(ilo + ib + (long)Wi * 64 + 64);
  short8 oh, ol;
  #pragma unroll
  for (int j = 0; j < 8; j++) {
    float v = 0.25f * ((bf2f((unsigned short)h00[j]) + bf2f((unsigned short)l00[j])) +
                       (bf2f((unsigned short)h01[j]) + bf2f((unsigned short)l01[j])) +
                       (bf2f((unsigned short)h10[j]) + bf2f((unsigned short)l10[j])) +
                       (bf2f((unsigned short)h11[j]) + bf2f((unsigned short)l11[j])));
    unsigned short hb = f2bf(v);
    oh[j] = (short)hb;
    ol[j] = (short)f2bf(v - bf2f(hb));
  }
  long ob = (((long)n << lognpo) + p) * 64 + cg * 8;
  *(short8*)(ohi + ob) = oh;
  *(short8*)(olo + ob) = ol;
}

// ---------------- head stage 1 GEMM: h = gelu(W1 @ concat), one px-chunk
__global__ __launch_bounds__(256) void out1_gemm_kernel(
    const unsigned short* __restrict__ v,       // concat NHWC [2][65536][576]
    const unsigned short* __restrict__ w1p,
    unsigned short* __restrict__ h,             // [2][CHPX][288] bf16
    int cpx)
{
  __shared__ short8 ws8[2400];                  // 38,400 B (stage / transpose)
  const int tid  = threadIdx.x;
  const int lane = tid & 63;
  const int wave = tid >> 6;
  const int row  = lane & 15;
  const int g    = lane >> 4;
  const int n    = blockIdx.y;
  const int px0  = cpx + blockIdx.x * 64;       // absolute px
  const int mtb  = (wave < 2) ? wave * 5 : 10 + (wave - 2) * 4;
  const int MTN  = (wave < 2) ? 5 : 4;
  const short8* w1v = (const short8*)w1p;

  floatx4 acc[4][5];
  #pragma unroll
  for (int t = 0; t < 4; t++)
    #pragma unroll
    for (int m = 0; m < 5; m++) acc[t][m] = (floatx4){0.f, 0.f, 0.f, 0.f};

  for (int kt = 0; kt < 18; kt++) {
    __syncthreads();                             // prev kt's LDS reads done
    #pragma unroll
    for (int p = 0; p < 9; p++)
      ws8[tid + p * 256] = w1v[kt * 2304 + tid + p * 256];
    __syncthreads();

    short8 a[4];
    #pragma unroll
    for (int t = 0; t < 4; t++)
      a[t] = *(const short8*)(v + ((long)n * HPX + px0 + t * 16 + row) * 576 +
                              kt * 32 + g * 8);
    #pragma unroll
    for (int m = 0; m < 5; m++) {
      if (m < MTN) {
        short8 bh = ws8[((mtb + m) * 2 + 0) * 64 + lane];
        short8 bl = ws8[((mtb + m) * 2 + 1) * 64 + lane];
        #pragma unroll
        for (int t = 0; t < 4; t++) {
          acc[t][m] = __builtin_amdgcn_mfma_f32_16x16x32_bf16(a[t], bh, acc[t][m], 0, 0, 0);
          acc[t][m] = __builtin_amdgcn_mfma_f32_16x16x32_bf16(a[t], bl, acc[t][m], 0, 0, 0);
        }
      }
    }
  }

  // epilogue: gelu -> bf16 -> LDS [64][300] -> coalesced h writes
  __syncthreads();
  unsigned short* hs2 = (unsigned short*)ws8;
  #pragma unroll
  for (int m = 0; m < 5; m++) {
    if (m < MTN) {
      #pragma unroll
      for (int t = 0; t < 4; t++)
        #pragma unroll
        for (int r = 0; r < 4; r++)
          hs2[(t * 16 + g * 4 + r) * 300 + (mtb + m) * 16 + row] =
              f2bf(gelu_f(acc[t][m][r]));
    }
  }
  __syncthreads();
  #pragma unroll
  for (int p = 0; p < 9; p++) {
    int li = tid + p * 256;                      // 2304 chunks of 16B
    int px = li / 36, c16 = li % 36;
    short8 v8 = *(const short8*)&hs2[px * 300 + c16 * 8];
    *(short8*)&h[((long)n * CHPX + (px0 - cpx) + px) * 288 + c16 * 8] = v8;
  }
}

// ---------------- head stage 2: out = w3 . gelu(W2 @ h), one px-chunk
__global__ __launch_bounds__(256) void out2_gemm_kernel(
    const unsigned short* __restrict__ h,       // [2][CHPX][288] bf16
    const unsigned short* __restrict__ w2p,
    const float* __restrict__ w3,               // [64]
    float* __restrict__ out,                    // [2][65536]
    int cpx)
{
  __shared__ short8 w2s[4608];                  // 73,728 B, whole w2p
  const int tid  = threadIdx.x;
  const int lane = tid & 63;
  const int wave = tid >> 6;
  const int row  = lane & 15;
  const int g    = lane >> 4;
  const int n    = blockIdx.y;
  const int pxc  = blockIdx.x * 256 + wave * 64; // px within chunk
  const short8* w2v = (const short8*)w2p;

  #pragma unroll
  for (int p = 0; p < 18; p++)
    w2s[tid + p * 256] = w2v[tid + p * 256];
  __syncthreads();

  floatx4 acc2[4][4];
  #pragma unroll
  for (int t = 0; t < 4; t++)
    #pragma unroll
    for (int ot = 0; ot < 4; ot++) acc2[t][ot] = (floatx4){0.f, 0.f, 0.f, 0.f};

  for (int kt = 0; kt < 9; kt++) {
    short8 a[4];
    #pragma unroll
    for (int t = 0; t < 4; t++)
      a[t] = *(const short8*)&h[((long)n * CHPX + pxc + t * 16 + row) * 288 +
                                kt * 32 + g * 8];
    #pragma unroll
    for (int ot = 0; ot < 4; ot++) {
      short8 bh = w2s[((kt * 4 + ot) * 2 + 0) * 64 + lane];
      short8 bl = w2s[((kt * 4 + ot) * 2 + 1) * 64 + lane];
      #pragma unroll
      for (int t = 0; t < 4; t++) {
        acc2[t][ot] = __builtin_amdgcn_mfma_f32_16x16x32_bf16(a[t], bh, acc2[t][ot], 0, 0, 0);
        acc2[t][ot] = __builtin_amdgcn_mfma_f32_16x16x32_bf16(a[t], bl, acc2[t][ot], 0, 0, 0);
      }
    }
  }

  float w3r[4];
  #pragma unroll
  for (int ot = 0; ot < 4; ot++) w3r[ot] = w3[ot * 16 + row];
  #pragma unroll
  for (int t = 0; t < 4; t++) {
    float r[4] = {0.f, 0.f, 0.f, 0.f};
    #pragma unroll
    for (int ot = 0; ot < 4; ot++)
      #pragma unroll
      for (int rr = 0; rr < 4; rr++)
        r[rr] = fmaf(w3r[ot], gelu_f(acc2[t][ot][rr]), r[rr]);
    #pragma unroll
    for (int rr = 0; rr < 4; rr++) {
      r[rr] += __shfl_xor(r[rr], 1);
      r[rr] += __shfl_xor(r[rr], 2);
      r[rr] += __shfl_xor(r[rr], 4);
      r[rr] += __shfl_xor(r[rr], 8);
    }
    if (row == 0) {
      int px = cpx + pxc + t * 16 + g * 4;
      #pragma unroll
      for (int rr = 0; rr < 4; rr++)
        out[(long)n * HPX + px + rr] = r[rr];
    }
  }
}

// ---------------------------------------------------------------------------
extern "C" void kernel_launch(void* const* d_in, const int* in_sizes, int n_in,
                              void* d_out, int out_size, void* d_ws, size_t ws_size,
                              hipStream_t stream) {
  const float* img      = (const float*)d_in[0];
  const float* w0a      = (const float*)d_in[1];
  const float* w0b      = (const float*)d_in[2];
  const float* first_p  = (const float*)d_in[3];
  const float* cl10     = (const float*)d_in[4];   // [4][2][64][64][9]
  const float* cl2      = (const float*)d_in[5];
  const float* dil_p    = (const float*)d_in[6];   // [4][64][64][8]
  const float* dilres_p = (const float*)d_in[7];
  const float* ups_w    = (const float*)d_in[8];   // [4][64][64]
  const float* w1       = (const float*)d_in[9];   // [288][576]
  const float* w2       = (const float*)d_in[10];  // [64][288]
  const float* w3       = (const float*)d_in[11];  // [64]

  const size_t CONCAT_B = 150994944ul;             // 2*65536*576*2
  const size_t ACT_B    = 16777216ul;              // 2*65536*64*2 per plane
  const size_t PACKS_B  = 3604480ul;               // 1,802,240 elems
  const size_t W1P_B    = 663552ul;
  const size_t W2P_B    = 73728ul;
  const size_t NEED = CONCAT_B + 4 * ACT_B + PACKS_B + W1P_B + W2P_B; // 222,445,568

  if (ws_size < NEED) {
    hipMemsetAsync(d_out, 0, (size_t)out_size * 4, stream);
    return;
  }

  char* wsb = (char*)d_ws;
  unsigned short* concat = (unsigned short*)wsb;
  unsigned short* Xhi = (unsigned short*)(wsb + CONCAT_B);
  unsigned short* Xlo = (unsigned short*)(wsb + CONCAT_B + ACT_B);
  unsigned short* Yhi = (unsigned short*)(wsb + CONCAT_B + 2 * ACT_B);
  unsigned short* Ylo = (unsigned short*)(wsb + CONCAT_B + 3 * ACT_B);
  unsigned short* packs = (unsigned short*)(wsb + CONCAT_B + 4 * ACT_B);
  unsigned short* w1p = (unsigned short*)(wsb + CONCAT_B + 4 * ACT_B + PACKS_B);
  unsigned short* w2p = (unsigned short*)(wsb + CONCAT_B + 4 * ACT_B + PACKS_B + W1P_B);
  unsigned short* hbuf = Xhi;   // head h buffer reuses dead act region

  // pack-destination offsets (elems)
  auto off_cl10   = [](int c) { return (long)c * 73728; };
  auto off_cl2    = [](int c) { return 589824l + (long)c * 73728; };
  const long OFF_FIRST = 1179648;
  auto off_dilres = [](int k) { return 1245184l + (long)k * 65536; };
  auto off_dil    = [](int k) { return 1507328l + (long)k * 65536; };
  auto off_ups    = [](int k) { return 1769472l + (long)k * 8192; };

  // ---- weight packing
  JobArr jobs;
  for (int c = 0; c < 8; c++) jobs.j[c]     = {0, c * 36864, 9, (int)off_cl10(c)};
  for (int c = 0; c < 8; c++) jobs.j[8 + c] = {1, c * 36864, 9, (int)off_cl2(c)};
  jobs.j[16] = {2, 0, 8, (int)OFF_FIRST};
  for (int k = 0; k < 4; k++) jobs.j[17 + k] = {3, k * 32768, 8, (int)off_dilres(k)};
  for (int k = 0; k < 4; k++) jobs.j[21 + k] = {4, k * 32768, 8, (int)off_dil(k)};
  for (int k = 0; k < 4; k++) jobs.j[25 + k] = {5, k * 4096, 1, (int)off_ups(k)};
  pack_conv_kernel<<<dim3(288, 29), 256, 0, stream>>>(
      cl10, cl2, first_p, dilres_p, dil_p, ups_w, packs, jobs);
  pack_w1_kernel<<<(18 * 18 * 512 + 255) / 256, 256, 0, stream>>>(w1, w1p);
  pack_w2_kernel<<<(9 * 4 * 512 + 255) / 256, 256, 0, stream>>>(w2, w2p);

  // ---- conv0 -> X @256 (elementwise part + 3x3 part)
  conv0_elem_kernel<<<(2 * HPX * 6) / 256, 256, 0, stream>>>(img, w0b, Xhi, Xlo);
  conv0_conv_kernel<<<(2 * HPX * 2) / 256, 256, 0, stream>>>(img, w0a, Xhi, Xlo);

  // ---- launch helpers (pipelined convs; MT=2 @256, MT=1 below)
  auto conv9 = [&](const unsigned short* ih, const unsigned short* il, long wo,
                   unsigned short* oh, unsigned short* ol, int Hs, int logW) {
    int npx = Hs << logW;
    if (npx == HPX)
      conv_pipe_kernel<9, 2, false, false><<<dim3(npx / 128, 1, 2), 256, 0, stream>>>(
          ih, il, packs + wo, nullptr, nullptr, oh, ol, Hs, logW, 1, 0);
    else
      conv_pipe_kernel<9, 1, false, false><<<dim3(npx / 64, 1, 2), 256, 0, stream>>>(
          ih, il, packs + wo, nullptr, nullptr, oh, ol, Hs, logW, 1, 0);
  };
  auto conv9r = [&](const unsigned short* ih, const unsigned short* il, long wo,
                    unsigned short* rh, unsigned short* rl, int Hs, int logW) {
    int npx = Hs << logW;
    if (npx == HPX)
      conv_pipe_kernel<9, 2, true, false><<<dim3(npx / 128, 1, 2), 256, 0, stream>>>(
          ih, il, packs + wo, rh, rl, rh, rl, Hs, logW, 1, 0);
    else
      conv_pipe_kernel<9, 1, true, false><<<dim3(npx / 64, 1, 2), 256, 0, stream>>>(
          ih, il, packs + wo, rh, rl, rh, rl, Hs, logW, 1, 0);
  };
  auto donutC = [&](const unsigned short* ih, const unsigned short* il, long wo,
                    int dil, int ccol) {  // @256 -> concat
    conv_pipe_kernel<8, 2, false, true><<<dim3(512, 1, 2), 256, 0, stream>>>(
        ih, il, packs + wo, nullptr, nullptr, concat, nullptr, 256, 8, dil, ccol);
  };
  auto donutA = [&](const unsigned short* ih, const unsigned short* il, long wo,
                    int dil, unsigned short* oh, unsigned short* ol, int Hs, int logW) {
    int npx = Hs << logW;
    if (npx == HPX)
      conv_pipe_kernel<8, 2, false, false><<<dim3(npx / 128, 1, 2), 256, 0, stream>>>(
          ih, il, packs + wo, nullptr, nullptr, oh, ol, Hs, logW, dil, 0);
    else
      conv_pipe_kernel<8, 1, false, false><<<dim3(npx / 64, 1, 2), 256, 0, stream>>>(
          ih, il, packs + wo, nullptr, nullptr, oh, ol, Hs, logW, dil, 0);
  };
  auto upsC = [&](const unsigned short* ih, const unsigned short* il, long wo,
                  int Hs, int logW, int ccol) {
    ups_mfma_kernel<4><<<dim3(256, 1, 2), 256, 0, stream>>>(
        ih, il, packs + wo, concat, Hs, logW, ccol);
  };
  auto avgp = [&](const unsigned short* ih, const unsigned short* il,
                  unsigned short* oh, unsigned short* ol, int logWo) {
    long total = 2l * (1l << (2 * logWo)) * 8;
    avgpool_nhwc_kernel<<<(int)(total / 256), 256, 0, stream>>>(ih, il, oh, ol, logWo);
  };

  // ---- @256: outs[0], resblock cl10[0], outs[1], resblock cl2[0]
  donutC(Xhi, Xlo, OFF_FIRST, 1, 0);
  conv9(Xhi, Xlo, off_cl10(0), Yhi, Ylo, 256, 8);
  conv9r(Yhi, Ylo, off_cl10(1), Xhi, Xlo, 256, 8);           // base = X @256
  donutC(Xhi, Xlo, off_dilres(0), 3, 64);
  conv9(Xhi, Xlo, off_cl2(0), Yhi, Ylo, 256, 8);
  conv9r(Yhi, Ylo, off_cl2(1), Xhi, Xlo, 256, 8);            // base = X @256

  // ---- i = 0 (dil 5 @256)
  donutA(Xhi, Xlo, off_dil(0), 5, Yhi, Ylo, 256, 8);
  upsC(Yhi, Ylo, off_ups(0), 256, 8, 128);
  avgp(Xhi, Xlo, Yhi, Ylo, 7);                               // base = Y @128
  conv9(Yhi, Ylo, off_cl10(2), Xhi, Xlo, 128, 7);
  conv9r(Xhi, Xlo, off_cl10(3), Yhi, Ylo, 128, 7);           // base = Y @128
  donutA(Yhi, Ylo, off_dilres(1), 6, Xhi, Xlo, 128, 7);
  upsC(Xhi, Xlo, off_ups(1), 128, 7, 192);
  conv9(Yhi, Ylo, off_cl2(2), Xhi, Xlo, 128, 7);
  conv9r(Xhi, Xlo, off_cl2(3), Yhi, Ylo, 128, 7);            // base = Y @128

  // ---- i = 1 (dil 8 @128)
  donutA(Yhi, Ylo, off_dil(1), 8, Xhi, Xlo, 128, 7);
  upsC(Xhi, Xlo, off_ups(1), 128, 7, 256);
  avgp(Yhi, Ylo, Xhi, Xlo, 6);                               // base = X @64
  conv9(Xhi, Xlo, off_cl10(4), Yhi, Ylo, 64, 6);
  conv9r(Yhi, Ylo, off_cl10(5), Xhi, Xlo, 64, 6);            // base = X @64
  donutA(Xhi, Xlo, off_dilres(2), 8, Yhi, Ylo, 64, 6);
  upsC(Yhi, Ylo, off_ups(2), 64, 6, 320);
  conv9(Xhi, Xlo, off_cl2(4), Yhi, Ylo, 64, 6);
  conv9r(Yhi, Ylo, off_cl2(5), Xhi, Xlo, 64, 6);             // base = X @64

  // ---- i = 2 (dil 10 @64)
  donutA(Xhi, Xlo, off_dil(2), 10, Yhi, Ylo, 64, 6);
  upsC(Yhi, Ylo, off_ups(2), 64, 6, 384);
  avgp(Xhi, Xlo, Yhi, Ylo, 5);                               // base = Y @32
  conv9(Yhi, Ylo, off_cl10(6), Xhi, Xlo, 32, 5);
  conv9r(Xhi, Xlo, off_cl10(7), Yhi, Ylo, 32, 5);            // base = Y @32
  donutA(Yhi, Ylo, off_dilres(3), 9, Xhi, Xlo, 32, 5);
  upsC(Xhi, Xlo, off_ups(3), 32, 5, 448);
  conv9(Yhi, Ylo, off_cl2(6), Xhi, Xlo, 32, 5);
  conv9r(Xhi, Xlo, off_cl2(7), Yhi, Ylo, 32, 5);             // base = Y @32

  // ---- i = 3 (dil 11 @32)
  donutA(Yhi, Ylo, off_dil(3), 11, Xhi, Xlo, 32, 5);
  upsC(Xhi, Xlo, off_ups(3), 32, 5, 512);

  // ---- head: 2 px-chunks, h bounced through dead act region
  for (int c = 0; c < 2; c++) {
    out1_gemm_kernel<<<dim3(CHPX / 64, 2), 256, 0, stream>>>(
        concat, w1p, hbuf, c * CHPX);
    out2_gemm_kernel<<<dim3(CHPX / 256, 2), 256, 0, stream>>>(
        hbuf, w2p, w3, (float*)d_out, c * CHPX);
  }
}